// Round 1
// baseline (1429.934 us; speedup 1.0000x reference)
//
#include <hip/hip_runtime.h>
#include <math.h>

#define BSZ 2048
#define U_NB 30
#define N_NB 30
#define TITLE_LEN 10
#define W_EMB 50
#define DIM 128
#define NCAPS 8
#define NHID 16
#define ROUTIT 4
#define CONV_CH 8
#define KH 2
#define KW 20
#define FLAT 992          // 8 * 4 * 31
#define NJOBS (BSZ * 31)  // 63488 titles / user-gathers
#define TPB 8             // titles (rows) per block

// ---------------------------------------------------------------------------
// Kernel 1: title CNN path.
// rows r: r<B -> title of news_indices[r]; r>=B -> j=r-B, b=j/30, k=j%30,
//   title of user_news[user_indices[b]][k].
// out[r][128] = relu(relu(relu(maxpool(conv(emb)))@dense_w+db) @ item_w + ib)
// ---------------------------------------------------------------------------
__global__ __launch_bounds__(256) void k_title(
    const int* __restrict__ news_indices, const int* __restrict__ user_indices,
    const int* __restrict__ user_news, const int* __restrict__ title,
    const float* __restrict__ word_emb,
    const float* __restrict__ conv_w, const float* __restrict__ conv_b,
    const float* __restrict__ dense_w, const float* __restrict__ dense_b,
    const float* __restrict__ item_w, const float* __restrict__ item_b,
    float* __restrict__ out) {
  __shared__ float s_x[TPB][TITLE_LEN][W_EMB];   // 16000 B
  __shared__ float s_flat[TPB][FLAT];            // 31744 B
  __shared__ float s_cnn[TPB][DIM];              // 4096 B
  __shared__ float s_cw[CONV_CH * KH * KW];      // 1280 B
  __shared__ float s_cb[CONV_CH];
  __shared__ int s_words[TPB][TITLE_LEN];

  const int tid = threadIdx.x;
  const int base = blockIdx.x * TPB;

  if (tid < CONV_CH * KH * KW) s_cw[tid] = conv_w[tid];
  if (tid < CONV_CH) s_cb[tid] = conv_b[tid];

  // word ids for the 8 titles
  for (int idx = tid; idx < TPB * TITLE_LEN; idx += 256) {
    const int t = idx / TITLE_LEN, wi = idx % TITLE_LEN;
    const int r = base + t;
    int nid = 0;
    if (r < NJOBS) {
      if (r < BSZ) {
        nid = news_indices[r];
      } else {
        const int j = r - BSZ;
        const int b = j / N_NB, k = j % N_NB;
        nid = user_news[(long long)user_indices[b] * N_NB + k];
      }
    }
    s_words[t][wi] = title[(long long)nid * TITLE_LEN + wi];
  }
  __syncthreads();

  // gather word embeddings -> s_x
  for (int idx = tid; idx < TPB * TITLE_LEN * W_EMB; idx += 256) {
    const int t = idx / (TITLE_LEN * W_EMB);
    const int e = idx % (TITLE_LEN * W_EMB);
    const int wi = e / W_EMB, d = e % W_EMB;
    s_x[t][wi][d] = word_emb[(long long)s_words[t][wi] * W_EMB + d];
  }
  __syncthreads();

  // conv + relu + maxpool -> s_flat.  thread = (c, t, h): c=tid>>5,
  // t=(tid>>2)&7, h=tid&3.  conv rows i0=2h (x rows 2h,2h+1) and i1=2h+1
  // (x rows 2h+1,2h+2); stream x rows through registers.
  {
    const int c = tid >> 5;
    const int t = (tid >> 2) & 7;
    const int h = tid & 3;
    float a0[31], a1[31];
    const float bias = s_cb[c];
#pragma unroll
    for (int w = 0; w < 31; ++w) { a0[w] = bias; a1[w] = bias; }
#pragma unroll
    for (int r = 0; r < 3; ++r) {
      float xr[W_EMB];
#pragma unroll
      for (int e = 0; e < W_EMB; ++e) xr[e] = s_x[t][2 * h + r][e];
      if (r < 2) {  // contributes to conv row 2h with di = r
#pragma unroll
        for (int dj = 0; dj < KW; ++dj) {
          const float wgt = s_cw[c * 40 + r * 20 + dj];
#pragma unroll
          for (int w = 0; w < 31; ++w) a0[w] += xr[w + dj] * wgt;
        }
      }
      if (r > 0) {  // contributes to conv row 2h+1 with di = r-1
#pragma unroll
        for (int dj = 0; dj < KW; ++dj) {
          const float wgt = s_cw[c * 40 + (r - 1) * 20 + dj];
#pragma unroll
          for (int w = 0; w < 31; ++w) a1[w] += xr[w + dj] * wgt;
        }
      }
    }
#pragma unroll
    for (int w = 0; w < 31; ++w)
      s_flat[t][c * 124 + h * 31 + w] = fmaxf(fmaxf(a0[w], a1[w]), 0.f);
  }
  __syncthreads();

  // dense [992 x 128]: thread (tg,o) handles titles tg,tg+2,tg+4,tg+6
  const int o = tid & 127;
  const int tg = tid >> 7;
  {
    float acc[4];
#pragma unroll
    for (int j = 0; j < 4; ++j) acc[j] = dense_b[o];
    for (int f = 0; f < FLAT; f += 4) {
      const float w0 = dense_w[(f + 0) * DIM + o];
      const float w1 = dense_w[(f + 1) * DIM + o];
      const float w2 = dense_w[(f + 2) * DIM + o];
      const float w3 = dense_w[(f + 3) * DIM + o];
#pragma unroll
      for (int j = 0; j < 4; ++j) {
        const float4 fl = *reinterpret_cast<const float4*>(&s_flat[tg + 2 * j][f]);
        acc[j] += fl.x * w0 + fl.y * w1 + fl.z * w2 + fl.w * w3;
      }
    }
#pragma unroll
    for (int j = 0; j < 4; ++j) s_cnn[tg + 2 * j][o] = fmaxf(acc[j], 0.f);
  }
  __syncthreads();

  // item transform [128 x 128] + relu, write out
  {
    float acc[4];
#pragma unroll
    for (int j = 0; j < 4; ++j) acc[j] = item_b[o];
    for (int k = 0; k < DIM; k += 4) {
      const float w0 = item_w[(k + 0) * DIM + o];
      const float w1 = item_w[(k + 1) * DIM + o];
      const float w2 = item_w[(k + 2) * DIM + o];
      const float w3 = item_w[(k + 3) * DIM + o];
#pragma unroll
      for (int j = 0; j < 4; ++j) {
        const float4 cv = *reinterpret_cast<const float4*>(&s_cnn[tg + 2 * j][k]);
        acc[j] += cv.x * w0 + cv.y * w1 + cv.z * w2 + cv.w * w3;
      }
    }
#pragma unroll
    for (int j = 0; j < 4; ++j) {
      const int r = base + tg + 2 * j;
      if (r < NJOBS) out[(long long)r * DIM + o] = fmaxf(acc[j], 0.f);
    }
  }
}

// ---------------------------------------------------------------------------
// Kernel 2: user path. rows r: r<B -> user_indices[r]; else
//   uid = news_user[news_indices[b]][k].  out = relu(emb @ user_w + user_b)
// ---------------------------------------------------------------------------
__global__ __launch_bounds__(256) void k_user(
    const int* __restrict__ user_indices, const int* __restrict__ news_indices,
    const int* __restrict__ news_user, const float* __restrict__ user_emb,
    const float* __restrict__ user_w, const float* __restrict__ user_b,
    float* __restrict__ out) {
  __shared__ float s_e[TPB][DIM];
  const int tid = threadIdx.x;
  const int base = blockIdx.x * TPB;
  for (int idx = tid; idx < TPB * DIM; idx += 256) {
    const int t = idx / DIM, d = idx % DIM;
    const int r = base + t;
    int uid = 0;
    if (r < NJOBS) {
      if (r < BSZ) {
        uid = user_indices[r];
      } else {
        const int j = r - BSZ;
        const int b = j / U_NB, k = j % U_NB;
        uid = news_user[(long long)news_indices[b] * U_NB + k];
      }
    }
    s_e[t][d] = user_emb[(long long)uid * DIM + d];
  }
  __syncthreads();
  const int o = tid & 127;
  const int tg = tid >> 7;
  float acc[4];
#pragma unroll
  for (int j = 0; j < 4; ++j) acc[j] = user_b[o];
  for (int k = 0; k < DIM; k += 4) {
    const float w0 = user_w[(k + 0) * DIM + o];
    const float w1 = user_w[(k + 1) * DIM + o];
    const float w2 = user_w[(k + 2) * DIM + o];
    const float w3 = user_w[(k + 3) * DIM + o];
#pragma unroll
    for (int j = 0; j < 4; ++j) {
      const float4 ev = *reinterpret_cast<const float4*>(&s_e[tg + 2 * j][k]);
      acc[j] += ev.x * w0 + ev.y * w1 + ev.z * w2 + ev.w * w3;
    }
  }
#pragma unroll
  for (int j = 0; j < 4; ++j) {
    const int r = base + tg + 2 * j;
    if (r < NJOBS) out[(long long)r * DIM + o] = fmaxf(acc[j], 0.f);
  }
}

// ---------------------------------------------------------------------------
// Kernel 3: capsule routing.  job j<B: news routing (x=conv_path[j],
// z=user_path[B+j*30+k]); j>=B: user routing (x=user_path[j-B],
// z=conv_path[B+(j-B)*30+k]).  128 threads: cap c=tid>>4, dim=tid&15.
// ---------------------------------------------------------------------------
__device__ __forceinline__ float gsum16(float v) {
  v += __shfl_xor(v, 1, 16);
  v += __shfl_xor(v, 2, 16);
  v += __shfl_xor(v, 4, 16);
  v += __shfl_xor(v, 8, 16);
  return v;
}

__global__ __launch_bounds__(128) void k_route(
    const float* __restrict__ conv_path, const float* __restrict__ user_path,
    float* __restrict__ news_out, float* __restrict__ user_out) {
  const int j = blockIdx.x;
  const int tid = threadIdx.x;
  const bool is_news = (j < BSZ);
  const int b = is_news ? j : j - BSZ;
  const float* xrow = is_news ? conv_path + (long long)b * DIM
                              : user_path + (long long)b * DIM;
  const float* zbase = is_news ? user_path + (long long)(BSZ + b * 30) * DIM
                               : conv_path + (long long)(BSZ + b * 30) * DIM;
  const int c = tid >> 4;

  float x = xrow[tid];
  x = x / (sqrtf(gsum16(x * x)) + 1e-9f);

  float z[30];
#pragma unroll
  for (int k = 0; k < 30; ++k) {
    float v = zbase[k * DIM + tid];
    z[k] = v / (sqrtf(gsum16(v * v)) + 1e-9f);
  }

  float u = x;
  __shared__ float s_p[30][NCAPS];
  for (int it = 0; it < ROUTIT; ++it) {
#pragma unroll
    for (int k = 0; k < 30; ++k) {
      const float dot = gsum16(z[k] * u);
      if ((tid & 15) == 0) s_p[k][c] = dot;
    }
    __syncthreads();
    if (tid < 30) {
      float m = -1e30f;
#pragma unroll
      for (int cc = 0; cc < NCAPS; ++cc) m = fmaxf(m, s_p[tid][cc]);
      float s = 0.f, e[NCAPS];
#pragma unroll
      for (int cc = 0; cc < NCAPS; ++cc) { e[cc] = expf(s_p[tid][cc] - m); s += e[cc]; }
#pragma unroll
      for (int cc = 0; cc < NCAPS; ++cc) s_p[tid][cc] = e[cc] / s;
    }
    __syncthreads();
    float agg = x;
#pragma unroll
    for (int k = 0; k < 30; ++k) agg += s_p[k][c] * z[k];
    u = agg / (sqrtf(gsum16(agg * agg)) + 1e-9f);
    __syncthreads();
  }
  (is_news ? news_out : user_out)[(long long)b * DIM + tid] = u;
}

// ---------------------------------------------------------------------------
// Kernel 4: scoring.  score = sum((u@W+b) * (n@W+b)); sigmoid.
// ---------------------------------------------------------------------------
__global__ __launch_bounds__(128) void k_score(
    const float* __restrict__ user_e, const float* __restrict__ news_e,
    const float* __restrict__ last_w, const float* __restrict__ last_b,
    float* __restrict__ out) {
  const int b = blockIdx.x, tid = threadIdx.x;
  __shared__ float s_u[DIM], s_n[DIM];
  __shared__ float s_r[2];
  s_u[tid] = user_e[(long long)b * DIM + tid];
  s_n[tid] = news_e[(long long)b * DIM + tid];
  __syncthreads();
  float xm = last_b[tid], ym = last_b[tid];
  for (int k = 0; k < DIM; k += 4) {
#pragma unroll
    for (int i = 0; i < 4; ++i) {
      const float w = last_w[(k + i) * DIM + tid];
      xm += s_u[k + i] * w;
      ym += s_n[k + i] * w;
    }
  }
  float prod = xm * ym;
#pragma unroll
  for (int off = 1; off < 64; off <<= 1) prod += __shfl_xor(prod, off, 64);
  if ((tid & 63) == 0) s_r[tid >> 6] = prod;
  __syncthreads();
  if (tid == 0) {
    const float s = s_r[0] + s_r[1];
    out[b] = 1.f / (1.f + expf(-s));
  }
}

// ---------------------------------------------------------------------------
extern "C" void kernel_launch(void* const* d_in, const int* in_sizes, int n_in,
                              void* d_out, int out_size, void* d_ws,
                              size_t ws_size, hipStream_t stream) {
  (void)in_sizes; (void)n_in; (void)out_size; (void)ws_size;
  const int* user_indices = (const int*)d_in[0];
  const int* news_indices = (const int*)d_in[1];
  // d_in[2] = labels (unused in forward)
  const int* news_user = (const int*)d_in[3];
  const int* user_news = (const int*)d_in[4];
  const int* title = (const int*)d_in[5];
  const float* user_emb_matrix = (const float*)d_in[6];
  const float* word_emb_matrix = (const float*)d_in[7];
  const float* conv_w = (const float*)d_in[8];
  const float* conv_b = (const float*)d_in[9];
  const float* dense_w = (const float*)d_in[10];
  const float* dense_b = (const float*)d_in[11];
  const float* user_weights = (const float*)d_in[12];
  const float* user_bias = (const float*)d_in[13];
  const float* item_weights = (const float*)d_in[14];
  const float* item_bias = (const float*)d_in[15];
  const float* last_w = (const float*)d_in[16];
  const float* last_b = (const float*)d_in[17];

  float* conv_path = (float*)d_ws;                          // NJOBS*128 f32
  float* user_path = conv_path + (size_t)NJOBS * DIM;       // NJOBS*128 f32
  float* news_emb = user_path + (size_t)NJOBS * DIM;        // B*128
  float* user_emb = news_emb + (size_t)BSZ * DIM;           // B*128
  float* out = (float*)d_out;

  k_title<<<NJOBS / TPB, 256, 0, stream>>>(
      news_indices, user_indices, user_news, title, word_emb_matrix, conv_w,
      conv_b, dense_w, dense_b, item_weights, item_bias, conv_path);
  k_user<<<NJOBS / TPB, 256, 0, stream>>>(
      user_indices, news_indices, news_user, user_emb_matrix, user_weights,
      user_bias, user_path);
  k_route<<<2 * BSZ, 128, 0, stream>>>(conv_path, user_path, news_emb, user_emb);
  k_score<<<BSZ, 128, 0, stream>>>(user_emb, news_emb, last_w, last_b, out);
}

// Round 3
// 418.917 us; speedup vs baseline: 3.4134x; 3.4134x over previous
//
#include <hip/hip_runtime.h>
#include <hip/hip_bf16.h>
#include <math.h>

#define BSZ 2048
#define NNEWS 50000
#define U_NB 30
#define N_NB 30
#define TITLE_LEN 10
#define W_EMB 50
#define DIM 128
#define ROUTIT 4
#define FLAT 992          // 8ch * 4 * 31
#define NJOBS (BSZ * 31)  // 63488 user-path rows

typedef __attribute__((ext_vector_type(8))) short bf16x8;
typedef __attribute__((ext_vector_type(4))) float f32x4;

// ---------------------------------------------------------------------------
// Prep: transpose + bf16-convert the three GEMM weight matrices.
// dwt[o][k]=dense_w[k][o] (992K), iwt[o][k]=item_w[k][o], uwt[o][k]=user_w[k][o]
// ---------------------------------------------------------------------------
__global__ __launch_bounds__(256) void k_prep(
    const float* __restrict__ dw, const float* __restrict__ iw,
    const float* __restrict__ uw, __hip_bfloat16* __restrict__ dwt,
    __hip_bfloat16* __restrict__ iwt, __hip_bfloat16* __restrict__ uwt) {
  const int idx = blockIdx.x * 256 + threadIdx.x;
  if (idx < FLAT * DIM) {
    const int o = idx & 127, k = idx >> 7;
    dwt[o * FLAT + k] = __float2bfloat16(dw[idx]);
  } else if (idx < FLAT * DIM + DIM * DIM) {
    const int j = idx - FLAT * DIM;
    const int o = j & 127, k = j >> 7;
    iwt[o * DIM + k] = __float2bfloat16(iw[j]);
  } else if (idx < FLAT * DIM + 2 * DIM * DIM) {
    const int j = idx - FLAT * DIM - DIM * DIM;
    const int o = j & 127, k = j >> 7;
    uwt[o * DIM + k] = __float2bfloat16(uw[j]);
  }
}

// ---------------------------------------------------------------------------
// k_news: per news id (0..49999): conv+pool -> flat(992) bf16 in LDS,
// then MFMA GEMM x dense_wt (+bias,relu), then x item_wt (+bias,relu) -> out.
// Block = 256 threads (4 waves), 32 news/block.
// Conv: lane = ri*8+ci (conv row 0..7, channel 0..7), one title per wave-pass.
// GEMM: wave w owns cols 32w..32w+31; 2 M-frags x 2 N-frags, K-step 32.
// ---------------------------------------------------------------------------
__global__ __launch_bounds__(256, 2) void k_news(
    const int* __restrict__ title, const float* __restrict__ word_emb,
    const float* __restrict__ conv_w, const float* __restrict__ conv_b,
    const __hip_bfloat16* __restrict__ dwt, const float* __restrict__ dense_b,
    const __hip_bfloat16* __restrict__ iwt, const float* __restrict__ item_b,
    float* __restrict__ out) {
  __shared__ __align__(16) __hip_bfloat16 s_flat[32][1000];  // 64000 B (pad 992->1000)
  __shared__ __align__(16) float s_x[4][TITLE_LEN][56];      // 8960 B, reused as s_c1
  __shared__ __align__(16) __hip_bfloat16 s_bt[DIM][32];     // 8192 B  B-slice [col][k]
  __hip_bfloat16* s_c1 = (__hip_bfloat16*)&s_x[0][0][0];     // [32][136] bf16 (8704 B)

  const int tid = threadIdx.x;
  const int wave = tid >> 6, lane = tid & 63;
  const int base = blockIdx.x * 32;

  // ---- conv phase ----
  const int ci = lane & 7;   // channel
  const int ri = lane >> 3;  // conv row 0..7
  float wreg[40];
#pragma unroll
  for (int d = 0; d < 10; ++d)
    *reinterpret_cast<float4*>(&wreg[d * 4]) =
        reinterpret_cast<const float4*>(conv_w)[ci * 10 + d];
  const float cbias = conv_b[ci];

  for (int t8 = 0; t8 < 8; ++t8) {
    const int t = wave * 8 + t8;
    int nid = base + t;
    if (nid >= NNEWS) nid = 0;
    // gather word embeddings for this wave's title
    for (int e = lane; e < TITLE_LEN * W_EMB; e += 64) {
      const int wi = e / W_EMB, d = e - wi * W_EMB;
      const int word = title[nid * TITLE_LEN + wi];
      s_x[wave][wi][d] = word_emb[word * W_EMB + d];
    }
    __syncthreads();
    float acc[31];
#pragma unroll
    for (int w = 0; w < 31; ++w) acc[w] = cbias;
    {
      float xr[52];
#pragma unroll
      for (int e = 0; e < 13; ++e)
        *reinterpret_cast<float4*>(&xr[e * 4]) =
            *reinterpret_cast<const float4*>(&s_x[wave][ri][e * 4]);
#pragma unroll
      for (int dj = 0; dj < 20; ++dj)
#pragma unroll
        for (int w = 0; w < 31; ++w) acc[w] += xr[w + dj] * wreg[dj];
#pragma unroll
      for (int e = 0; e < 13; ++e)
        *reinterpret_cast<float4*>(&xr[e * 4]) =
            *reinterpret_cast<const float4*>(&s_x[wave][ri + 1][e * 4]);
#pragma unroll
      for (int dj = 0; dj < 20; ++dj)
#pragma unroll
        for (int w = 0; w < 31; ++w) acc[w] += xr[w + dj] * wreg[20 + dj];
    }
    // maxpool over conv-row pairs (2h,2h+1) + relu -> s_flat bf16
#pragma unroll
    for (int w = 0; w < 31; ++w) {
      const float m = fmaxf(fmaxf(acc[w], __shfl_xor(acc[w], 8)), 0.f);
      if ((ri & 1) == 0)
        s_flat[t][ci * 124 + (ri >> 1) * 31 + w] = __float2bfloat16(m);
    }
    __syncthreads();
  }

  // ---- dense GEMM: [32 x 992] @ [992 x 128] ----
  const int fr = lane & 15, gk = lane >> 4;
  f32x4 acc[2][2];
#pragma unroll
  for (int m = 0; m < 2; ++m)
#pragma unroll
    for (int n = 0; n < 2; ++n) acc[m][n] = (f32x4){0.f, 0.f, 0.f, 0.f};

  for (int ks = 0; ks < 31; ++ks) {
    __syncthreads();
#pragma unroll
    for (int q = 0; q < 2; ++q) {  // stage B slice: 512 uint4
      const int uu = tid * 2 + q;
      const int o = uu >> 2, koff = (uu & 3) * 8;
      *reinterpret_cast<uint4*>(&s_bt[o][koff]) =
          *reinterpret_cast<const uint4*>(&dwt[o * FLAT + ks * 32 + koff]);
    }
    __syncthreads();
    bf16x8 af[2], bfr[2];
#pragma unroll
    for (int m = 0; m < 2; ++m)
      af[m] = *reinterpret_cast<const bf16x8*>(
          &s_flat[m * 16 + fr][ks * 32 + gk * 8]);
#pragma unroll
    for (int n = 0; n < 2; ++n)
      bfr[n] = *reinterpret_cast<const bf16x8*>(
          &s_bt[wave * 32 + n * 16 + fr][gk * 8]);
#pragma unroll
    for (int m = 0; m < 2; ++m)
#pragma unroll
      for (int n = 0; n < 2; ++n)
        acc[m][n] =
            __builtin_amdgcn_mfma_f32_16x16x32_bf16(af[m], bfr[n], acc[m][n], 0, 0, 0);
  }

  // epilogue: +bias, relu, bf16 -> s_c1[32][136]
#pragma unroll
  for (int n = 0; n < 2; ++n) {
    const int col = wave * 32 + n * 16 + fr;
    const float bb = dense_b[col];
#pragma unroll
    for (int m = 0; m < 2; ++m)
#pragma unroll
      for (int r = 0; r < 4; ++r) {
        const int row = m * 16 + gk * 4 + r;
        s_c1[row * 136 + col] = __float2bfloat16(fmaxf(acc[m][n][r] + bb, 0.f));
      }
  }

  // ---- item GEMM: [32 x 128] @ [128 x 128] ----
  f32x4 acc2[2][2];
#pragma unroll
  for (int m = 0; m < 2; ++m)
#pragma unroll
    for (int n = 0; n < 2; ++n) acc2[m][n] = (f32x4){0.f, 0.f, 0.f, 0.f};

  for (int ks = 0; ks < 4; ++ks) {
    __syncthreads();
#pragma unroll
    for (int q = 0; q < 2; ++q) {
      const int uu = tid * 2 + q;
      const int o = uu >> 2, koff = (uu & 3) * 8;
      *reinterpret_cast<uint4*>(&s_bt[o][koff]) =
          *reinterpret_cast<const uint4*>(&iwt[o * DIM + ks * 32 + koff]);
    }
    __syncthreads();
    bf16x8 af[2], bfr[2];
#pragma unroll
    for (int m = 0; m < 2; ++m)
      af[m] = *reinterpret_cast<const bf16x8*>(
          &s_c1[(m * 16 + fr) * 136 + ks * 32 + gk * 8]);
#pragma unroll
    for (int n = 0; n < 2; ++n)
      bfr[n] = *reinterpret_cast<const bf16x8*>(
          &s_bt[wave * 32 + n * 16 + fr][gk * 8]);
#pragma unroll
    for (int m = 0; m < 2; ++m)
#pragma unroll
      for (int n = 0; n < 2; ++n)
        acc2[m][n] =
            __builtin_amdgcn_mfma_f32_16x16x32_bf16(af[m], bfr[n], acc2[m][n], 0, 0, 0);
  }

#pragma unroll
  for (int n = 0; n < 2; ++n) {
    const int col = wave * 32 + n * 16 + fr;
    const float bb = item_b[col];
#pragma unroll
    for (int m = 0; m < 2; ++m)
#pragma unroll
      for (int r = 0; r < 4; ++r) {
        const int row = m * 16 + gk * 4 + r;
        const int nid = base + row;
        if (nid < NNEWS) out[nid * DIM + col] = fmaxf(acc2[m][n][r] + bb, 0.f);
      }
  }
}

// ---------------------------------------------------------------------------
// k_user: gather user_emb rows (bf16) then MFMA x user_wt (+bias, relu).
// rows r: r<B -> user_indices[r]; else j=r-B: news_user[news_indices[j/30]][j%30]
// ---------------------------------------------------------------------------
__global__ __launch_bounds__(256) void k_user(
    const int* __restrict__ user_indices, const int* __restrict__ news_indices,
    const int* __restrict__ news_user, const float* __restrict__ user_emb,
    const __hip_bfloat16* __restrict__ uwt, const float* __restrict__ user_b,
    float* __restrict__ out) {
  __shared__ __align__(16) __hip_bfloat16 s_e[32][136];
  __shared__ __align__(16) __hip_bfloat16 s_bt[DIM][32];
  __shared__ int s_uid[32];
  const int tid = threadIdx.x;
  const int wave = tid >> 6, lane = tid & 63;
  const int base = blockIdx.x * 32;

  if (tid < 32) {
    const int r = base + tid;
    int uid;
    if (r < BSZ) {
      uid = user_indices[r];
    } else {
      const int j = r - BSZ;
      const int b = j / U_NB, k = j - b * U_NB;
      uid = news_user[(long long)news_indices[b] * U_NB + k];
    }
    s_uid[tid] = uid;
  }
  __syncthreads();
#pragma unroll
  for (int i = 0; i < 4; ++i) {  // 1024 float4 total
    const int u = tid + i * 256;
    const int row = u >> 5, d4 = u & 31;
    const float4 v = *reinterpret_cast<const float4*>(
        &user_emb[(long long)s_uid[row] * DIM + d4 * 4]);
    __hip_bfloat16* p = &s_e[row][d4 * 4];
    p[0] = __float2bfloat16(v.x);
    p[1] = __float2bfloat16(v.y);
    p[2] = __float2bfloat16(v.z);
    p[3] = __float2bfloat16(v.w);
  }

  const int fr = lane & 15, gk = lane >> 4;
  f32x4 acc[2][2];
#pragma unroll
  for (int m = 0; m < 2; ++m)
#pragma unroll
    for (int n = 0; n < 2; ++n) acc[m][n] = (f32x4){0.f, 0.f, 0.f, 0.f};

  for (int ks = 0; ks < 4; ++ks) {
    __syncthreads();
#pragma unroll
    for (int q = 0; q < 2; ++q) {
      const int uu = tid * 2 + q;
      const int o = uu >> 2, koff = (uu & 3) * 8;
      *reinterpret_cast<uint4*>(&s_bt[o][koff]) =
          *reinterpret_cast<const uint4*>(&uwt[o * DIM + ks * 32 + koff]);
    }
    __syncthreads();
    bf16x8 af[2], bfr[2];
#pragma unroll
    for (int m = 0; m < 2; ++m)
      af[m] = *reinterpret_cast<const bf16x8*>(
          &s_e[m * 16 + fr][ks * 32 + gk * 8]);
#pragma unroll
    for (int n = 0; n < 2; ++n)
      bfr[n] = *reinterpret_cast<const bf16x8*>(
          &s_bt[wave * 32 + n * 16 + fr][gk * 8]);
#pragma unroll
    for (int m = 0; m < 2; ++m)
#pragma unroll
      for (int n = 0; n < 2; ++n)
        acc[m][n] =
            __builtin_amdgcn_mfma_f32_16x16x32_bf16(af[m], bfr[n], acc[m][n], 0, 0, 0);
  }

#pragma unroll
  for (int n = 0; n < 2; ++n) {
    const int col = wave * 32 + n * 16 + fr;
    const float bb = user_b[col];
#pragma unroll
    for (int m = 0; m < 2; ++m)
#pragma unroll
      for (int r = 0; r < 4; ++r) {
        const int row = m * 16 + gk * 4 + r;
        out[(base + row) * DIM + col] = fmaxf(acc[m][n][r] + bb, 0.f);
      }
  }
}

// ---------------------------------------------------------------------------
// k_route: capsule routing. j<B: news routing (x=news_cnn[news_indices[j]],
// z=user_path[B+j*30+k]); j>=B: b=j-B, user routing (x=user_path[b],
// z=news_cnn[user_news[user_indices[b]][k]]). 128 thr: cap=tid>>4, dim=tid&15.
// ---------------------------------------------------------------------------
__device__ __forceinline__ float gsum16(float v) {
  v += __shfl_xor(v, 1, 16);
  v += __shfl_xor(v, 2, 16);
  v += __shfl_xor(v, 4, 16);
  v += __shfl_xor(v, 8, 16);
  return v;
}

__global__ __launch_bounds__(128) void k_route(
    const float* __restrict__ news_cnn, const float* __restrict__ user_path,
    const int* __restrict__ user_indices, const int* __restrict__ news_indices,
    const int* __restrict__ user_news, float* __restrict__ news_out,
    float* __restrict__ user_out) {
  const int j = blockIdx.x;
  const int tid = threadIdx.x;
  const bool is_news = (j < BSZ);
  const int b = is_news ? j : j - BSZ;
  __shared__ int s_nid[N_NB];
  if (!is_news && tid < N_NB)
    s_nid[tid] = user_news[(long long)user_indices[b] * N_NB + tid];
  __syncthreads();

  const float* xrow = is_news ? news_cnn + (long long)news_indices[b] * DIM
                              : user_path + (long long)b * DIM;
  const int c = tid >> 4;

  float x = xrow[tid];
  x = x / (sqrtf(gsum16(x * x)) + 1e-9f);

  float z[30];
#pragma unroll
  for (int k = 0; k < 30; ++k) {
    const float* zr = is_news ? user_path + (long long)(BSZ + b * 30 + k) * DIM
                              : news_cnn + (long long)s_nid[k] * DIM;
    const float v = zr[tid];
    z[k] = v / (sqrtf(gsum16(v * v)) + 1e-9f);
  }

  float u = x;
  __shared__ float s_p[30][8];
  for (int it = 0; it < ROUTIT; ++it) {
#pragma unroll
    for (int k = 0; k < 30; ++k) {
      const float dot = gsum16(z[k] * u);
      if ((tid & 15) == 0) s_p[k][c] = dot;
    }
    __syncthreads();
    if (tid < 30) {
      float m = -1e30f;
#pragma unroll
      for (int cc = 0; cc < 8; ++cc) m = fmaxf(m, s_p[tid][cc]);
      float s = 0.f, e[8];
#pragma unroll
      for (int cc = 0; cc < 8; ++cc) {
        e[cc] = expf(s_p[tid][cc] - m);
        s += e[cc];
      }
#pragma unroll
      for (int cc = 0; cc < 8; ++cc) s_p[tid][cc] = e[cc] / s;
    }
    __syncthreads();
    float agg = x;
#pragma unroll
    for (int k = 0; k < 30; ++k) agg += s_p[k][c] * z[k];
    u = agg / (sqrtf(gsum16(agg * agg)) + 1e-9f);
    __syncthreads();
  }
  (is_news ? news_out : user_out)[(long long)b * DIM + tid] = u;
}

// ---------------------------------------------------------------------------
// k_score: score = sum((u@W+b) * (n@W+b)); sigmoid.
// ---------------------------------------------------------------------------
__global__ __launch_bounds__(128) void k_score(
    const float* __restrict__ user_e, const float* __restrict__ news_e,
    const float* __restrict__ last_w, const float* __restrict__ last_b,
    float* __restrict__ out) {
  const int b = blockIdx.x, tid = threadIdx.x;
  __shared__ float s_u[DIM], s_n[DIM];
  __shared__ float s_r[2];
  s_u[tid] = user_e[(long long)b * DIM + tid];
  s_n[tid] = news_e[(long long)b * DIM + tid];
  __syncthreads();
  float xm = last_b[tid], ym = last_b[tid];
  for (int k = 0; k < DIM; k += 4) {
#pragma unroll
    for (int i = 0; i < 4; ++i) {
      const float w = last_w[(k + i) * DIM + tid];
      xm += s_u[k + i] * w;
      ym += s_n[k + i] * w;
    }
  }
  float prod = xm * ym;
#pragma unroll
  for (int off = 1; off < 64; off <<= 1) prod += __shfl_xor(prod, off, 64);
  if ((tid & 63) == 0) s_r[tid >> 6] = prod;
  __syncthreads();
  if (tid == 0) {
    const float s = s_r[0] + s_r[1];
    out[b] = 1.f / (1.f + expf(-s));
  }
}

// ---------------------------------------------------------------------------
extern "C" void kernel_launch(void* const* d_in, const int* in_sizes, int n_in,
                              void* d_out, int out_size, void* d_ws,
                              size_t ws_size, hipStream_t stream) {
  (void)in_sizes; (void)n_in; (void)out_size; (void)ws_size;
  const int* user_indices = (const int*)d_in[0];
  const int* news_indices = (const int*)d_in[1];
  const int* news_user = (const int*)d_in[3];
  const int* user_news = (const int*)d_in[4];
  const int* title = (const int*)d_in[5];
  const float* user_emb_matrix = (const float*)d_in[6];
  const float* word_emb_matrix = (const float*)d_in[7];
  const float* conv_w = (const float*)d_in[8];
  const float* conv_b = (const float*)d_in[9];
  const float* dense_w = (const float*)d_in[10];
  const float* dense_b = (const float*)d_in[11];
  const float* user_weights = (const float*)d_in[12];
  const float* user_bias = (const float*)d_in[13];
  const float* item_weights = (const float*)d_in[14];
  const float* item_bias = (const float*)d_in[15];
  const float* last_w = (const float*)d_in[16];
  const float* last_b = (const float*)d_in[17];

  float* news_cnn = (float*)d_ws;                            // 50000*128
  float* user_path = news_cnn + (size_t)NNEWS * DIM;         // 63488*128
  float* news_emb = user_path + (size_t)NJOBS * DIM;         // 2048*128
  float* user_emb = news_emb + (size_t)BSZ * DIM;            // 2048*128
  __hip_bfloat16* dwt = (__hip_bfloat16*)(user_emb + (size_t)BSZ * DIM);
  __hip_bfloat16* iwt = dwt + (size_t)FLAT * DIM;
  __hip_bfloat16* uwt = iwt + (size_t)DIM * DIM;
  float* out = (float*)d_out;

  k_prep<<<(FLAT * DIM + 2 * DIM * DIM + 255) / 256, 256, 0, stream>>>(
      dense_w, item_weights, user_weights, dwt, iwt, uwt);
  k_news<<<(NNEWS + 31) / 32, 256, 0, stream>>>(
      title, word_emb_matrix, conv_w, conv_b, dwt, dense_b, iwt, item_bias,
      news_cnn);
  k_user<<<NJOBS / 32, 256, 0, stream>>>(
      user_indices, news_indices, news_user, user_emb_matrix, uwt, user_bias,
      user_path);
  k_route<<<2 * BSZ, 128, 0, stream>>>(news_cnn, user_path, user_indices,
                                       news_indices, user_news, news_emb,
                                       user_emb);
  k_score<<<BSZ, 128, 0, stream>>>(user_emb, news_emb, last_w, last_b, out);
}

// Round 4
// 392.321 us; speedup vs baseline: 3.6448x; 1.0678x over previous
//
#include <hip/hip_runtime.h>
#include <hip/hip_bf16.h>
#include <math.h>

#define BSZ 2048
#define NNEWS 50000
#define U_NB 30
#define N_NB 30
#define TITLE_LEN 10
#define W_EMB 50
#define DIM 128
#define ROUTIT 4
#define FLAT 992          // 8ch * 4 * 31
#define NJOBS (BSZ * 31)  // 63488 user-path rows

typedef __attribute__((ext_vector_type(8))) short bf16x8;
typedef __attribute__((ext_vector_type(4))) float f32x4;
typedef __attribute__((ext_vector_type(2))) float f32x2;

// ---------------------------------------------------------------------------
// Prep: transpose + bf16-convert the three GEMM weight matrices.
// ---------------------------------------------------------------------------
__global__ __launch_bounds__(256) void k_prep(
    const float* __restrict__ dw, const float* __restrict__ iw,
    const float* __restrict__ uw, __hip_bfloat16* __restrict__ dwt,
    __hip_bfloat16* __restrict__ iwt, __hip_bfloat16* __restrict__ uwt) {
  const int idx = blockIdx.x * 256 + threadIdx.x;
  if (idx < FLAT * DIM) {
    const int o = idx & 127, k = idx >> 7;
    dwt[o * FLAT + k] = __float2bfloat16(dw[idx]);
  } else if (idx < FLAT * DIM + DIM * DIM) {
    const int j = idx - FLAT * DIM;
    const int o = j & 127, k = j >> 7;
    iwt[o * DIM + k] = __float2bfloat16(iw[j]);
  } else if (idx < FLAT * DIM + 2 * DIM * DIM) {
    const int j = idx - FLAT * DIM - DIM * DIM;
    const int o = j & 127, k = j >> 7;
    uwt[o * DIM + k] = __float2bfloat16(uw[j]);
  }
}

// ---------------------------------------------------------------------------
// k_news v2: 32 news/block, 256 threads. base clamped -> no tail guards
// (overlapping blocks recompute identical values; benign duplicate writes).
// LDS map (131,840 B total):
//   [0      .. 64,000)  s_flat  [32][1000] bf16
//   [64,000 ..130,560)  s_x     [32][10][52] f32   (aliased after conv by:)
//        dense sB0 @64,000 [128][72] bf16 (18,432)
//        dense sB1 @82,432 [128][72] bf16 (18,432)
//        s_c1      @100,864 [32][136] bf16 (8,704)
//        item  sBI @64,000 [128][136] bf16 (34,816)
//   [130,560..131,840)  s_words [320] int
// ---------------------------------------------------------------------------
__global__ __launch_bounds__(256, 1) void k_news(
    const int* __restrict__ title, const float* __restrict__ word_emb,
    const float* __restrict__ conv_w, const float* __restrict__ conv_b,
    const __hip_bfloat16* __restrict__ dwt, const float* __restrict__ dense_b,
    const __hip_bfloat16* __restrict__ iwt, const float* __restrict__ item_b,
    float* __restrict__ out) {
  __shared__ __align__(16) char lds[131840];
  __hip_bfloat16* s_flat = (__hip_bfloat16*)lds;        // [32][1000]
  float* s_xf = (float*)(lds + 64000);                  // [32][10][52]
  __hip_bfloat16* sB0 = (__hip_bfloat16*)(lds + 64000);
  __hip_bfloat16* sB1 = (__hip_bfloat16*)(lds + 82432);
  __hip_bfloat16* s_c1 = (__hip_bfloat16*)(lds + 100864);
  __hip_bfloat16* sBI = (__hip_bfloat16*)(lds + 64000);
  int* s_words = (int*)(lds + 130560);

  const int tid = threadIdx.x;
  const int wv = tid >> 6, lane = tid & 63;
  const int base = min((int)blockIdx.x * 32, NNEWS - 32);

  // ---- conv weights to registers (ci = tid&7 mapping used in conv) ----
  const int t = tid >> 3, ci = tid & 7;
  float wreg[40];
#pragma unroll
  for (int d = 0; d < 10; ++d)
    *reinterpret_cast<float4*>(&wreg[d * 4]) =
        reinterpret_cast<const float4*>(conv_w)[ci * 10 + d];
  const float cb = conv_b[ci];

  // ---- phase A: word ids (coalesced; title rows for base..base+32 are
  // contiguous 320 ints) ----
  for (int idx = tid; idx < 320; idx += 256)
    s_words[idx] = title[base * 10 + idx];
  __syncthreads();

  // ---- phase B: bulk embedding gather, float2 ----
  {
    const float2* we2 = reinterpret_cast<const float2*>(word_emb);
    float2* sx2 = reinterpret_cast<float2*>(s_xf);
#pragma unroll
    for (int i = 0; i < 40; ++i) {
      const int u = i * 256 + tid;
      const int row = u >> 5, c = u & 31;
      if (c < 25) sx2[row * 26 + c] = we2[(long long)s_words[row] * 25 + c];
    }
  }
  __syncthreads();

  // ---- phase C: conv + pool + relu -> s_flat, packed f32x2 math ----
  {
    f32x2 E[26], O[25];
#define LOADROW(r)                                                           \
  {                                                                          \
    const f32x4* rp = reinterpret_cast<const f32x4*>(&s_xf[(t * 10 + (r)) * 52]); \
    _Pragma("unroll") for (int i = 0; i < 13; ++i) {                         \
      const f32x4 v = rp[i];                                                 \
      E[2 * i] = (f32x2){v.x, v.y};                                          \
      E[2 * i + 1] = (f32x2){v.z, v.w};                                      \
    }                                                                        \
    _Pragma("unroll") for (int j = 0; j < 25; ++j)                           \
        O[j] = (f32x2){E[j].y, E[j + 1].x};                                  \
  }
#define TAPS(ACC, KB)                                                        \
  _Pragma("unroll") for (int dj = 0; dj < 20; ++dj) {                        \
    const float kv = wreg[(KB) + dj];                                        \
    const f32x2 kk2 = (f32x2){kv, kv};                                       \
    const int d2 = dj >> 1;                                                  \
    if ((dj & 1) == 0) {                                                     \
      _Pragma("unroll") for (int p = 0; p < 16; ++p) ACC[p] += E[p + d2] * kk2; \
    } else {                                                                 \
      _Pragma("unroll") for (int p = 0; p < 16; ++p) ACC[p] += O[p + d2] * kk2; \
    }                                                                        \
  }
#pragma unroll 1
    for (int h = 0; h < 4; ++h) {
      f32x2 a0[16], a1[16];
#pragma unroll
      for (int p = 0; p < 16; ++p) {
        a0[p] = (f32x2){cb, cb};
        a1[p] = (f32x2){cb, cb};
      }
      LOADROW(2 * h);
      TAPS(a0, 0);
      LOADROW(2 * h + 1);
      TAPS(a0, 20);
      TAPS(a1, 0);
      LOADROW(2 * h + 2);
      TAPS(a1, 20);
      __hip_bfloat16* dst = &s_flat[t * 1000 + ci * 124 + h * 31];
#pragma unroll
      for (int p = 0; p < 15; ++p) {
        dst[2 * p] = __float2bfloat16(fmaxf(fmaxf(a0[p].x, a1[p].x), 0.f));
        dst[2 * p + 1] = __float2bfloat16(fmaxf(fmaxf(a0[p].y, a1[p].y), 0.f));
      }
      dst[30] = __float2bfloat16(fmaxf(fmaxf(a0[15].x, a1[15].x), 0.f));
    }
#undef LOADROW
#undef TAPS
  }
  __syncthreads();

  // ---- phase D: dense GEMM [32x992]@[992x128], K-step 64, dbuf + prefetch ----
  const int fr = lane & 15, gk = lane >> 4;
  uint4 pre[4];
#define DW_LOAD(KS)                                                          \
  _Pragma("unroll") for (int q = 0; q < 4; ++q) {                            \
    const int uu = tid + q * 256;                                            \
    const int o = uu >> 3, c8 = uu & 7;                                      \
    const int kof = min((KS) * 64 + c8 * 8, FLAT - 8);                       \
    pre[q] = *reinterpret_cast<const uint4*>(&dwt[o * FLAT + kof]);          \
  }
#define DW_STORE(BUF)                                                        \
  _Pragma("unroll") for (int q = 0; q < 4; ++q) {                            \
    const int uu = tid + q * 256;                                            \
    const int o = uu >> 3, c8 = uu & 7;                                      \
    *reinterpret_cast<uint4*>(&(BUF)[o * 72 + c8 * 8]) = pre[q];             \
  }
  DW_LOAD(0);
  DW_STORE(sB0);
  DW_LOAD(1);
  __syncthreads();

  f32x4 acc[2][2];
#pragma unroll
  for (int m = 0; m < 2; ++m)
#pragma unroll
    for (int n = 0; n < 2; ++n) acc[m][n] = (f32x4){0.f, 0.f, 0.f, 0.f};

  for (int ks = 0; ks < 16; ++ks) {
    __hip_bfloat16* bb = (ks & 1) ? sB1 : sB0;
    const int nkk = (ks == 15) ? 1 : 2;
#pragma unroll
    for (int kk = 0; kk < 2; ++kk) {
      if (kk < nkk) {
        bf16x8 af[2], bfr[2];
#pragma unroll
        for (int m = 0; m < 2; ++m)
          af[m] = *reinterpret_cast<const bf16x8*>(
              &s_flat[(m * 16 + fr) * 1000 + ks * 64 + kk * 32 + gk * 8]);
#pragma unroll
        for (int n = 0; n < 2; ++n)
          bfr[n] = *reinterpret_cast<const bf16x8*>(
              &bb[(wv * 32 + n * 16 + fr) * 72 + kk * 32 + gk * 8]);
#pragma unroll
        for (int m = 0; m < 2; ++m)
#pragma unroll
          for (int n = 0; n < 2; ++n)
            acc[m][n] = __builtin_amdgcn_mfma_f32_16x16x32_bf16(
                af[m], bfr[n], acc[m][n], 0, 0, 0);
      }
    }
    if (ks < 15) {
      if (ks & 1) { DW_STORE(sB0); } else { DW_STORE(sB1); }
    }
    if (ks < 14) DW_LOAD(ks + 2);
    __syncthreads();
  }
#undef DW_LOAD
#undef DW_STORE

  // dense epilogue -> s_c1 [32][136]
#pragma unroll
  for (int n = 0; n < 2; ++n) {
    const int col = wv * 32 + n * 16 + fr;
    const float bbf = dense_b[col];
#pragma unroll
    for (int m = 0; m < 2; ++m)
#pragma unroll
      for (int r = 0; r < 4; ++r) {
        const int row = m * 16 + gk * 4 + r;
        s_c1[row * 136 + col] = __float2bfloat16(fmaxf(acc[m][n][r] + bbf, 0.f));
      }
  }
  __syncthreads();

  // ---- phase E: item GEMM [32x128]@[128x128], B staged once ----
#pragma unroll
  for (int q = 0; q < 8; ++q) {
    const int uu = tid + q * 256;
    const int o = uu >> 4, c8 = uu & 15;
    *reinterpret_cast<uint4*>(&sBI[o * 136 + c8 * 8]) =
        *reinterpret_cast<const uint4*>(&iwt[o * DIM + c8 * 8]);
  }
  __syncthreads();

  f32x4 acc2[2][2];
#pragma unroll
  for (int m = 0; m < 2; ++m)
#pragma unroll
    for (int n = 0; n < 2; ++n) acc2[m][n] = (f32x4){0.f, 0.f, 0.f, 0.f};
#pragma unroll
  for (int kk = 0; kk < 4; ++kk) {
    bf16x8 af[2], bfr[2];
#pragma unroll
    for (int m = 0; m < 2; ++m)
      af[m] = *reinterpret_cast<const bf16x8*>(
          &s_c1[(m * 16 + fr) * 136 + kk * 32 + gk * 8]);
#pragma unroll
    for (int n = 0; n < 2; ++n)
      bfr[n] = *reinterpret_cast<const bf16x8*>(
          &sBI[(wv * 32 + n * 16 + fr) * 136 + kk * 32 + gk * 8]);
#pragma unroll
    for (int m = 0; m < 2; ++m)
#pragma unroll
      for (int n = 0; n < 2; ++n)
        acc2[m][n] = __builtin_amdgcn_mfma_f32_16x16x32_bf16(
            af[m], bfr[n], acc2[m][n], 0, 0, 0);
  }

#pragma unroll
  for (int n = 0; n < 2; ++n) {
    const int col = wv * 32 + n * 16 + fr;
    const float bbf = item_b[col];
#pragma unroll
    for (int m = 0; m < 2; ++m)
#pragma unroll
      for (int r = 0; r < 4; ++r) {
        const int row = m * 16 + gk * 4 + r;
        out[(base + row) * DIM + col] = fmaxf(acc2[m][n][r] + bbf, 0.f);
      }
  }
}

// ---------------------------------------------------------------------------
// k_user: gather user_emb rows (bf16) then MFMA x user_wt (+bias, relu).
// s_bt padded [128][40] to kill the 8-way bank conflict.
// ---------------------------------------------------------------------------
__global__ __launch_bounds__(256) void k_user(
    const int* __restrict__ user_indices, const int* __restrict__ news_indices,
    const int* __restrict__ news_user, const float* __restrict__ user_emb,
    const __hip_bfloat16* __restrict__ uwt, const float* __restrict__ user_b,
    float* __restrict__ out) {
  __shared__ __align__(16) __hip_bfloat16 s_e[32][136];
  __shared__ __align__(16) __hip_bfloat16 s_bt[128][40];
  __shared__ int s_uid[32];
  const int tid = threadIdx.x;
  const int wave = tid >> 6, lane = tid & 63;
  const int base = blockIdx.x * 32;

  if (tid < 32) {
    const int r = base + tid;
    int uid;
    if (r < BSZ) {
      uid = user_indices[r];
    } else {
      const int j = r - BSZ;
      const int b = j / U_NB, k = j - b * U_NB;
      uid = news_user[(long long)news_indices[b] * U_NB + k];
    }
    s_uid[tid] = uid;
  }
  __syncthreads();
#pragma unroll
  for (int i = 0; i < 4; ++i) {
    const int u = tid + i * 256;
    const int row = u >> 5, d4 = u & 31;
    const float4 v = *reinterpret_cast<const float4*>(
        &user_emb[(long long)s_uid[row] * DIM + d4 * 4]);
    __hip_bfloat16* p = &s_e[row][d4 * 4];
    p[0] = __float2bfloat16(v.x);
    p[1] = __float2bfloat16(v.y);
    p[2] = __float2bfloat16(v.z);
    p[3] = __float2bfloat16(v.w);
  }

  const int fr = lane & 15, gk = lane >> 4;
  f32x4 acc[2][2];
#pragma unroll
  for (int m = 0; m < 2; ++m)
#pragma unroll
    for (int n = 0; n < 2; ++n) acc[m][n] = (f32x4){0.f, 0.f, 0.f, 0.f};

  for (int ks = 0; ks < 4; ++ks) {
    __syncthreads();
#pragma unroll
    for (int q = 0; q < 2; ++q) {
      const int uu = tid * 2 + q;
      const int o = uu >> 2, koff = (uu & 3) * 8;
      *reinterpret_cast<uint4*>(&s_bt[o][koff]) =
          *reinterpret_cast<const uint4*>(&uwt[o * DIM + ks * 32 + koff]);
    }
    __syncthreads();
    bf16x8 af[2], bfr[2];
#pragma unroll
    for (int m = 0; m < 2; ++m)
      af[m] = *reinterpret_cast<const bf16x8*>(
          &s_e[m * 16 + fr][ks * 32 + gk * 8]);
#pragma unroll
    for (int n = 0; n < 2; ++n)
      bfr[n] = *reinterpret_cast<const bf16x8*>(
          &s_bt[wave * 32 + n * 16 + fr][gk * 8]);
#pragma unroll
    for (int m = 0; m < 2; ++m)
#pragma unroll
      for (int n = 0; n < 2; ++n)
        acc[m][n] =
            __builtin_amdgcn_mfma_f32_16x16x32_bf16(af[m], bfr[n], acc[m][n], 0, 0, 0);
  }

#pragma unroll
  for (int n = 0; n < 2; ++n) {
    const int col = wave * 32 + n * 16 + fr;
    const float bb = user_b[col];
#pragma unroll
    for (int m = 0; m < 2; ++m)
#pragma unroll
      for (int r = 0; r < 4; ++r) {
        const int row = m * 16 + gk * 4 + r;
        out[(base + row) * DIM + col] = fmaxf(acc[m][n][r] + bb, 0.f);
      }
  }
}

// ---------------------------------------------------------------------------
// k_route: capsule routing (unchanged from R3 — correct & cheap).
// ---------------------------------------------------------------------------
__device__ __forceinline__ float gsum16(float v) {
  v += __shfl_xor(v, 1, 16);
  v += __shfl_xor(v, 2, 16);
  v += __shfl_xor(v, 4, 16);
  v += __shfl_xor(v, 8, 16);
  return v;
}

__global__ __launch_bounds__(128) void k_route(
    const float* __restrict__ news_cnn, const float* __restrict__ user_path,
    const int* __restrict__ user_indices, const int* __restrict__ news_indices,
    const int* __restrict__ user_news, float* __restrict__ news_out,
    float* __restrict__ user_out) {
  const int j = blockIdx.x;
  const int tid = threadIdx.x;
  const bool is_news = (j < BSZ);
  const int b = is_news ? j : j - BSZ;
  __shared__ int s_nid[N_NB];
  if (!is_news && tid < N_NB)
    s_nid[tid] = user_news[(long long)user_indices[b] * N_NB + tid];
  __syncthreads();

  const float* xrow = is_news ? news_cnn + (long long)news_indices[b] * DIM
                              : user_path + (long long)b * DIM;
  const int c = tid >> 4;

  float x = xrow[tid];
  x = x / (sqrtf(gsum16(x * x)) + 1e-9f);

  float z[30];
#pragma unroll
  for (int k = 0; k < 30; ++k) {
    const float* zr = is_news ? user_path + (long long)(BSZ + b * 30 + k) * DIM
                              : news_cnn + (long long)s_nid[k] * DIM;
    const float v = zr[tid];
    z[k] = v / (sqrtf(gsum16(v * v)) + 1e-9f);
  }

  float u = x;
  __shared__ float s_p[30][8];
  for (int it = 0; it < ROUTIT; ++it) {
#pragma unroll
    for (int k = 0; k < 30; ++k) {
      const float dot = gsum16(z[k] * u);
      if ((tid & 15) == 0) s_p[k][c] = dot;
    }
    __syncthreads();
    if (tid < 30) {
      float m = -1e30f;
#pragma unroll
      for (int cc = 0; cc < 8; ++cc) m = fmaxf(m, s_p[tid][cc]);
      float s = 0.f, e[8];
#pragma unroll
      for (int cc = 0; cc < 8; ++cc) {
        e[cc] = expf(s_p[tid][cc] - m);
        s += e[cc];
      }
#pragma unroll
      for (int cc = 0; cc < 8; ++cc) s_p[tid][cc] = e[cc] / s;
    }
    __syncthreads();
    float agg = x;
#pragma unroll
    for (int k = 0; k < 30; ++k) agg += s_p[k][c] * z[k];
    u = agg / (sqrtf(gsum16(agg * agg)) + 1e-9f);
    __syncthreads();
  }
  (is_news ? news_out : user_out)[(long long)b * DIM + tid] = u;
}

// ---------------------------------------------------------------------------
// k_score: score = sum((u@W+b) * (n@W+b)); sigmoid.
// ---------------------------------------------------------------------------
__global__ __launch_bounds__(128) void k_score(
    const float* __restrict__ user_e, const float* __restrict__ news_e,
    const float* __restrict__ last_w, const float* __restrict__ last_b,
    float* __restrict__ out) {
  const int b = blockIdx.x, tid = threadIdx.x;
  __shared__ float s_u[DIM], s_n[DIM];
  __shared__ float s_r[2];
  s_u[tid] = user_e[(long long)b * DIM + tid];
  s_n[tid] = news_e[(long long)b * DIM + tid];
  __syncthreads();
  float xm = last_b[tid], ym = last_b[tid];
  for (int k = 0; k < DIM; k += 4) {
#pragma unroll
    for (int i = 0; i < 4; ++i) {
      const float w = last_w[(k + i) * DIM + tid];
      xm += s_u[k + i] * w;
      ym += s_n[k + i] * w;
    }
  }
  float prod = xm * ym;
#pragma unroll
  for (int off = 1; off < 64; off <<= 1) prod += __shfl_xor(prod, off, 64);
  if ((tid & 63) == 0) s_r[tid >> 6] = prod;
  __syncthreads();
  if (tid == 0) {
    const float s = s_r[0] + s_r[1];
    out[b] = 1.f / (1.f + expf(-s));
  }
}

// ---------------------------------------------------------------------------
extern "C" void kernel_launch(void* const* d_in, const int* in_sizes, int n_in,
                              void* d_out, int out_size, void* d_ws,
                              size_t ws_size, hipStream_t stream) {
  (void)in_sizes; (void)n_in; (void)out_size; (void)ws_size;
  const int* user_indices = (const int*)d_in[0];
  const int* news_indices = (const int*)d_in[1];
  const int* news_user = (const int*)d_in[3];
  const int* user_news = (const int*)d_in[4];
  const int* title = (const int*)d_in[5];
  const float* user_emb_matrix = (const float*)d_in[6];
  const float* word_emb_matrix = (const float*)d_in[7];
  const float* conv_w = (const float*)d_in[8];
  const float* conv_b = (const float*)d_in[9];
  const float* dense_w = (const float*)d_in[10];
  const float* dense_b = (const float*)d_in[11];
  const float* user_weights = (const float*)d_in[12];
  const float* user_bias = (const float*)d_in[13];
  const float* item_weights = (const float*)d_in[14];
  const float* item_bias = (const float*)d_in[15];
  const float* last_w = (const float*)d_in[16];
  const float* last_b = (const float*)d_in[17];

  float* news_cnn = (float*)d_ws;                            // 50000*128
  float* user_path = news_cnn + (size_t)NNEWS * DIM;         // 63488*128
  float* news_emb = user_path + (size_t)NJOBS * DIM;         // 2048*128
  float* user_emb = news_emb + (size_t)BSZ * DIM;            // 2048*128
  __hip_bfloat16* dwt = (__hip_bfloat16*)(user_emb + (size_t)BSZ * DIM);
  __hip_bfloat16* iwt = dwt + (size_t)FLAT * DIM;
  __hip_bfloat16* uwt = iwt + (size_t)DIM * DIM;
  float* out = (float*)d_out;

  k_prep<<<(FLAT * DIM + 2 * DIM * DIM + 255) / 256, 256, 0, stream>>>(
      dense_w, item_weights, user_weights, dwt, iwt, uwt);
  k_news<<<(NNEWS + 31) / 32, 256, 0, stream>>>(
      title, word_emb_matrix, conv_w, conv_b, dwt, dense_b, iwt, item_bias,
      news_cnn);
  k_user<<<NJOBS / 32, 256, 0, stream>>>(
      user_indices, news_indices, news_user, user_emb_matrix, uwt, user_bias,
      user_path);
  k_route<<<2 * BSZ, 128, 0, stream>>>(news_cnn, user_path, user_indices,
                                       news_indices, user_news, news_emb,
                                       user_emb);
  k_score<<<BSZ, 128, 0, stream>>>(user_emb, news_emb, last_w, last_b, out);
}

// Round 5
// 360.977 us; speedup vs baseline: 3.9613x; 1.0868x over previous
//
#include <hip/hip_runtime.h>
#include <hip/hip_bf16.h>
#include <math.h>

#define BSZ 2048
#define NNEWS 50000
#define U_NB 30
#define N_NB 30
#define TITLE_LEN 10
#define W_EMB 50
#define DIM 128
#define ROUTIT 4
#define FLAT 992          // 8ch * 4 * 31
#define NJOBS (BSZ * 31)  // 63488 user-path rows
#define CHUNK_MAX 16768

typedef __attribute__((ext_vector_type(8))) short bf16x8;
typedef __attribute__((ext_vector_type(4))) float f32x4;
typedef __attribute__((ext_vector_type(2))) float f32x2;

// ---------------------------------------------------------------------------
// Prep: transpose + bf16-convert the three GEMM weight matrices.
// ---------------------------------------------------------------------------
__global__ __launch_bounds__(256) void k_prep(
    const float* __restrict__ dw, const float* __restrict__ iw,
    const float* __restrict__ uw, __hip_bfloat16* __restrict__ dwt,
    __hip_bfloat16* __restrict__ iwt, __hip_bfloat16* __restrict__ uwt) {
  const int idx = blockIdx.x * 256 + threadIdx.x;
  if (idx < FLAT * DIM) {
    const int o = idx & 127, k = idx >> 7;
    dwt[o * FLAT + k] = __float2bfloat16(dw[idx]);
  } else if (idx < FLAT * DIM + DIM * DIM) {
    const int j = idx - FLAT * DIM;
    const int o = j & 127, k = j >> 7;
    iwt[o * DIM + k] = __float2bfloat16(iw[j]);
  } else if (idx < FLAT * DIM + 2 * DIM * DIM) {
    const int j = idx - FLAT * DIM - DIM * DIM;
    const int o = j & 127, k = j >> 7;
    uwt[o * DIM + k] = __float2bfloat16(uw[j]);
  }
}

// ---------------------------------------------------------------------------
// k_conv: 8 titles/block, 256 threads: t=tid>>5, ci=(tid>>2)&7, h=tid&3.
// Packed f32x2 conv + pool + relu -> staged bf16 -> coalesced flush to
// flat[(local row)*992] for this chunk. Only 3 syncs.
// ---------------------------------------------------------------------------
__global__ __launch_bounds__(256, 2) void k_conv(
    const int* __restrict__ title, const float* __restrict__ word_emb,
    const float* __restrict__ conv_w, const float* __restrict__ conv_b,
    __hip_bfloat16* __restrict__ flat, int cbase, int crows) {
  __shared__ __align__(16) float s_x[8][10][52];        // 16,640 B
  __shared__ __align__(16) __hip_bfloat16 s_f[8][992];  // 15,872 B
  __shared__ int s_words[80];
  const int tid = threadIdx.x;
  const int lbase = min((int)blockIdx.x * 8, crows - 8);
  const int t = tid >> 5, ci = (tid >> 2) & 7, h = tid & 3;

  float wreg[40];
#pragma unroll
  for (int d = 0; d < 10; ++d)
    *reinterpret_cast<float4*>(&wreg[d * 4]) =
        *reinterpret_cast<const float4*>(&conv_w[ci * 40 + d * 4]);
  const float cb = conv_b[ci];

  if (tid < 80) s_words[tid] = title[(cbase + lbase) * 10 + tid];
  __syncthreads();

  {  // bulk embedding gather: 80 rows x 25 float2
    const float2* we2 = reinterpret_cast<const float2*>(word_emb);
    float2* sx2 = reinterpret_cast<float2*>(&s_x[0][0][0]);
#pragma unroll
    for (int i = 0; i < 8; ++i) {
      const int u = i * 256 + tid;
      if (u < 2000) {
        const int row = u / 25, c = u - row * 25;
        sx2[row * 26 + c] = we2[(long long)s_words[row] * 25 + c];
      }
    }
  }
  __syncthreads();

  {  // conv (packed) for this thread's (t, ci, h)
    f32x2 E[26], O[25];
#define LOADROW(r)                                                            \
  {                                                                           \
    const f32x4* rp = reinterpret_cast<const f32x4*>(&s_x[t][(r)][0]);        \
    _Pragma("unroll") for (int i = 0; i < 13; ++i) {                          \
      const f32x4 v = rp[i];                                                  \
      E[2 * i] = (f32x2){v.x, v.y};                                           \
      E[2 * i + 1] = (f32x2){v.z, v.w};                                       \
    }                                                                         \
    _Pragma("unroll") for (int j = 0; j < 25; ++j)                            \
        O[j] = (f32x2){E[j].y, E[j + 1].x};                                   \
  }
#define TAPS(ACC, KB)                                                         \
  _Pragma("unroll") for (int dj = 0; dj < 20; ++dj) {                         \
    const float kv = wreg[(KB) + dj];                                         \
    const f32x2 kk2 = (f32x2){kv, kv};                                        \
    const int d2 = dj >> 1;                                                   \
    if ((dj & 1) == 0) {                                                      \
      _Pragma("unroll") for (int p = 0; p < 16; ++p) ACC[p] += E[p + d2] * kk2; \
    } else {                                                                  \
      _Pragma("unroll") for (int p = 0; p < 16; ++p) ACC[p] += O[p + d2] * kk2; \
    }                                                                         \
  }
    f32x2 a0[16], a1[16];
#pragma unroll
    for (int p = 0; p < 16; ++p) {
      a0[p] = (f32x2){cb, cb};
      a1[p] = (f32x2){cb, cb};
    }
    LOADROW(2 * h);
    TAPS(a0, 0);
    LOADROW(2 * h + 1);
    TAPS(a0, 20);
    TAPS(a1, 0);
    LOADROW(2 * h + 2);
    TAPS(a1, 20);
#undef LOADROW
#undef TAPS
    __hip_bfloat16* dst = &s_f[t][ci * 124 + h * 31];
#pragma unroll
    for (int p = 0; p < 15; ++p) {
      dst[2 * p] = __float2bfloat16(fmaxf(fmaxf(a0[p].x, a1[p].x), 0.f));
      dst[2 * p + 1] = __float2bfloat16(fmaxf(fmaxf(a0[p].y, a1[p].y), 0.f));
    }
    dst[30] = __float2bfloat16(fmaxf(fmaxf(a0[15].x, a1[15].x), 0.f));
  }
  __syncthreads();

  {  // coalesced flush: 8*992 bf16 = 992 uint4
    const uint4* sf4 = reinterpret_cast<const uint4*>(&s_f[0][0]);
    uint4* g4 = reinterpret_cast<uint4*>(&flat[(size_t)lbase * FLAT]);
#pragma unroll
    for (int i = 0; i < 4; ++i) {
      const int u = i * 256 + tid;
      if (u < 992) g4[u] = sf4[u];
    }
  }
}

// ---------------------------------------------------------------------------
// k_dense: [64 x 992]@[992 x 128] (relu,+b) then @[128 x 128] (relu,+b).
// 256 thr = 4 waves; wave wv computes 64 rows x cols [32wv,32wv+32).
// Double-buffered LDS + register prefetch, BK=64.
// LDS: A0@0(9216) A1@9216(9216) B0@18432(18432) B1@36864(18432) = 55,296 B
//   after dense: c1[64][136]@0 (17,408), sBI[128][136]@18432 (34,816)
// ---------------------------------------------------------------------------
__global__ __launch_bounds__(256, 2) void k_dense(
    const __hip_bfloat16* __restrict__ flat,
    const __hip_bfloat16* __restrict__ dwt, const float* __restrict__ dense_b,
    const __hip_bfloat16* __restrict__ iwt, const float* __restrict__ item_b,
    __hip_bfloat16* __restrict__ out, int cbase, int crows) {
  __shared__ __align__(16) char lds[55296];
  __hip_bfloat16* sA0 = (__hip_bfloat16*)lds;
  __hip_bfloat16* sA1 = (__hip_bfloat16*)(lds + 9216);
  __hip_bfloat16* sB0 = (__hip_bfloat16*)(lds + 18432);
  __hip_bfloat16* sB1 = (__hip_bfloat16*)(lds + 36864);
  __hip_bfloat16* s_c1 = (__hip_bfloat16*)lds;
  __hip_bfloat16* sBI = (__hip_bfloat16*)(lds + 18432);

  const int tid = threadIdx.x;
  const int wv = tid >> 6, lane = tid & 63;
  const int fr = lane & 15, gk = lane >> 4;
  const int lrow0 = min((int)blockIdx.x * 64, crows - 64);

  uint4 pA[2], pB[4];
#define LD_A(KS)                                                             \
  _Pragma("unroll") for (int q = 0; q < 2; ++q) {                            \
    const int uu = tid + q * 256;                                            \
    const int row = uu >> 3, c8 = uu & 7;                                    \
    const int kof = min((KS) * 64 + c8 * 8, FLAT - 8);                       \
    pA[q] = *reinterpret_cast<const uint4*>(                                 \
        &flat[(size_t)(lrow0 + row) * FLAT + kof]);                          \
  }
#define ST_A(BUF)                                                            \
  _Pragma("unroll") for (int q = 0; q < 2; ++q) {                            \
    const int uu = tid + q * 256;                                            \
    *reinterpret_cast<uint4*>(&(BUF)[(uu >> 3) * 72 + (uu & 7) * 8]) = pA[q]; \
  }
#define LD_B(KS)                                                             \
  _Pragma("unroll") for (int q = 0; q < 4; ++q) {                            \
    const int uu = tid + q * 256;                                            \
    const int o = uu >> 3, c8 = uu & 7;                                      \
    const int kof = min((KS) * 64 + c8 * 8, FLAT - 8);                       \
    pB[q] = *reinterpret_cast<const uint4*>(&dwt[o * FLAT + kof]);           \
  }
#define ST_B(BUF)                                                            \
  _Pragma("unroll") for (int q = 0; q < 4; ++q) {                            \
    const int uu = tid + q * 256;                                            \
    *reinterpret_cast<uint4*>(&(BUF)[(uu >> 3) * 72 + (uu & 7) * 8]) = pB[q]; \
  }

  LD_A(0);
  LD_B(0);
  ST_A(sA0);
  ST_B(sB0);
  LD_A(1);
  LD_B(1);
  __syncthreads();

  f32x4 acc[4][2];
#pragma unroll
  for (int m = 0; m < 4; ++m)
#pragma unroll
    for (int n = 0; n < 2; ++n) acc[m][n] = (f32x4){0.f, 0.f, 0.f, 0.f};

  for (int ks = 0; ks < 16; ++ks) {
    const __hip_bfloat16* cA = (ks & 1) ? sA1 : sA0;
    const __hip_bfloat16* cB = (ks & 1) ? sB1 : sB0;
    const int nkk = (ks == 15) ? 1 : 2;
#pragma unroll
    for (int kk = 0; kk < 2; ++kk) {
      if (kk < nkk) {
        bf16x8 af[4], bfr[2];
#pragma unroll
        for (int m = 0; m < 4; ++m)
          af[m] = *reinterpret_cast<const bf16x8*>(
              &cA[(m * 16 + fr) * 72 + kk * 32 + gk * 8]);
#pragma unroll
        for (int n = 0; n < 2; ++n)
          bfr[n] = *reinterpret_cast<const bf16x8*>(
              &cB[(wv * 32 + n * 16 + fr) * 72 + kk * 32 + gk * 8]);
#pragma unroll
        for (int m = 0; m < 4; ++m)
#pragma unroll
          for (int n = 0; n < 2; ++n)
            acc[m][n] = __builtin_amdgcn_mfma_f32_16x16x32_bf16(
                af[m], bfr[n], acc[m][n], 0, 0, 0);
      }
    }
    if (ks < 15) {
      if (ks & 1) {
        ST_A(sA0);
        ST_B(sB0);
      } else {
        ST_A(sA1);
        ST_B(sB1);
      }
    }
    if (ks < 14) {
      LD_A(ks + 2);
      LD_B(ks + 2);
    }
    __syncthreads();
  }
#undef LD_A
#undef ST_A
#undef LD_B
#undef ST_B

  // dense epilogue -> s_c1[64][136]; stage item weights
#pragma unroll
  for (int n = 0; n < 2; ++n) {
    const int col = wv * 32 + n * 16 + fr;
    const float bbf = dense_b[col];
#pragma unroll
    for (int m = 0; m < 4; ++m)
#pragma unroll
      for (int r = 0; r < 4; ++r) {
        const int row = m * 16 + gk * 4 + r;
        s_c1[row * 136 + col] = __float2bfloat16(fmaxf(acc[m][n][r] + bbf, 0.f));
      }
  }
#pragma unroll
  for (int q = 0; q < 8; ++q) {
    const int uu = tid + q * 256;
    const int o = uu >> 4, c = uu & 15;
    *reinterpret_cast<uint4*>(&sBI[o * 136 + c * 8]) =
        *reinterpret_cast<const uint4*>(&iwt[o * DIM + c * 8]);
  }
  __syncthreads();

  f32x4 acc2[4][2];
#pragma unroll
  for (int m = 0; m < 4; ++m)
#pragma unroll
    for (int n = 0; n < 2; ++n) acc2[m][n] = (f32x4){0.f, 0.f, 0.f, 0.f};
#pragma unroll
  for (int kk = 0; kk < 4; ++kk) {
    bf16x8 af[4], bfr[2];
#pragma unroll
    for (int m = 0; m < 4; ++m)
      af[m] = *reinterpret_cast<const bf16x8*>(
          &s_c1[(m * 16 + fr) * 136 + kk * 32 + gk * 8]);
#pragma unroll
    for (int n = 0; n < 2; ++n)
      bfr[n] = *reinterpret_cast<const bf16x8*>(
          &sBI[(wv * 32 + n * 16 + fr) * 136 + kk * 32 + gk * 8]);
#pragma unroll
    for (int m = 0; m < 4; ++m)
#pragma unroll
      for (int n = 0; n < 2; ++n)
        acc2[m][n] = __builtin_amdgcn_mfma_f32_16x16x32_bf16(
            af[m], bfr[n], acc2[m][n], 0, 0, 0);
  }

#pragma unroll
  for (int n = 0; n < 2; ++n) {
    const int col = wv * 32 + n * 16 + fr;
    const float bbf = item_b[col];
#pragma unroll
    for (int m = 0; m < 4; ++m)
#pragma unroll
      for (int r = 0; r < 4; ++r) {
        const int row = m * 16 + gk * 4 + r;
        out[(size_t)(cbase + lrow0 + row) * DIM + col] =
            __float2bfloat16(fmaxf(acc2[m][n][r] + bbf, 0.f));
      }
  }
}

// ---------------------------------------------------------------------------
// k_user: gather user_emb rows (bf16) then MFMA x user_wt (+bias, relu),
// output bf16.
// ---------------------------------------------------------------------------
__global__ __launch_bounds__(256) void k_user(
    const int* __restrict__ user_indices, const int* __restrict__ news_indices,
    const int* __restrict__ news_user, const float* __restrict__ user_emb,
    const __hip_bfloat16* __restrict__ uwt, const float* __restrict__ user_b,
    __hip_bfloat16* __restrict__ out) {
  __shared__ __align__(16) __hip_bfloat16 s_e[32][136];
  __shared__ __align__(16) __hip_bfloat16 s_bt[128][40];
  __shared__ int s_uid[32];
  const int tid = threadIdx.x;
  const int wave = tid >> 6, lane = tid & 63;
  const int base = blockIdx.x * 32;

  if (tid < 32) {
    const int r = base + tid;
    int uid;
    if (r < BSZ) {
      uid = user_indices[r];
    } else {
      const int j = r - BSZ;
      const int b = j / U_NB, k = j - b * U_NB;
      uid = news_user[(long long)news_indices[b] * U_NB + k];
    }
    s_uid[tid] = uid;
  }
  __syncthreads();
#pragma unroll
  for (int i = 0; i < 4; ++i) {
    const int u = tid + i * 256;
    const int row = u >> 5, d4 = u & 31;
    const float4 v = *reinterpret_cast<const float4*>(
        &user_emb[(long long)s_uid[row] * DIM + d4 * 4]);
    __hip_bfloat16* p = &s_e[row][d4 * 4];
    p[0] = __float2bfloat16(v.x);
    p[1] = __float2bfloat16(v.y);
    p[2] = __float2bfloat16(v.z);
    p[3] = __float2bfloat16(v.w);
  }

  const int fr = lane & 15, gk = lane >> 4;
  f32x4 acc[2][2];
#pragma unroll
  for (int m = 0; m < 2; ++m)
#pragma unroll
    for (int n = 0; n < 2; ++n) acc[m][n] = (f32x4){0.f, 0.f, 0.f, 0.f};

  for (int ks = 0; ks < 4; ++ks) {
    __syncthreads();
#pragma unroll
    for (int q = 0; q < 2; ++q) {
      const int uu = tid * 2 + q;
      const int o = uu >> 2, koff = (uu & 3) * 8;
      *reinterpret_cast<uint4*>(&s_bt[o][koff]) =
          *reinterpret_cast<const uint4*>(&uwt[o * DIM + ks * 32 + koff]);
    }
    __syncthreads();
    bf16x8 af[2], bfr[2];
#pragma unroll
    for (int m = 0; m < 2; ++m)
      af[m] = *reinterpret_cast<const bf16x8*>(
          &s_e[m * 16 + fr][ks * 32 + gk * 8]);
#pragma unroll
    for (int n = 0; n < 2; ++n)
      bfr[n] = *reinterpret_cast<const bf16x8*>(
          &s_bt[wave * 32 + n * 16 + fr][gk * 8]);
#pragma unroll
    for (int m = 0; m < 2; ++m)
#pragma unroll
      for (int n = 0; n < 2; ++n)
        acc[m][n] =
            __builtin_amdgcn_mfma_f32_16x16x32_bf16(af[m], bfr[n], acc[m][n], 0, 0, 0);
  }

#pragma unroll
  for (int n = 0; n < 2; ++n) {
    const int col = wave * 32 + n * 16 + fr;
    const float bb = user_b[col];
#pragma unroll
    for (int m = 0; m < 2; ++m)
#pragma unroll
      for (int r = 0; r < 4; ++r) {
        const int row = m * 16 + gk * 4 + r;
        out[(size_t)(base + row) * DIM + col] =
            __float2bfloat16(fmaxf(acc[m][n][r] + bb, 0.f));
      }
  }
}

// ---------------------------------------------------------------------------
// k_route: capsule routing on bf16 inputs.
// ---------------------------------------------------------------------------
__device__ __forceinline__ float gsum16(float v) {
  v += __shfl_xor(v, 1, 16);
  v += __shfl_xor(v, 2, 16);
  v += __shfl_xor(v, 4, 16);
  v += __shfl_xor(v, 8, 16);
  return v;
}

__global__ __launch_bounds__(128) void k_route(
    const __hip_bfloat16* __restrict__ news_cnn,
    const __hip_bfloat16* __restrict__ user_path,
    const int* __restrict__ user_indices, const int* __restrict__ news_indices,
    const int* __restrict__ user_news, float* __restrict__ news_out,
    float* __restrict__ user_out) {
  const int j = blockIdx.x;
  const int tid = threadIdx.x;
  const bool is_news = (j < BSZ);
  const int b = is_news ? j : j - BSZ;
  __shared__ int s_nid[N_NB];
  if (!is_news && tid < N_NB)
    s_nid[tid] = user_news[(long long)user_indices[b] * N_NB + tid];
  __syncthreads();

  const __hip_bfloat16* xrow =
      is_news ? news_cnn + (long long)news_indices[b] * DIM
              : user_path + (long long)b * DIM;
  const int c = tid >> 4;

  float x = __bfloat162float(xrow[tid]);
  x = x / (sqrtf(gsum16(x * x)) + 1e-9f);

  float z[30];
#pragma unroll
  for (int k = 0; k < 30; ++k) {
    const __hip_bfloat16* zr =
        is_news ? user_path + (long long)(BSZ + b * 30 + k) * DIM
                : news_cnn + (long long)s_nid[k] * DIM;
    const float v = __bfloat162float(zr[tid]);
    z[k] = v / (sqrtf(gsum16(v * v)) + 1e-9f);
  }

  float u = x;
  __shared__ float s_p[30][8];
  for (int it = 0; it < ROUTIT; ++it) {
#pragma unroll
    for (int k = 0; k < 30; ++k) {
      const float dot = gsum16(z[k] * u);
      if ((tid & 15) == 0) s_p[k][c] = dot;
    }
    __syncthreads();
    if (tid < 30) {
      float m = -1e30f;
#pragma unroll
      for (int cc = 0; cc < 8; ++cc) m = fmaxf(m, s_p[tid][cc]);
      float s = 0.f, e[8];
#pragma unroll
      for (int cc = 0; cc < 8; ++cc) {
        e[cc] = expf(s_p[tid][cc] - m);
        s += e[cc];
      }
#pragma unroll
      for (int cc = 0; cc < 8; ++cc) s_p[tid][cc] = e[cc] / s;
    }
    __syncthreads();
    float agg = x;
#pragma unroll
    for (int k = 0; k < 30; ++k) agg += s_p[k][c] * z[k];
    u = agg / (sqrtf(gsum16(agg * agg)) + 1e-9f);
    __syncthreads();
  }
  (is_news ? news_out : user_out)[(long long)b * DIM + tid] = u;
}

// ---------------------------------------------------------------------------
// k_score: score = sum((u@W+b) * (n@W+b)); sigmoid.
// ---------------------------------------------------------------------------
__global__ __launch_bounds__(128) void k_score(
    const float* __restrict__ user_e, const float* __restrict__ news_e,
    const float* __restrict__ last_w, const float* __restrict__ last_b,
    float* __restrict__ out) {
  const int b = blockIdx.x, tid = threadIdx.x;
  __shared__ float s_u[DIM], s_n[DIM];
  __shared__ float s_r[2];
  s_u[tid] = user_e[(long long)b * DIM + tid];
  s_n[tid] = news_e[(long long)b * DIM + tid];
  __syncthreads();
  float xm = last_b[tid], ym = last_b[tid];
  for (int k = 0; k < DIM; k += 4) {
#pragma unroll
    for (int i = 0; i < 4; ++i) {
      const float w = last_w[(k + i) * DIM + tid];
      xm += s_u[k + i] * w;
      ym += s_n[k + i] * w;
    }
  }
  float prod = xm * ym;
#pragma unroll
  for (int off = 1; off < 64; off <<= 1) prod += __shfl_xor(prod, off, 64);
  if ((tid & 63) == 0) s_r[tid >> 6] = prod;
  __syncthreads();
  if (tid == 0) {
    const float s = s_r[0] + s_r[1];
    out[b] = 1.f / (1.f + expf(-s));
  }
}

// ---------------------------------------------------------------------------
extern "C" void kernel_launch(void* const* d_in, const int* in_sizes, int n_in,
                              void* d_out, int out_size, void* d_ws,
                              size_t ws_size, hipStream_t stream) {
  (void)in_sizes; (void)n_in; (void)out_size; (void)ws_size;
  const int* user_indices = (const int*)d_in[0];
  const int* news_indices = (const int*)d_in[1];
  const int* news_user = (const int*)d_in[3];
  const int* user_news = (const int*)d_in[4];
  const int* title = (const int*)d_in[5];
  const float* user_emb_matrix = (const float*)d_in[6];
  const float* word_emb_matrix = (const float*)d_in[7];
  const float* conv_w = (const float*)d_in[8];
  const float* conv_b = (const float*)d_in[9];
  const float* dense_w = (const float*)d_in[10];
  const float* dense_b = (const float*)d_in[11];
  const float* user_weights = (const float*)d_in[12];
  const float* user_bias = (const float*)d_in[13];
  const float* item_weights = (const float*)d_in[14];
  const float* item_bias = (const float*)d_in[15];
  const float* last_w = (const float*)d_in[16];
  const float* last_b = (const float*)d_in[17];

  char* ws = (char*)d_ws;
  __hip_bfloat16* flat = (__hip_bfloat16*)ws;                 // 16768*992*2 = 33,267,712
  ws += (size_t)CHUNK_MAX * FLAT * 2;
  __hip_bfloat16* news_cnn = (__hip_bfloat16*)ws;             // 50000*128*2 = 12,800,000
  ws += (size_t)NNEWS * DIM * 2;
  __hip_bfloat16* user_path = (__hip_bfloat16*)ws;            // 63488*128*2 = 16,252,928
  ws += (size_t)NJOBS * DIM * 2;
  float* news_emb = (float*)ws;                               // 1,048,576
  ws += (size_t)BSZ * DIM * 4;
  float* user_emb = (float*)ws;                               // 1,048,576
  ws += (size_t)BSZ * DIM * 4;
  __hip_bfloat16* dwt = (__hip_bfloat16*)ws;                  // 253,952
  ws += (size_t)FLAT * DIM * 2;
  __hip_bfloat16* iwt = (__hip_bfloat16*)ws;                  // 32,768
  ws += (size_t)DIM * DIM * 2;
  __hip_bfloat16* uwt = (__hip_bfloat16*)ws;                  // 32,768
  float* out = (float*)d_out;

  k_prep<<<(FLAT * DIM + 2 * DIM * DIM + 255) / 256, 256, 0, stream>>>(
      dense_w, item_weights, user_weights, dwt, iwt, uwt);

  const int cb[3] = {0, 16768, 33536};
  const int cr[3] = {16768, 16768, 16464};
  for (int c = 0; c < 3; ++c) {
    k_conv<<<cr[c] / 8, 256, 0, stream>>>(title, word_emb_matrix, conv_w,
                                          conv_b, flat, cb[c], cr[c]);
    k_dense<<<(cr[c] + 63) / 64, 256, 0, stream>>>(
        flat, dwt, dense_b, iwt, item_bias, news_cnn, cb[c], cr[c]);
  }
  k_user<<<NJOBS / 32, 256, 0, stream>>>(
      user_indices, news_indices, news_user, user_emb_matrix, uwt, user_bias,
      user_path);
  k_route<<<2 * BSZ, 128, 0, stream>>>(news_cnn, user_path, user_indices,
                                       news_indices, user_news, news_emb,
                                       user_emb);
  k_score<<<BSZ, 128, 0, stream>>>(user_emb, news_emb, last_w, last_b, out);
}

// Round 6
// 295.360 us; speedup vs baseline: 4.8413x; 1.2222x over previous
//
#include <hip/hip_runtime.h>
#include <hip/hip_bf16.h>
#include <math.h>

#define BSZ 2048
#define NNEWS 50000
#define U_NB 30
#define N_NB 30
#define TITLE_LEN 10
#define W_EMB 50
#define DIM 128
#define ROUTIT 4
#define FLAT 992          // 8ch * 4 * 31
#define NJOBS (BSZ * 31)  // 63488 user-path rows

typedef __attribute__((ext_vector_type(8))) short bf16x8;
typedef short bf16x8u __attribute__((ext_vector_type(8), aligned(2)));
typedef __attribute__((ext_vector_type(4))) float f32x4;

__device__ __forceinline__ short f2bf(float v) {
  __hip_bfloat16 h = __float2bfloat16(v);
  return *reinterpret_cast<short*>(&h);
}

// ---------------------------------------------------------------------------
// Prep: transpose + bf16-convert the three GEMM weight matrices.
// ---------------------------------------------------------------------------
__global__ __launch_bounds__(256) void k_prep(
    const float* __restrict__ dw, const float* __restrict__ iw,
    const float* __restrict__ uw, __hip_bfloat16* __restrict__ dwt,
    __hip_bfloat16* __restrict__ iwt, __hip_bfloat16* __restrict__ uwt) {
  const int idx = blockIdx.x * 256 + threadIdx.x;
  if (idx < FLAT * DIM) {
    const int o = idx & 127, k = idx >> 7;
    dwt[o * FLAT + k] = __float2bfloat16(dw[idx]);
  } else if (idx < FLAT * DIM + DIM * DIM) {
    const int j = idx - FLAT * DIM;
    const int o = j & 127, k = j >> 7;
    iwt[o * DIM + k] = __float2bfloat16(iw[j]);
  } else if (idx < FLAT * DIM + 2 * DIM * DIM) {
    const int j = idx - FLAT * DIM - DIM * DIM;
    const int o = j & 127, k = j >> 7;
    uwt[o * DIM + k] = __float2bfloat16(uw[j]);
  }
}

// ---------------------------------------------------------------------------
// k_conv (MFMA formulation): 8 titles/block, 256 thr (4 waves, 2 titles/wave).
// Per conv-row r: A[(j)][k] = x[r + k/32][j + (k&31)], K=64 with taps 20..31
// zeroed IN B (weights), so A-frags are contiguous 8-elem x-row reads and
// garbage-times-zero is harmless (all LDS content is defined numbers).
// D: col=lane&15=channel (8 used), row=(lane>>4)*4+i = j.  Pool pairs
// (r=2h, 2h+1) via elementwise max of two D tiles, +bias, relu -> s_f.
// ---------------------------------------------------------------------------
__global__ __launch_bounds__(256, 4) void k_conv(
    const int* __restrict__ title, const float* __restrict__ word_emb,
    const float* __restrict__ conv_w, const float* __restrict__ conv_b,
    __hip_bfloat16* __restrict__ flat) {
  __shared__ int s_words[80];
  __shared__ __align__(16) __hip_bfloat16 s_x[8][TITLE_LEN][56];  // 8,960 B
  __shared__ __align__(16) __hip_bfloat16 s_f[8][992];            // 15,872 B

  const int tid = threadIdx.x;
  const int wv = tid >> 6, lane = tid & 63;
  const int base = blockIdx.x * 8;  // 6250 blocks * 8 = 50000 exactly

  if (tid < 80) s_words[tid] = title[base * TITLE_LEN + tid];

  // B-frags (weights), built once: lane holds channel c=lane&15, k-slice gkb.
  const int c = lane & 15, gkb = lane >> 4, fr = lane & 15;
  bf16x8 b0, b1;
#pragma unroll
  for (int i = 0; i < 8; ++i) {
    const int k = gkb * 8 + i;
    float v0 = 0.f, v1 = 0.f;
    if (c < 8 && k < 20) {
      v0 = conv_w[c * 40 + k];
      v1 = conv_w[c * 40 + 20 + k];
    }
    b0[i] = f2bf(v0);
    b1[i] = f2bf(v1);
  }
  const float cbias = (c < 8) ? conv_b[c] : 0.f;
  __syncthreads();

  // bulk embedding gather -> bf16 rows padded to 56 (cols 50..55 zero)
  {
    const float2* we2 = reinterpret_cast<const float2*>(word_emb);
    __hip_bfloat16* xb = &s_x[0][0][0];
#pragma unroll
    for (int i = 0; i < 9; ++i) {
      const int u = tid + i * 256;
      if (u < 2240) {  // 80 rows x 28 float2-cols
        const int row = u / 28, cc = u - row * 28;
        float2 v = make_float2(0.f, 0.f);
        if (cc < 25) v = we2[(long long)s_words[row] * 25 + cc];
        xb[row * 56 + cc * 2] = __float2bfloat16(v.x);
        xb[row * 56 + cc * 2 + 1] = __float2bfloat16(v.y);
      }
    }
  }
  __syncthreads();

  // conv via MFMA, rolling 3-frag window over x rows
#pragma unroll 1
  for (int tt = 0; tt < 2; ++tt) {
    const int t = wv * 2 + tt;
    const __hip_bfloat16* xb = &s_x[t][0][0];
#pragma unroll
    for (int jh = 0; jh < 2; ++jh) {
      const int joff = jh * 16 + fr + gkb * 8;
      bf16x8 fprev = (bf16x8) * reinterpret_cast<const bf16x8u*>(&xb[joff]);
#pragma unroll
      for (int h = 0; h < 4; ++h) {
        const bf16x8 fmid =
            (bf16x8) * reinterpret_cast<const bf16x8u*>(&xb[(2 * h + 1) * 56 + joff]);
        const bf16x8 fnext =
            (bf16x8) * reinterpret_cast<const bf16x8u*>(&xb[(2 * h + 2) * 56 + joff]);
        f32x4 d0 = (f32x4){0.f, 0.f, 0.f, 0.f};
        f32x4 d1 = (f32x4){0.f, 0.f, 0.f, 0.f};
        d0 = __builtin_amdgcn_mfma_f32_16x16x32_bf16(fprev, b0, d0, 0, 0, 0);
        d0 = __builtin_amdgcn_mfma_f32_16x16x32_bf16(fmid, b1, d0, 0, 0, 0);
        d1 = __builtin_amdgcn_mfma_f32_16x16x32_bf16(fmid, b0, d1, 0, 0, 0);
        d1 = __builtin_amdgcn_mfma_f32_16x16x32_bf16(fnext, b1, d1, 0, 0, 0);
        if (c < 8) {
#pragma unroll
          for (int i = 0; i < 4; ++i) {
            const int j = jh * 16 + gkb * 4 + i;
            if (j < 31) {
              const float v = fmaxf(fmaxf(d0[i], d1[i]) + cbias, 0.f);
              s_f[t][c * 124 + h * 31 + j] = __float2bfloat16(v);
            }
          }
        }
        fprev = fnext;
      }
    }
  }
  __syncthreads();

  // coalesced flush: 8*992 bf16 = 992 uint4
  {
    const uint4* sf4 = reinterpret_cast<const uint4*>(&s_f[0][0]);
    uint4* g4 = reinterpret_cast<uint4*>(&flat[(size_t)base * FLAT]);
#pragma unroll
    for (int i = 0; i < 4; ++i) {
      const int u = tid + i * 256;
      if (u < 992) g4[u] = sf4[u];
    }
  }
}

// ---------------------------------------------------------------------------
// k_dense: [64 x 992]@[992 x 128] (relu,+b) then @[128 x 128] (relu,+b).
// Double-buffered LDS + register prefetch, BK=64. Single launch, 782 blocks.
// ---------------------------------------------------------------------------
__global__ __launch_bounds__(256, 2) void k_dense(
    const __hip_bfloat16* __restrict__ flat,
    const __hip_bfloat16* __restrict__ dwt, const float* __restrict__ dense_b,
    const __hip_bfloat16* __restrict__ iwt, const float* __restrict__ item_b,
    __hip_bfloat16* __restrict__ out, int nrows) {
  __shared__ __align__(16) char lds[55296];
  __hip_bfloat16* sA0 = (__hip_bfloat16*)lds;
  __hip_bfloat16* sA1 = (__hip_bfloat16*)(lds + 9216);
  __hip_bfloat16* sB0 = (__hip_bfloat16*)(lds + 18432);
  __hip_bfloat16* sB1 = (__hip_bfloat16*)(lds + 36864);
  __hip_bfloat16* s_c1 = (__hip_bfloat16*)lds;
  __hip_bfloat16* sBI = (__hip_bfloat16*)(lds + 18432);

  const int tid = threadIdx.x;
  const int wv = tid >> 6, lane = tid & 63;
  const int fr = lane & 15, gk = lane >> 4;
  const int lrow0 = min((int)blockIdx.x * 64, nrows - 64);

  uint4 pA[2], pB[4];
#define LD_A(KS)                                                             \
  _Pragma("unroll") for (int q = 0; q < 2; ++q) {                            \
    const int uu = tid + q * 256;                                            \
    const int row = uu >> 3, c8 = uu & 7;                                    \
    const int kof = min((KS) * 64 + c8 * 8, FLAT - 8);                       \
    pA[q] = *reinterpret_cast<const uint4*>(                                 \
        &flat[(size_t)(lrow0 + row) * FLAT + kof]);                          \
  }
#define ST_A(BUF)                                                            \
  _Pragma("unroll") for (int q = 0; q < 2; ++q) {                            \
    const int uu = tid + q * 256;                                            \
    *reinterpret_cast<uint4*>(&(BUF)[(uu >> 3) * 72 + (uu & 7) * 8]) = pA[q]; \
  }
#define LD_B(KS)                                                             \
  _Pragma("unroll") for (int q = 0; q < 4; ++q) {                            \
    const int uu = tid + q * 256;                                            \
    const int o = uu >> 3, c8 = uu & 7;                                      \
    const int kof = min((KS) * 64 + c8 * 8, FLAT - 8);                       \
    pB[q] = *reinterpret_cast<const uint4*>(&dwt[o * FLAT + kof]);           \
  }
#define ST_B(BUF)                                                            \
  _Pragma("unroll") for (int q = 0; q < 4; ++q) {                            \
    const int uu = tid + q * 256;                                            \
    *reinterpret_cast<uint4*>(&(BUF)[(uu >> 3) * 72 + (uu & 7) * 8]) = pB[q]; \
  }

  LD_A(0);
  LD_B(0);
  ST_A(sA0);
  ST_B(sB0);
  LD_A(1);
  LD_B(1);
  __syncthreads();

  f32x4 acc[4][2];
#pragma unroll
  for (int m = 0; m < 4; ++m)
#pragma unroll
    for (int n = 0; n < 2; ++n) acc[m][n] = (f32x4){0.f, 0.f, 0.f, 0.f};

  for (int ks = 0; ks < 16; ++ks) {
    const __hip_bfloat16* cA = (ks & 1) ? sA1 : sA0;
    const __hip_bfloat16* cB = (ks & 1) ? sB1 : sB0;
    const int nkk = (ks == 15) ? 1 : 2;
#pragma unroll
    for (int kk = 0; kk < 2; ++kk) {
      if (kk < nkk) {
        bf16x8 af[4], bfr[2];
#pragma unroll
        for (int m = 0; m < 4; ++m)
          af[m] = *reinterpret_cast<const bf16x8*>(
              &cA[(m * 16 + fr) * 72 + kk * 32 + gk * 8]);
#pragma unroll
        for (int n = 0; n < 2; ++n)
          bfr[n] = *reinterpret_cast<const bf16x8*>(
              &cB[(wv * 32 + n * 16 + fr) * 72 + kk * 32 + gk * 8]);
#pragma unroll
        for (int m = 0; m < 4; ++m)
#pragma unroll
          for (int n = 0; n < 2; ++n)
            acc[m][n] = __builtin_amdgcn_mfma_f32_16x16x32_bf16(
                af[m], bfr[n], acc[m][n], 0, 0, 0);
      }
    }
    if (ks < 15) {
      if (ks & 1) {
        ST_A(sA0);
        ST_B(sB0);
      } else {
        ST_A(sA1);
        ST_B(sB1);
      }
    }
    if (ks < 14) {
      LD_A(ks + 2);
      LD_B(ks + 2);
    }
    __syncthreads();
  }
#undef LD_A
#undef ST_A
#undef LD_B
#undef ST_B

  // dense epilogue -> s_c1[64][136]; stage item weights
#pragma unroll
  for (int n = 0; n < 2; ++n) {
    const int col = wv * 32 + n * 16 + fr;
    const float bbf = dense_b[col];
#pragma unroll
    for (int m = 0; m < 4; ++m)
#pragma unroll
      for (int r = 0; r < 4; ++r) {
        const int row = m * 16 + gk * 4 + r;
        s_c1[row * 136 + col] = __float2bfloat16(fmaxf(acc[m][n][r] + bbf, 0.f));
      }
  }
#pragma unroll
  for (int q = 0; q < 8; ++q) {
    const int uu = tid + q * 256;
    const int o = uu >> 4, cc = uu & 15;
    *reinterpret_cast<uint4*>(&sBI[o * 136 + cc * 8]) =
        *reinterpret_cast<const uint4*>(&iwt[o * DIM + cc * 8]);
  }
  __syncthreads();

  f32x4 acc2[4][2];
#pragma unroll
  for (int m = 0; m < 4; ++m)
#pragma unroll
    for (int n = 0; n < 2; ++n) acc2[m][n] = (f32x4){0.f, 0.f, 0.f, 0.f};
#pragma unroll
  for (int kk = 0; kk < 4; ++kk) {
    bf16x8 af[4], bfr[2];
#pragma unroll
    for (int m = 0; m < 4; ++m)
      af[m] = *reinterpret_cast<const bf16x8*>(
          &s_c1[(m * 16 + fr) * 136 + kk * 32 + gk * 8]);
#pragma unroll
    for (int n = 0; n < 2; ++n)
      bfr[n] = *reinterpret_cast<const bf16x8*>(
          &sBI[(wv * 32 + n * 16 + fr) * 136 + kk * 32 + gk * 8]);
#pragma unroll
    for (int m = 0; m < 4; ++m)
#pragma unroll
      for (int n = 0; n < 2; ++n)
        acc2[m][n] = __builtin_amdgcn_mfma_f32_16x16x32_bf16(
            af[m], bfr[n], acc2[m][n], 0, 0, 0);
  }

#pragma unroll
  for (int n = 0; n < 2; ++n) {
    const int col = wv * 32 + n * 16 + fr;
    const float bbf = item_b[col];
#pragma unroll
    for (int m = 0; m < 4; ++m)
#pragma unroll
      for (int r = 0; r < 4; ++r) {
        const int row = m * 16 + gk * 4 + r;
        out[(size_t)(lrow0 + row) * DIM + col] =
            __float2bfloat16(fmaxf(acc2[m][n][r] + bbf, 0.f));
      }
  }
}

// ---------------------------------------------------------------------------
// k_user: gather user_emb rows (bf16) then MFMA x user_wt (+bias, relu).
// ---------------------------------------------------------------------------
__global__ __launch_bounds__(256) void k_user(
    const int* __restrict__ user_indices, const int* __restrict__ news_indices,
    const int* __restrict__ news_user, const float* __restrict__ user_emb,
    const __hip_bfloat16* __restrict__ uwt, const float* __restrict__ user_b,
    __hip_bfloat16* __restrict__ out) {
  __shared__ __align__(16) __hip_bfloat16 s_e[32][136];
  __shared__ __align__(16) __hip_bfloat16 s_bt[128][40];
  __shared__ int s_uid[32];
  const int tid = threadIdx.x;
  const int wave = tid >> 6, lane = tid & 63;
  const int base = blockIdx.x * 32;

  if (tid < 32) {
    const int r = base + tid;
    int uid;
    if (r < BSZ) {
      uid = user_indices[r];
    } else {
      const int j = r - BSZ;
      const int b = j / U_NB, k = j - b * U_NB;
      uid = news_user[(long long)news_indices[b] * U_NB + k];
    }
    s_uid[tid] = uid;
  }
  __syncthreads();
#pragma unroll
  for (int i = 0; i < 4; ++i) {
    const int u = tid + i * 256;
    const int row = u >> 5, d4 = u & 31;
    const float4 v = *reinterpret_cast<const float4*>(
        &user_emb[(long long)s_uid[row] * DIM + d4 * 4]);
    __hip_bfloat16* p = &s_e[row][d4 * 4];
    p[0] = __float2bfloat16(v.x);
    p[1] = __float2bfloat16(v.y);
    p[2] = __float2bfloat16(v.z);
    p[3] = __float2bfloat16(v.w);
  }

  const int fr = lane & 15, gk = lane >> 4;
  f32x4 acc[2][2];
#pragma unroll
  for (int m = 0; m < 2; ++m)
#pragma unroll
    for (int n = 0; n < 2; ++n) acc[m][n] = (f32x4){0.f, 0.f, 0.f, 0.f};

  for (int ks = 0; ks < 4; ++ks) {
    __syncthreads();
#pragma unroll
    for (int q = 0; q < 2; ++q) {
      const int uu = tid * 2 + q;
      const int o = uu >> 2, koff = (uu & 3) * 8;
      *reinterpret_cast<uint4*>(&s_bt[o][koff]) =
          *reinterpret_cast<const uint4*>(&uwt[o * DIM + ks * 32 + koff]);
    }
    __syncthreads();
    bf16x8 af[2], bfr[2];
#pragma unroll
    for (int m = 0; m < 2; ++m)
      af[m] = *reinterpret_cast<const bf16x8*>(
          &s_e[m * 16 + fr][ks * 32 + gk * 8]);
#pragma unroll
    for (int n = 0; n < 2; ++n)
      bfr[n] = *reinterpret_cast<const bf16x8*>(
          &s_bt[wave * 32 + n * 16 + fr][gk * 8]);
#pragma unroll
    for (int m = 0; m < 2; ++m)
#pragma unroll
      for (int n = 0; n < 2; ++n)
        acc[m][n] =
            __builtin_amdgcn_mfma_f32_16x16x32_bf16(af[m], bfr[n], acc[m][n], 0, 0, 0);
  }

#pragma unroll
  for (int n = 0; n < 2; ++n) {
    const int col = wave * 32 + n * 16 + fr;
    const float bb = user_b[col];
#pragma unroll
    for (int m = 0; m < 2; ++m)
#pragma unroll
      for (int r = 0; r < 4; ++r) {
        const int row = m * 16 + gk * 4 + r;
        out[(size_t)(base + row) * DIM + col] =
            __float2bfloat16(fmaxf(acc[m][n][r] + bb, 0.f));
      }
  }
}

// ---------------------------------------------------------------------------
// k_route: capsule routing on bf16 inputs.
// ---------------------------------------------------------------------------
__device__ __forceinline__ float gsum16(float v) {
  v += __shfl_xor(v, 1, 16);
  v += __shfl_xor(v, 2, 16);
  v += __shfl_xor(v, 4, 16);
  v += __shfl_xor(v, 8, 16);
  return v;
}

__global__ __launch_bounds__(128) void k_route(
    const __hip_bfloat16* __restrict__ news_cnn,
    const __hip_bfloat16* __restrict__ user_path,
    const int* __restrict__ user_indices, const int* __restrict__ news_indices,
    const int* __restrict__ user_news, float* __restrict__ news_out,
    float* __restrict__ user_out) {
  const int j = blockIdx.x;
  const int tid = threadIdx.x;
  const bool is_news = (j < BSZ);
  const int b = is_news ? j : j - BSZ;
  __shared__ int s_nid[N_NB];
  if (!is_news && tid < N_NB)
    s_nid[tid] = user_news[(long long)user_indices[b] * N_NB + tid];
  __syncthreads();

  const __hip_bfloat16* xrow =
      is_news ? news_cnn + (long long)news_indices[b] * DIM
              : user_path + (long long)b * DIM;
  const int c = tid >> 4;

  float x = __bfloat162float(xrow[tid]);
  x = x / (sqrtf(gsum16(x * x)) + 1e-9f);

  float z[30];
#pragma unroll
  for (int k = 0; k < 30; ++k) {
    const __hip_bfloat16* zr =
        is_news ? user_path + (long long)(BSZ + b * 30 + k) * DIM
                : news_cnn + (long long)s_nid[k] * DIM;
    const float v = __bfloat162float(zr[tid]);
    z[k] = v / (sqrtf(gsum16(v * v)) + 1e-9f);
  }

  float u = x;
  __shared__ float s_p[30][8];
  for (int it = 0; it < ROUTIT; ++it) {
#pragma unroll
    for (int k = 0; k < 30; ++k) {
      const float dot = gsum16(z[k] * u);
      if ((tid & 15) == 0) s_p[k][c] = dot;
    }
    __syncthreads();
    if (tid < 30) {
      float m = -1e30f;
#pragma unroll
      for (int cc = 0; cc < 8; ++cc) m = fmaxf(m, s_p[tid][cc]);
      float s = 0.f, e[8];
#pragma unroll
      for (int cc = 0; cc < 8; ++cc) {
        e[cc] = expf(s_p[tid][cc] - m);
        s += e[cc];
      }
#pragma unroll
      for (int cc = 0; cc < 8; ++cc) s_p[tid][cc] = e[cc] / s;
    }
    __syncthreads();
    float agg = x;
#pragma unroll
    for (int k = 0; k < 30; ++k) agg += s_p[k][c] * z[k];
    u = agg / (sqrtf(gsum16(agg * agg)) + 1e-9f);
    __syncthreads();
  }
  (is_news ? news_out : user_out)[(long long)b * DIM + tid] = u;
}

// ---------------------------------------------------------------------------
// k_score: score = sum((u@W+b) * (n@W+b)); sigmoid.
// ---------------------------------------------------------------------------
__global__ __launch_bounds__(128) void k_score(
    const float* __restrict__ user_e, const float* __restrict__ news_e,
    const float* __restrict__ last_w, const float* __restrict__ last_b,
    float* __restrict__ out) {
  const int b = blockIdx.x, tid = threadIdx.x;
  __shared__ float s_u[DIM], s_n[DIM];
  __shared__ float s_r[2];
  s_u[tid] = user_e[(long long)b * DIM + tid];
  s_n[tid] = news_e[(long long)b * DIM + tid];
  __syncthreads();
  float xm = last_b[tid], ym = last_b[tid];
  for (int k = 0; k < DIM; k += 4) {
#pragma unroll
    for (int i = 0; i < 4; ++i) {
      const float w = last_w[(k + i) * DIM + tid];
      xm += s_u[k + i] * w;
      ym += s_n[k + i] * w;
    }
  }
  float prod = xm * ym;
#pragma unroll
  for (int off = 1; off < 64; off <<= 1) prod += __shfl_xor(prod, off, 64);
  if ((tid & 63) == 0) s_r[tid >> 6] = prod;
  __syncthreads();
  if (tid == 0) {
    const float s = s_r[0] + s_r[1];
    out[b] = 1.f / (1.f + expf(-s));
  }
}

// ---------------------------------------------------------------------------
extern "C" void kernel_launch(void* const* d_in, const int* in_sizes, int n_in,
                              void* d_out, int out_size, void* d_ws,
                              size_t ws_size, hipStream_t stream) {
  (void)in_sizes; (void)n_in; (void)out_size; (void)ws_size;
  const int* user_indices = (const int*)d_in[0];
  const int* news_indices = (const int*)d_in[1];
  const int* news_user = (const int*)d_in[3];
  const int* user_news = (const int*)d_in[4];
  const int* title = (const int*)d_in[5];
  const float* user_emb_matrix = (const float*)d_in[6];
  const float* word_emb_matrix = (const float*)d_in[7];
  const float* conv_w = (const float*)d_in[8];
  const float* conv_b = (const float*)d_in[9];
  const float* dense_w = (const float*)d_in[10];
  const float* dense_b = (const float*)d_in[11];
  const float* user_weights = (const float*)d_in[12];
  const float* user_bias = (const float*)d_in[13];
  const float* item_weights = (const float*)d_in[14];
  const float* item_bias = (const float*)d_in[15];
  const float* last_w = (const float*)d_in[16];
  const float* last_b = (const float*)d_in[17];

  char* ws = (char*)d_ws;
  __hip_bfloat16* flat = (__hip_bfloat16*)ws;                 // 50000*992*2 = 99,200,000
  ws += (size_t)NNEWS * FLAT * 2;
  __hip_bfloat16* news_cnn = (__hip_bfloat16*)ws;             // 12,800,000
  ws += (size_t)NNEWS * DIM * 2;
  __hip_bfloat16* user_path = (__hip_bfloat16*)ws;            // 16,252,928
  ws += (size_t)NJOBS * DIM * 2;
  float* news_emb = (float*)ws;                               // 1,048,576
  ws += (size_t)BSZ * DIM * 4;
  float* user_emb = (float*)ws;                               // 1,048,576
  ws += (size_t)BSZ * DIM * 4;
  __hip_bfloat16* dwt = (__hip_bfloat16*)ws;                  // 253,952
  ws += (size_t)FLAT * DIM * 2;
  __hip_bfloat16* iwt = (__hip_bfloat16*)ws;                  // 32,768
  ws += (size_t)DIM * DIM * 2;
  __hip_bfloat16* uwt = (__hip_bfloat16*)ws;                  // 32,768
  float* out = (float*)d_out;

  k_prep<<<(FLAT * DIM + 2 * DIM * DIM + 255) / 256, 256, 0, stream>>>(
      dense_w, item_weights, user_weights, dwt, iwt, uwt);
  k_conv<<<NNEWS / 8, 256, 0, stream>>>(title, word_emb_matrix, conv_w,
                                        conv_b, flat);
  k_dense<<<(NNEWS + 63) / 64, 256, 0, stream>>>(
      flat, dwt, dense_b, iwt, item_bias, news_cnn, NNEWS);
  k_user<<<NJOBS / 32, 256, 0, stream>>>(
      user_indices, news_indices, news_user, user_emb_matrix, uwt, user_bias,
      user_path);
  k_route<<<2 * BSZ, 128, 0, stream>>>(news_cnn, user_path, user_indices,
                                       news_indices, user_news, news_emb,
                                       user_emb);
  k_score<<<BSZ, 128, 0, stream>>>(user_emb, news_emb, last_w, last_b, out);
}

// Round 7
// 238.329 us; speedup vs baseline: 5.9998x; 1.2393x over previous
//
#include <hip/hip_runtime.h>
#include <hip/hip_bf16.h>
#include <math.h>

#define BSZ 2048
#define NNEWS 50000
#define U_NB 30
#define N_NB 30
#define TITLE_LEN 10
#define W_EMB 50
#define DIM 128
#define ROUTIT 4
#define FLAT2 1024        // permuted, zero-padded K (was 992)
#define NJOBS (BSZ * 31)  // 63488 user-path rows

typedef __attribute__((ext_vector_type(8))) short bf16x8;
typedef __attribute__((ext_vector_type(4))) float f32x4;

__device__ __forceinline__ ushort bfbits(float v) {
  __hip_bfloat16 h = __float2bfloat16(v);
  ushort u;
  __builtin_memcpy(&u, &h, 2);
  return u;
}

// Build a bf16x8 A-frag = x[s..s+8) from a 16B-aligned 64-elem bf16 row.
// 2 aligned ds_read_b128 + branch-free cndmask/funnel shift.
__device__ __forceinline__ bf16x8 bfrag(const ushort* row, int s) {
  const char* p = reinterpret_cast<const char*>(row) + ((s * 2) & ~15);
  const uint4 lo = *reinterpret_cast<const uint4*>(p);
  const uint4 hi = *reinterpret_cast<const uint4*>(p + 16);
  const uint d0 = lo.x, d1 = lo.y, d2 = lo.z, d3 = lo.w;
  const uint d4 = hi.x, d5 = hi.y, d6 = hi.z, d7 = hi.w;
  const bool q2 = (s & 4) != 0;
  const uint e0 = q2 ? d2 : d0, e1 = q2 ? d3 : d1, e2 = q2 ? d4 : d2;
  const uint e3 = q2 ? d5 : d3, e4 = q2 ? d6 : d4, e5 = q2 ? d7 : d5;
  const bool q1 = (s & 2) != 0;
  const uint f0 = q1 ? e1 : e0, f1 = q1 ? e2 : e1, f2 = q1 ? e3 : e2;
  const uint f3 = q1 ? e4 : e3, f4 = q1 ? e5 : e4;
  const bool r1 = (s & 1) != 0;
  uint g[4];
  g[0] = r1 ? ((f0 >> 16) | (f1 << 16)) : f0;
  g[1] = r1 ? ((f1 >> 16) | (f2 << 16)) : f1;
  g[2] = r1 ? ((f2 >> 16) | (f3 << 16)) : f2;
  g[3] = r1 ? ((f3 >> 16) | (f4 << 16)) : f3;
  bf16x8 r;
  __builtin_memcpy(&r, g, 16);
  return r;
}

// ---------------------------------------------------------------------------
// k_prep: build dwt' (permuted zero-padded K=1024) + transposed iwt/uwt.
// k2 = (h*64 + jh*32 + gk*8 + c)*4 + i ; j = jh*16 + gk*4 + i (j==31 -> 0)
// ---------------------------------------------------------------------------
__global__ __launch_bounds__(256) void k_prep(
    const float* __restrict__ dw, const float* __restrict__ iw,
    const float* __restrict__ uw, __hip_bfloat16* __restrict__ dwt,
    __hip_bfloat16* __restrict__ iwt, __hip_bfloat16* __restrict__ uwt) {
  const int idx = blockIdx.x * 256 + threadIdx.x;
  if (idx < DIM * FLAT2) {
    const int col = idx & 127, k2 = idx >> 7;
    const int i = k2 & 3, X = k2 >> 2;
    const int c = X & 7, gkq = (X >> 3) & 3, jhq = (X >> 5) & 1, h = X >> 6;
    const int j = jhq * 16 + gkq * 4 + i;
    const float v = (j < 31) ? dw[(c * 124 + h * 31 + j) * 128 + col] : 0.f;
    dwt[col * FLAT2 + k2] = __float2bfloat16(v);
  } else if (idx < DIM * FLAT2 + DIM * DIM) {
    const int j = idx - DIM * FLAT2;
    const int o = j & 127, k = j >> 7;
    iwt[o * DIM + k] = __float2bfloat16(iw[j]);
  } else if (idx < DIM * FLAT2 + 2 * DIM * DIM) {
    const int j = idx - DIM * FLAT2 - DIM * DIM;
    const int o = j & 127, k = j >> 7;
    uwt[o * DIM + k] = __float2bfloat16(uw[j]);
  }
}

// ---------------------------------------------------------------------------
// k_conv: 8 titles/block, 256 thr (4 waves, 2 titles each). MFMA Toeplitz
// conv, aligned-b128 frag builds, conflict-free b64 epilogue writes into the
// permuted flat' layout, coalesced uint4 flush.
// ---------------------------------------------------------------------------
__global__ __launch_bounds__(256, 4) void k_conv(
    const int* __restrict__ title, const float* __restrict__ word_emb,
    const float* __restrict__ conv_w, const float* __restrict__ conv_b,
    __hip_bfloat16* __restrict__ flat) {
  __shared__ int s_words[80];
  __shared__ __align__(16) ushort s_x[80 * 64];   // 10,240 B (rows padded to 64)
  __shared__ __align__(16) ushort s_f[8 * 1024];  // 16,384 B (flat' layout)

  const int tid = threadIdx.x;
  const int wv = tid >> 6, lane = tid & 63;
  const int base = blockIdx.x * 8;  // 6250 * 8 = 50000 exactly
  const int c = lane & 15, gk = lane >> 4;

  // B-frags (weights) once; taps >=20 zeroed in B
  bf16x8 b0, b1;
#pragma unroll
  for (int i = 0; i < 8; ++i) {
    const int k = gk * 8 + i;
    float v0 = 0.f, v1 = 0.f;
    if (c < 8 && k < 20) {
      v0 = conv_w[c * 40 + k];
      v1 = conv_w[c * 40 + 20 + k];
    }
    b0[i] = (short)bfbits(v0);
    b1[i] = (short)bfbits(v1);
  }
  const float cbias = (c < 8) ? conv_b[c] : 0.f;

  if (tid < 80) s_words[tid] = title[base * TITLE_LEN + tid];
  __syncthreads();

  // gather: 80 rows x 64 bf16 (elems 50..63 zero), uint4 LDS writes
  {
    const float2* we2 = reinterpret_cast<const float2*>(word_emb);
#pragma unroll
    for (int i = 0; i < 3; ++i) {
      const int u = tid + i * 256;
      if (u < 640) {
        const int row = u >> 3, slot = u & 7;
        ushort o[8];
#pragma unroll
        for (int p = 0; p < 4; ++p) {
          const int c2 = slot * 4 + p;
          float2 v = make_float2(0.f, 0.f);
          if (c2 < 25) v = we2[(long long)s_words[row] * 25 + c2];
          o[2 * p] = bfbits(v.x);
          o[2 * p + 1] = bfbits(v.y);
        }
        *reinterpret_cast<uint4*>(&s_x[row * 64 + slot * 8]) =
            *reinterpret_cast<const uint4*>(o);
      }
    }
  }
  __syncthreads();

  // conv via MFMA, rolling 3-frag window
#pragma unroll 1
  for (int tt = 0; tt < 2; ++tt) {
    const int t = wv * 2 + tt;
    const ushort* xb = &s_x[t * 640];  // 10 rows x 64
#pragma unroll
    for (int jh = 0; jh < 2; ++jh) {
      const int s = jh * 16 + (lane & 15) + gk * 8;
      bf16x8 fprev = bfrag(xb, s);  // row 0
#pragma unroll
      for (int h = 0; h < 4; ++h) {
        const bf16x8 fmid = bfrag(xb + (2 * h + 1) * 64, s);
        const bf16x8 fnext = bfrag(xb + (2 * h + 2) * 64, s);
        f32x4 d0 = (f32x4){0.f, 0.f, 0.f, 0.f};
        f32x4 d1 = (f32x4){0.f, 0.f, 0.f, 0.f};
        d0 = __builtin_amdgcn_mfma_f32_16x16x32_bf16(fprev, b0, d0, 0, 0, 0);
        d0 = __builtin_amdgcn_mfma_f32_16x16x32_bf16(fmid, b1, d0, 0, 0, 0);
        d1 = __builtin_amdgcn_mfma_f32_16x16x32_bf16(fmid, b0, d1, 0, 0, 0);
        d1 = __builtin_amdgcn_mfma_f32_16x16x32_bf16(fnext, b1, d1, 0, 0, 0);
        if (c < 8) {
          ushort w[4];
#pragma unroll
          for (int i2 = 0; i2 < 4; ++i2)
            w[i2] = bfbits(fmaxf(fmaxf(d0[i2], d1[i2]) + cbias, 0.f));
          // k2 = (h*64 + jh*32 + gk*8 + c)*4 + i2  -> aligned b64, 2-way max
          *reinterpret_cast<uint2*>(
              &s_f[t * 1024 + (h * 64 + jh * 32 + gk * 8 + c) * 4]) =
              *reinterpret_cast<const uint2*>(w);
        }
        fprev = fnext;
      }
    }
  }
  __syncthreads();

  // flush: 8 * 1024 bf16 = 1024 uint4, fully coalesced
  {
    const uint4* sf4 = reinterpret_cast<const uint4*>(s_f);
    uint4* g4 = reinterpret_cast<uint4*>(flat) + (size_t)base * 128;
#pragma unroll
    for (int i = 0; i < 4; ++i) g4[tid + i * 256] = sf4[tid + i * 256];
  }
}

// ---------------------------------------------------------------------------
// k_dense: [64 x 1024]@[1024 x 128] (+b, relu) then @[128 x 128] (+b, relu).
// A double-buffered in LDS (18.4 KB total); B read direct from L2 with
// 1-step register prefetch; item/c1 phases reuse the A region.
// ---------------------------------------------------------------------------
__global__ __launch_bounds__(256, 2) void k_dense(
    const __hip_bfloat16* __restrict__ flat,
    const __hip_bfloat16* __restrict__ dwt, const float* __restrict__ dense_b,
    const __hip_bfloat16* __restrict__ iwt, const float* __restrict__ item_b,
    __hip_bfloat16* __restrict__ out, int nrows) {
  __shared__ __align__(16) char lds[18432];
  ushort* A0 = (ushort*)lds;            // [64][72]
  ushort* A1 = (ushort*)(lds + 9216);   // [64][72]
  ushort* c1 = (ushort*)lds;            // [64][136] overlay after dense

  const int tid = threadIdx.x;
  const int wv = tid >> 6, lane = tid & 63;
  const int fr = lane & 15, gk = lane >> 4;
  const int lrow0 = min((int)blockIdx.x * 64, nrows - 64);
  const ushort* fl = (const ushort*)flat;
  const ushort* dwp = (const ushort*)dwt;

  uint4 pA[2];
#define LD_A(KS)                                                              \
  {                                                                           \
    _Pragma("unroll") for (int q = 0; q < 2; ++q) {                           \
      const int uu = tid + q * 256;                                           \
      pA[q] = *reinterpret_cast<const uint4*>(                                \
          &fl[(size_t)(lrow0 + (uu >> 3)) * FLAT2 + (KS) * 64 + (uu & 7) * 8]); \
    }                                                                         \
  }
#define ST_A(BUF)                                                             \
  {                                                                           \
    _Pragma("unroll") for (int q = 0; q < 2; ++q) {                           \
      const int uu = tid + q * 256;                                           \
      *reinterpret_cast<uint4*>(&(BUF)[(uu >> 3) * 72 + (uu & 7) * 8]) = pA[q]; \
    }                                                                         \
  }
#define LD_B(DST, KS)                                                         \
  {                                                                           \
    _Pragma("unroll") for (int nn = 0; nn < 2; ++nn)                          \
        _Pragma("unroll") for (int qq = 0; qq < 2; ++qq) {                    \
      (DST)[nn * 2 + qq] = *reinterpret_cast<const bf16x8*>(                  \
          &dwp[(wv * 32 + nn * 16 + fr) * FLAT2 + (KS) * 64 + qq * 32 +       \
               gk * 8]);                                                      \
    }                                                                         \
  }

  LD_A(0);
  ST_A(A0);
  LD_A(1);
  bf16x8 bA[4];
  LD_B(bA, 0);
  __syncthreads();

  f32x4 acc[4][2];
#pragma unroll
  for (int m = 0; m < 4; ++m)
#pragma unroll
    for (int n = 0; n < 2; ++n) acc[m][n] = (f32x4){0.f, 0.f, 0.f, 0.f};

  for (int ks = 0; ks < 16; ++ks) {
    const ushort* cA = (ks & 1) ? A1 : A0;
    bf16x8 bN[4];
    if (ks < 15) {
      LD_B(bN, ks + 1);
    } else {
#pragma unroll
      for (int z = 0; z < 4; ++z) bN[z] = bA[z];
    }
    bf16x8 af[2][4];
#pragma unroll
    for (int kk = 0; kk < 2; ++kk)
#pragma unroll
      for (int m = 0; m < 4; ++m)
        af[kk][m] = *reinterpret_cast<const bf16x8*>(
            &cA[(m * 16 + fr) * 72 + kk * 32 + gk * 8]);
#pragma unroll
    for (int kk = 0; kk < 2; ++kk)
#pragma unroll
      for (int m = 0; m < 4; ++m)
#pragma unroll
        for (int n = 0; n < 2; ++n)
          acc[m][n] = __builtin_amdgcn_mfma_f32_16x16x32_bf16(
              af[kk][m], bA[n * 2 + kk], acc[m][n], 0, 0, 0);
    if (ks < 15) {
      if (ks & 1) {
        ST_A(A0);
      } else {
        ST_A(A1);
      }
    }
    if (ks < 14) LD_A(ks + 2);
    __syncthreads();
#pragma unroll
    for (int z = 0; z < 4; ++z) bA[z] = bN[z];
  }
#undef LD_A
#undef ST_A
#undef LD_B

  // dense epilogue -> c1[64][136] (A buffers dead; post-loop barrier done)
#pragma unroll
  for (int n = 0; n < 2; ++n) {
    const int col = wv * 32 + n * 16 + fr;
    const float bb = dense_b[col];
#pragma unroll
    for (int m = 0; m < 4; ++m)
#pragma unroll
      for (int r = 0; r < 4; ++r)
        c1[(m * 16 + gk * 4 + r) * 136 + col] =
            bfbits(fmaxf(acc[m][n][r] + bb, 0.f));
  }
  __syncthreads();

  // item GEMM [64x128]@[128x128], B direct from L2
  const ushort* iwp = (const ushort*)iwt;
  f32x4 a2[4][2];
#pragma unroll
  for (int m = 0; m < 4; ++m)
#pragma unroll
    for (int n = 0; n < 2; ++n) a2[m][n] = (f32x4){0.f, 0.f, 0.f, 0.f};
#pragma unroll
  for (int kk = 0; kk < 4; ++kk) {
    bf16x8 af[4], bfr[2];
#pragma unroll
    for (int m = 0; m < 4; ++m)
      af[m] = *reinterpret_cast<const bf16x8*>(
          &c1[(m * 16 + fr) * 136 + kk * 32 + gk * 8]);
#pragma unroll
    for (int n = 0; n < 2; ++n)
      bfr[n] = *reinterpret_cast<const bf16x8*>(
          &iwp[(wv * 32 + n * 16 + fr) * DIM + kk * 32 + gk * 8]);
#pragma unroll
    for (int m = 0; m < 4; ++m)
#pragma unroll
      for (int n = 0; n < 2; ++n)
        a2[m][n] = __builtin_amdgcn_mfma_f32_16x16x32_bf16(af[m], bfr[n],
                                                           a2[m][n], 0, 0, 0);
  }

#pragma unroll
  for (int n = 0; n < 2; ++n) {
    const int col = wv * 32 + n * 16 + fr;
    const float bb = item_b[col];
#pragma unroll
    for (int m = 0; m < 4; ++m)
#pragma unroll
      for (int r = 0; r < 4; ++r) {
        const int row = m * 16 + gk * 4 + r;
        out[(size_t)(lrow0 + row) * DIM + col] =
            __float2bfloat16(fmaxf(a2[m][n][r] + bb, 0.f));
      }
  }
}

// ---------------------------------------------------------------------------
// k_user: gather user_emb rows -> bf16 LDS, MFMA x uwt (B direct from L2),
// 1 sync total.
// ---------------------------------------------------------------------------
__global__ __launch_bounds__(256) void k_user(
    const int* __restrict__ user_indices, const int* __restrict__ news_indices,
    const int* __restrict__ news_user, const float* __restrict__ user_emb,
    const __hip_bfloat16* __restrict__ uwt, const float* __restrict__ user_b,
    __hip_bfloat16* __restrict__ out) {
  __shared__ __align__(16) __hip_bfloat16 s_e[32][136];
  __shared__ int s_uid[32];
  const int tid = threadIdx.x;
  const int wave = tid >> 6, lane = tid & 63;
  const int base = blockIdx.x * 32;

  if (tid < 32) {
    const int r = base + tid;
    int uid;
    if (r < BSZ) {
      uid = user_indices[r];
    } else {
      const int j = r - BSZ;
      const int b = j / U_NB, k = j - b * U_NB;
      uid = news_user[(long long)news_indices[b] * U_NB + k];
    }
    s_uid[tid] = uid;
  }
  __syncthreads();
#pragma unroll
  for (int i = 0; i < 4; ++i) {
    const int u = tid + i * 256;
    const int row = u >> 5, d4 = u & 31;
    const float4 v = *reinterpret_cast<const float4*>(
        &user_emb[(long long)s_uid[row] * DIM + d4 * 4]);
    __hip_bfloat16* p = &s_e[row][d4 * 4];
    p[0] = __float2bfloat16(v.x);
    p[1] = __float2bfloat16(v.y);
    p[2] = __float2bfloat16(v.z);
    p[3] = __float2bfloat16(v.w);
  }
  __syncthreads();

  const int fr = lane & 15, gk = lane >> 4;
  const ushort* uwp = (const ushort*)uwt;
  f32x4 acc[2][2];
#pragma unroll
  for (int m = 0; m < 2; ++m)
#pragma unroll
    for (int n = 0; n < 2; ++n) acc[m][n] = (f32x4){0.f, 0.f, 0.f, 0.f};

#pragma unroll
  for (int ks = 0; ks < 4; ++ks) {
    bf16x8 af[2], bfr[2];
#pragma unroll
    for (int m = 0; m < 2; ++m)
      af[m] = *reinterpret_cast<const bf16x8*>(
          &s_e[m * 16 + fr][ks * 32 + gk * 8]);
#pragma unroll
    for (int n = 0; n < 2; ++n)
      bfr[n] = *reinterpret_cast<const bf16x8*>(
          &uwp[(wave * 32 + n * 16 + fr) * DIM + ks * 32 + gk * 8]);
#pragma unroll
    for (int m = 0; m < 2; ++m)
#pragma unroll
      for (int n = 0; n < 2; ++n)
        acc[m][n] = __builtin_amdgcn_mfma_f32_16x16x32_bf16(af[m], bfr[n],
                                                            acc[m][n], 0, 0, 0);
  }

#pragma unroll
  for (int n = 0; n < 2; ++n) {
    const int col = wave * 32 + n * 16 + fr;
    const float bb = user_b[col];
#pragma unroll
    for (int m = 0; m < 2; ++m)
#pragma unroll
      for (int r = 0; r < 4; ++r) {
        const int row = m * 16 + gk * 4 + r;
        out[(size_t)(base + row) * DIM + col] =
            __float2bfloat16(fmaxf(acc[m][n][r] + bb, 0.f));
      }
  }
}

// ---------------------------------------------------------------------------
// k_route: capsule routing on bf16 inputs (unchanged from R6).
// ---------------------------------------------------------------------------
__device__ __forceinline__ float gsum16(float v) {
  v += __shfl_xor(v, 1, 16);
  v += __shfl_xor(v, 2, 16);
  v += __shfl_xor(v, 4, 16);
  v += __shfl_xor(v, 8, 16);
  return v;
}

__global__ __launch_bounds__(128) void k_route(
    const __hip_bfloat16* __restrict__ news_cnn,
    const __hip_bfloat16* __restrict__ user_path,
    const int* __restrict__ user_indices, const int* __restrict__ news_indices,
    const int* __restrict__ user_news, float* __restrict__ news_out,
    float* __restrict__ user_out) {
  const int j = blockIdx.x;
  const int tid = threadIdx.x;
  const bool is_news = (j < BSZ);
  const int b = is_news ? j : j - BSZ;
  __shared__ int s_nid[N_NB];
  if (!is_news && tid < N_NB)
    s_nid[tid] = user_news[(long long)user_indices[b] * N_NB + tid];
  __syncthreads();

  const __hip_bfloat16* xrow =
      is_news ? news_cnn + (long long)news_indices[b] * DIM
              : user_path + (long long)b * DIM;
  const int c = tid >> 4;

  float x = __bfloat162float(xrow[tid]);
  x = x / (sqrtf(gsum16(x * x)) + 1e-9f);

  float z[30];
#pragma unroll
  for (int k = 0; k < 30; ++k) {
    const __hip_bfloat16* zr =
        is_news ? user_path + (long long)(BSZ + b * 30 + k) * DIM
                : news_cnn + (long long)s_nid[k] * DIM;
    const float v = __bfloat162float(zr[tid]);
    z[k] = v / (sqrtf(gsum16(v * v)) + 1e-9f);
  }

  float u = x;
  __shared__ float s_p[30][8];
  for (int it = 0; it < ROUTIT; ++it) {
#pragma unroll
    for (int k = 0; k < 30; ++k) {
      const float dot = gsum16(z[k] * u);
      if ((tid & 15) == 0) s_p[k][c] = dot;
    }
    __syncthreads();
    if (tid < 30) {
      float m = -1e30f;
#pragma unroll
      for (int cc = 0; cc < 8; ++cc) m = fmaxf(m, s_p[tid][cc]);
      float s = 0.f, e[8];
#pragma unroll
      for (int cc = 0; cc < 8; ++cc) {
        e[cc] = expf(s_p[tid][cc] - m);
        s += e[cc];
      }
#pragma unroll
      for (int cc = 0; cc < 8; ++cc) s_p[tid][cc] = e[cc] / s;
    }
    __syncthreads();
    float agg = x;
#pragma unroll
    for (int k = 0; k < 30; ++k) agg += s_p[k][c] * z[k];
    u = agg / (sqrtf(gsum16(agg * agg)) + 1e-9f);
    __syncthreads();
  }
  (is_news ? news_out : user_out)[(long long)b * DIM + tid] = u;
}

// ---------------------------------------------------------------------------
// k_score: score = sum((u@W+b) * (n@W+b)); sigmoid. (unchanged)
// ---------------------------------------------------------------------------
__global__ __launch_bounds__(128) void k_score(
    const float* __restrict__ user_e, const float* __restrict__ news_e,
    const float* __restrict__ last_w, const float* __restrict__ last_b,
    float* __restrict__ out) {
  const int b = blockIdx.x, tid = threadIdx.x;
  __shared__ float s_u[DIM], s_n[DIM];
  __shared__ float s_r[2];
  s_u[tid] = user_e[(long long)b * DIM + tid];
  s_n[tid] = news_e[(long long)b * DIM + tid];
  __syncthreads();
  float xm = last_b[tid], ym = last_b[tid];
  for (int k = 0; k < DIM; k += 4) {
#pragma unroll
    for (int i = 0; i < 4; ++i) {
      const float w = last_w[(k + i) * DIM + tid];
      xm += s_u[k + i] * w;
      ym += s_n[k + i] * w;
    }
  }
  float prod = xm * ym;
#pragma unroll
  for (int off = 1; off < 64; off <<= 1) prod += __shfl_xor(prod, off, 64);
  if ((tid & 63) == 0) s_r[tid >> 6] = prod;
  __syncthreads();
  if (tid == 0) {
    const float s = s_r[0] + s_r[1];
    out[b] = 1.f / (1.f + expf(-s));
  }
}

// ---------------------------------------------------------------------------
extern "C" void kernel_launch(void* const* d_in, const int* in_sizes, int n_in,
                              void* d_out, int out_size, void* d_ws,
                              size_t ws_size, hipStream_t stream) {
  (void)in_sizes; (void)n_in; (void)out_size; (void)ws_size;
  const int* user_indices = (const int*)d_in[0];
  const int* news_indices = (const int*)d_in[1];
  const int* news_user = (const int*)d_in[3];
  const int* user_news = (const int*)d_in[4];
  const int* title = (const int*)d_in[5];
  const float* user_emb_matrix = (const float*)d_in[6];
  const float* word_emb_matrix = (const float*)d_in[7];
  const float* conv_w = (const float*)d_in[8];
  const float* conv_b = (const float*)d_in[9];
  const float* dense_w = (const float*)d_in[10];
  const float* dense_b = (const float*)d_in[11];
  const float* user_weights = (const float*)d_in[12];
  const float* user_bias = (const float*)d_in[13];
  const float* item_weights = (const float*)d_in[14];
  const float* item_bias = (const float*)d_in[15];
  const float* last_w = (const float*)d_in[16];
  const float* last_b = (const float*)d_in[17];

  char* ws = (char*)d_ws;
  __hip_bfloat16* flat = (__hip_bfloat16*)ws;            // 50000*1024*2 = 102.4 MB
  ws += (size_t)NNEWS * FLAT2 * 2;
  __hip_bfloat16* news_cnn = (__hip_bfloat16*)ws;        // 12.8 MB
  ws += (size_t)NNEWS * DIM * 2;
  __hip_bfloat16* user_path = (__hip_bfloat16*)ws;       // 16.25 MB
  ws += (size_t)NJOBS * DIM * 2;
  float* news_emb = (float*)ws;
  ws += (size_t)BSZ * DIM * 4;
  float* user_emb = (float*)ws;
  ws += (size_t)BSZ * DIM * 4;
  __hip_bfloat16* dwt = (__hip_bfloat16*)ws;             // 262,144 B
  ws += (size_t)DIM * FLAT2 * 2;
  __hip_bfloat16* iwt = (__hip_bfloat16*)ws;
  ws += (size_t)DIM * DIM * 2;
  __hip_bfloat16* uwt = (__hip_bfloat16*)ws;
  float* out = (float*)d_out;

  k_prep<<<(DIM * FLAT2 + 2 * DIM * DIM + 255) / 256, 256, 0, stream>>>(
      dense_w, item_weights, user_weights, dwt, iwt, uwt);
  k_conv<<<NNEWS / 8, 256, 0, stream>>>(title, word_emb_matrix, conv_w,
                                        conv_b, flat);
  k_dense<<<(NNEWS + 63) / 64, 256, 0, stream>>>(
      flat, dwt, dense_b, iwt, item_bias, news_cnn, NNEWS);
  k_user<<<NJOBS / 32, 256, 0, stream>>>(
      user_indices, news_indices, news_user, user_emb_matrix, uwt, user_bias,
      user_path);
  k_route<<<2 * BSZ, 128, 0, stream>>>(news_cnn, user_path, user_indices,
                                       news_indices, user_news, news_emb,
                                       user_emb);
  k_score<<<BSZ, 128, 0, stream>>>(user_emb, news_emb, last_w, last_b, out);
}

// Round 9
// 200.456 us; speedup vs baseline: 7.1334x; 1.1889x over previous
//
#include <hip/hip_runtime.h>
#include <hip/hip_bf16.h>
#include <math.h>

#define BSZ 2048
#define NNEWS 50000
#define U_NB 30
#define N_NB 30
#define TITLE_LEN 10
#define W_EMB 50
#define DIM 128
#define ROUTIT 4
#define FLAT2 1024        // permuted, zero-padded K
#define NJOBS (BSZ * 31)  // 63488 user-path rows

typedef __attribute__((ext_vector_type(8))) short bf16x8;
typedef __attribute__((ext_vector_type(4))) float f32x4;

__device__ __forceinline__ ushort bfbits(float v) {
  __hip_bfloat16 h = __float2bfloat16(v);
  ushort u;
  __builtin_memcpy(&u, &h, 2);
  return u;
}

// Build a bf16x8 A-frag = x[s..s+8) from a 16B-aligned 64-elem bf16 row.
// 2 aligned ds_read_b128 + branch-free cndmask/funnel shift.
__device__ __forceinline__ bf16x8 bfrag(const ushort* row, int s) {
  const char* p = reinterpret_cast<const char*>(row) + ((s * 2) & ~15);
  const uint4 lo = *reinterpret_cast<const uint4*>(p);
  const uint4 hi = *reinterpret_cast<const uint4*>(p + 16);
  const uint d0 = lo.x, d1 = lo.y, d2 = lo.z, d3 = lo.w;
  const uint d4 = hi.x, d5 = hi.y, d6 = hi.z, d7 = hi.w;
  const bool q2 = (s & 4) != 0;
  const uint e0 = q2 ? d2 : d0, e1 = q2 ? d3 : d1, e2 = q2 ? d4 : d2;
  const uint e3 = q2 ? d5 : d3, e4 = q2 ? d6 : d4, e5 = q2 ? d7 : d5;
  const bool q1 = (s & 2) != 0;
  const uint f0 = q1 ? e1 : e0, f1 = q1 ? e2 : e1, f2 = q1 ? e3 : e2;
  const uint f3 = q1 ? e4 : e3, f4 = q1 ? e5 : e4;
  const bool r1 = (s & 1) != 0;
  uint g[4];
  g[0] = r1 ? ((f0 >> 16) | (f1 << 16)) : f0;
  g[1] = r1 ? ((f1 >> 16) | (f2 << 16)) : f1;
  g[2] = r1 ? ((f2 >> 16) | (f3 << 16)) : f2;
  g[3] = r1 ? ((f3 >> 16) | (f4 << 16)) : f3;
  bf16x8 r;
  __builtin_memcpy(&r, g, 16);
  return r;
}

// ---------------------------------------------------------------------------
// k_prep: build dwt' (permuted zero-padded K=1024) + transposed iwt/uwt.
// ---------------------------------------------------------------------------
__global__ __launch_bounds__(256) void k_prep(
    const float* __restrict__ dw, const float* __restrict__ iw,
    const float* __restrict__ uw, __hip_bfloat16* __restrict__ dwt,
    __hip_bfloat16* __restrict__ iwt, __hip_bfloat16* __restrict__ uwt) {
  const int idx = blockIdx.x * 256 + threadIdx.x;
  if (idx < DIM * FLAT2) {
    const int col = idx & 127, k2 = idx >> 7;
    const int i = k2 & 3, X = k2 >> 2;
    const int c = X & 7, gkq = (X >> 3) & 3, jhq = (X >> 5) & 1, h = X >> 6;
    const int j = jhq * 16 + gkq * 4 + i;
    const float v = (j < 31) ? dw[(c * 124 + h * 31 + j) * 128 + col] : 0.f;
    dwt[col * FLAT2 + k2] = __float2bfloat16(v);
  } else if (idx < DIM * FLAT2 + DIM * DIM) {
    const int j = idx - DIM * FLAT2;
    const int o = j & 127, k = j >> 7;
    iwt[o * DIM + k] = __float2bfloat16(iw[j]);
  } else if (idx < DIM * FLAT2 + 2 * DIM * DIM) {
    const int j = idx - DIM * FLAT2 - DIM * DIM;
    const int o = j & 127, k = j >> 7;
    uwt[o * DIM + k] = __float2bfloat16(uw[j]);
  }
}

// ---------------------------------------------------------------------------
// k_conv: 8 titles/block, 256 thr (4 waves, 2 titles each). MFMA Toeplitz
// conv; epilogue writes DIRECT to global (256 B contiguous per store).
// ---------------------------------------------------------------------------
__global__ __launch_bounds__(256, 4) void k_conv(
    const int* __restrict__ title, const float* __restrict__ word_emb,
    const float* __restrict__ conv_w, const float* __restrict__ conv_b,
    __hip_bfloat16* __restrict__ flat) {
  __shared__ int s_words[80];
  __shared__ __align__(16) ushort s_x[80 * 64];  // 10,240 B (rows padded to 64)

  const int tid = threadIdx.x;
  const int wv = tid >> 6, lane = tid & 63;
  const int base = blockIdx.x * 8;  // 6250 * 8 = 50000 exactly
  const int c = lane & 15, gk = lane >> 4;

  // B-frags (weights) once; taps >=20 zeroed in B
  bf16x8 b0, b1;
#pragma unroll
  for (int i = 0; i < 8; ++i) {
    const int k = gk * 8 + i;
    float v0 = 0.f, v1 = 0.f;
    if (c < 8 && k < 20) {
      v0 = conv_w[c * 40 + k];
      v1 = conv_w[c * 40 + 20 + k];
    }
    b0[i] = (short)bfbits(v0);
    b1[i] = (short)bfbits(v1);
  }
  const float cbias = (c < 8) ? conv_b[c] : 0.f;

  if (tid < 80) s_words[tid] = title[base * TITLE_LEN + tid];
  __syncthreads();

  // gather: 80 rows x 64 bf16 (elems 50..63 zero), uint4 LDS writes
  {
    const float2* we2 = reinterpret_cast<const float2*>(word_emb);
#pragma unroll
    for (int i = 0; i < 3; ++i) {
      const int u = tid + i * 256;
      if (u < 640) {
        const int row = u >> 3, slot = u & 7;
        ushort o[8];
#pragma unroll
        for (int p = 0; p < 4; ++p) {
          const int c2 = slot * 4 + p;
          float2 v = make_float2(0.f, 0.f);
          if (c2 < 25) v = we2[(long long)s_words[row] * 25 + c2];
          o[2 * p] = bfbits(v.x);
          o[2 * p + 1] = bfbits(v.y);
        }
        *reinterpret_cast<uint4*>(&s_x[row * 64 + slot * 8]) =
            *reinterpret_cast<const uint4*>(o);
      }
    }
  }
  __syncthreads();

  // conv via MFMA, rolling 3-frag window; direct-global epilogue
  ushort* fl = reinterpret_cast<ushort*>(flat);
#pragma unroll 1
  for (int tt = 0; tt < 2; ++tt) {
    const int t = wv * 2 + tt;
    const ushort* xb = &s_x[t * 640];  // 10 rows x 64
    ushort* gout = &fl[(size_t)(base + t) * FLAT2];
#pragma unroll
    for (int jh = 0; jh < 2; ++jh) {
      const int s = jh * 16 + (lane & 15) + gk * 8;
      bf16x8 fprev = bfrag(xb, s);  // row 0
#pragma unroll
      for (int h = 0; h < 4; ++h) {
        const bf16x8 fmid = bfrag(xb + (2 * h + 1) * 64, s);
        const bf16x8 fnext = bfrag(xb + (2 * h + 2) * 64, s);
        f32x4 d0 = (f32x4){0.f, 0.f, 0.f, 0.f};
        f32x4 d1 = (f32x4){0.f, 0.f, 0.f, 0.f};
        d0 = __builtin_amdgcn_mfma_f32_16x16x32_bf16(fprev, b0, d0, 0, 0, 0);
        d0 = __builtin_amdgcn_mfma_f32_16x16x32_bf16(fmid, b1, d0, 0, 0, 0);
        d1 = __builtin_amdgcn_mfma_f32_16x16x32_bf16(fmid, b0, d1, 0, 0, 0);
        d1 = __builtin_amdgcn_mfma_f32_16x16x32_bf16(fnext, b1, d1, 0, 0, 0);
        if (c < 8) {
          ushort w[4];
#pragma unroll
          for (int i2 = 0; i2 < 4; ++i2)
            w[i2] = bfbits(fmaxf(fmaxf(d0[i2], d1[i2]) + cbias, 0.f));
          // k2 = (h*64 + jh*32 + gk*8 + c)*4 + i2 : 256 B contiguous per store
          *reinterpret_cast<uint2*>(&gout[(h * 64 + jh * 32 + gk * 8 + c) * 4]) =
              *reinterpret_cast<const uint2*>(w);
        }
        fprev = fnext;
      }
    }
  }
}

// ---------------------------------------------------------------------------
// k_dense: [64 x 1024]@[1024 x 128] (+b, relu) then @[128 x 128] (+b, relu).
// A double-buffered in LDS; B direct from L2 with register prefetch.
// ---------------------------------------------------------------------------
__global__ __launch_bounds__(256, 2) void k_dense(
    const __hip_bfloat16* __restrict__ flat,
    const __hip_bfloat16* __restrict__ dwt, const float* __restrict__ dense_b,
    const __hip_bfloat16* __restrict__ iwt, const float* __restrict__ item_b,
    __hip_bfloat16* __restrict__ out, int nrows) {
  __shared__ __align__(16) char lds[18432];
  ushort* A0 = (ushort*)lds;            // [64][72]
  ushort* A1 = (ushort*)(lds + 9216);   // [64][72]
  ushort* c1 = (ushort*)lds;            // [64][136] overlay after dense

  const int tid = threadIdx.x;
  const int wv = tid >> 6, lane = tid & 63;
  const int fr = lane & 15, gk = lane >> 4;
  const int lrow0 = min((int)blockIdx.x * 64, nrows - 64);
  const ushort* fl = (const ushort*)flat;
  const ushort* dwp = (const ushort*)dwt;

  uint4 pA[2];
#define LD_A(KS)                                                              \
  {                                                                           \
    _Pragma("unroll") for (int q = 0; q < 2; ++q) {                           \
      const int uu = tid + q * 256;                                           \
      pA[q] = *reinterpret_cast<const uint4*>(                                \
          &fl[(size_t)(lrow0 + (uu >> 3)) * FLAT2 + (KS) * 64 + (uu & 7) * 8]); \
    }                                                                         \
  }
#define ST_A(BUF)                                                             \
  {                                                                           \
    _Pragma("unroll") for (int q = 0; q < 2; ++q) {                           \
      const int uu = tid + q * 256;                                           \
      *reinterpret_cast<uint4*>(&(BUF)[(uu >> 3) * 72 + (uu & 7) * 8]) = pA[q]; \
    }                                                                         \
  }
#define LD_B(DST, KS)                                                         \
  {                                                                           \
    _Pragma("unroll") for (int nn = 0; nn < 2; ++nn)                          \
        _Pragma("unroll") for (int qq = 0; qq < 2; ++qq) {                    \
      (DST)[nn * 2 + qq] = *reinterpret_cast<const bf16x8*>(                  \
          &dwp[(wv * 32 + nn * 16 + fr) * FLAT2 + (KS) * 64 + qq * 32 +       \
               gk * 8]);                                                      \
    }                                                                         \
  }

  LD_A(0);
  ST_A(A0);
  LD_A(1);
  bf16x8 bA[4];
  LD_B(bA, 0);
  __syncthreads();

  f32x4 acc[4][2];
#pragma unroll
  for (int m = 0; m < 4; ++m)
#pragma unroll
    for (int n = 0; n < 2; ++n) acc[m][n] = (f32x4){0.f, 0.f, 0.f, 0.f};

  for (int ks = 0; ks < 16; ++ks) {
    const ushort* cA = (ks & 1) ? A1 : A0;
    bf16x8 bN[4];
    if (ks < 15) {
      LD_B(bN, ks + 1);
    } else {
#pragma unroll
      for (int z = 0; z < 4; ++z) bN[z] = bA[z];
    }
    bf16x8 af[2][4];
#pragma unroll
    for (int kk = 0; kk < 2; ++kk)
#pragma unroll
      for (int m = 0; m < 4; ++m)
        af[kk][m] = *reinterpret_cast<const bf16x8*>(
            &cA[(m * 16 + fr) * 72 + kk * 32 + gk * 8]);
#pragma unroll
    for (int kk = 0; kk < 2; ++kk)
#pragma unroll
      for (int m = 0; m < 4; ++m)
#pragma unroll
        for (int n = 0; n < 2; ++n)
          acc[m][n] = __builtin_amdgcn_mfma_f32_16x16x32_bf16(
              af[kk][m], bA[n * 2 + kk], acc[m][n], 0, 0, 0);
    if (ks < 15) {
      if (ks & 1) {
        ST_A(A0);
      } else {
        ST_A(A1);
      }
    }
    if (ks < 14) LD_A(ks + 2);
    __syncthreads();
#pragma unroll
    for (int z = 0; z < 4; ++z) bA[z] = bN[z];
  }
#undef LD_A
#undef ST_A
#undef LD_B

  // dense epilogue -> c1[64][136]
#pragma unroll
  for (int n = 0; n < 2; ++n) {
    const int col = wv * 32 + n * 16 + fr;
    const float bb = dense_b[col];
#pragma unroll
    for (int m = 0; m < 4; ++m)
#pragma unroll
      for (int r = 0; r < 4; ++r)
        c1[(m * 16 + gk * 4 + r) * 136 + col] =
            bfbits(fmaxf(acc[m][n][r] + bb, 0.f));
  }
  __syncthreads();

  // item GEMM [64x128]@[128x128], B direct from L2
  const ushort* iwp = (const ushort*)iwt;
  f32x4 a2[4][2];
#pragma unroll
  for (int m = 0; m < 4; ++m)
#pragma unroll
    for (int n = 0; n < 2; ++n) a2[m][n] = (f32x4){0.f, 0.f, 0.f, 0.f};
#pragma unroll
  for (int kk = 0; kk < 4; ++kk) {
    bf16x8 af[4], bfr[2];
#pragma unroll
    for (int m = 0; m < 4; ++m)
      af[m] = *reinterpret_cast<const bf16x8*>(
          &c1[(m * 16 + fr) * 136 + kk * 32 + gk * 8]);
#pragma unroll
    for (int n = 0; n < 2; ++n)
      bfr[n] = *reinterpret_cast<const bf16x8*>(
          &iwp[(wv * 32 + n * 16 + fr) * DIM + kk * 32 + gk * 8]);
#pragma unroll
    for (int m = 0; m < 4; ++m)
#pragma unroll
      for (int n = 0; n < 2; ++n)
        a2[m][n] = __builtin_amdgcn_mfma_f32_16x16x32_bf16(af[m], bfr[n],
                                                           a2[m][n], 0, 0, 0);
  }

#pragma unroll
  for (int n = 0; n < 2; ++n) {
    const int col = wv * 32 + n * 16 + fr;
    const float bb = item_b[col];
#pragma unroll
    for (int m = 0; m < 4; ++m)
#pragma unroll
      for (int r = 0; r < 4; ++r) {
        const int row = m * 16 + gk * 4 + r;
        out[(size_t)(lrow0 + row) * DIM + col] =
            __float2bfloat16(fmaxf(a2[m][n][r] + bb, 0.f));
      }
  }
}

// ---------------------------------------------------------------------------
// k_user: gather user_emb rows -> bf16 LDS, MFMA x uwt (B direct from L2).
// ---------------------------------------------------------------------------
__global__ __launch_bounds__(256) void k_user(
    const int* __restrict__ user_indices, const int* __restrict__ news_indices,
    const int* __restrict__ news_user, const float* __restrict__ user_emb,
    const __hip_bfloat16* __restrict__ uwt, const float* __restrict__ user_b,
    __hip_bfloat16* __restrict__ out) {
  __shared__ __align__(16) __hip_bfloat16 s_e[32][136];
  __shared__ int s_uid[32];
  const int tid = threadIdx.x;
  const int wave = tid >> 6, lane = tid & 63;
  const int base = blockIdx.x * 32;

  if (tid < 32) {
    const int r = base + tid;
    int uid;
    if (r < BSZ) {
      uid = user_indices[r];
    } else {
      const int j = r - BSZ;
      const int b = j / U_NB, k = j - b * U_NB;
      uid = news_user[(long long)news_indices[b] * U_NB + k];
    }
    s_uid[tid] = uid;
  }
  __syncthreads();
#pragma unroll
  for (int i = 0; i < 4; ++i) {
    const int u = tid + i * 256;
    const int row = u >> 5, d4 = u & 31;
    const float4 v = *reinterpret_cast<const float4*>(
        &user_emb[(long long)s_uid[row] * DIM + d4 * 4]);
    __hip_bfloat16* p = &s_e[row][d4 * 4];
    p[0] = __float2bfloat16(v.x);
    p[1] = __float2bfloat16(v.y);
    p[2] = __float2bfloat16(v.z);
    p[3] = __float2bfloat16(v.w);
  }
  __syncthreads();

  const int fr = lane & 15, gk = lane >> 4;
  const ushort* uwp = (const ushort*)uwt;
  f32x4 acc[2][2];
#pragma unroll
  for (int m = 0; m < 2; ++m)
#pragma unroll
    for (int n = 0; n < 2; ++n) acc[m][n] = (f32x4){0.f, 0.f, 0.f, 0.f};

#pragma unroll
  for (int ks = 0; ks < 4; ++ks) {
    bf16x8 af[2], bfr[2];
#pragma unroll
    for (int m = 0; m < 2; ++m)
      af[m] = *reinterpret_cast<const bf16x8*>(
          &s_e[m * 16 + fr][ks * 32 + gk * 8]);
#pragma unroll
    for (int n = 0; n < 2; ++n)
      bfr[n] = *reinterpret_cast<const bf16x8*>(
          &uwp[(wave * 32 + n * 16 + fr) * DIM + ks * 32 + gk * 8]);
#pragma unroll
    for (int m = 0; m < 2; ++m)
#pragma unroll
      for (int n = 0; n < 2; ++n)
        acc[m][n] = __builtin_amdgcn_mfma_f32_16x16x32_bf16(af[m], bfr[n],
                                                            acc[m][n], 0, 0, 0);
  }

#pragma unroll
  for (int n = 0; n < 2; ++n) {
    const int col = wave * 32 + n * 16 + fr;
    const float bb = user_b[col];
#pragma unroll
    for (int m = 0; m < 2; ++m)
#pragma unroll
      for (int r = 0; r < 4; ++r) {
        const int row = m * 16 + gk * 4 + r;
        out[(size_t)(base + row) * DIM + col] =
            __float2bfloat16(fmaxf(acc[m][n][r] + bb, 0.f));
      }
  }
}

// ---------------------------------------------------------------------------
// k_route v2 (shuffle-free inner loop): 256 thr/block, 1 job/block.
// z staged f32 in LDS [30][132]; thread (k,c)=tid<240 stages 16 elems and
// keeps its normalized 16-dim capsule in registers; dots = 16 local FMA;
// softmax thread-per-k; agg thread-per-(c,d).
// ---------------------------------------------------------------------------
__device__ __forceinline__ float gsum16(float v) {
  v += __shfl_xor(v, 1, 16);
  v += __shfl_xor(v, 2, 16);
  v += __shfl_xor(v, 4, 16);
  v += __shfl_xor(v, 8, 16);
  return v;
}

__global__ __launch_bounds__(256) void k_route(
    const __hip_bfloat16* __restrict__ news_cnn,
    const __hip_bfloat16* __restrict__ user_path,
    const int* __restrict__ user_indices, const int* __restrict__ news_indices,
    const int* __restrict__ user_news, float* __restrict__ news_out,
    float* __restrict__ user_out) {
  __shared__ int s_nid[32];
  __shared__ __align__(16) float zf[30][132];
  __shared__ __align__(16) float xn[128];
  __shared__ __align__(16) float uu[128];
  __shared__ __align__(16) float pp[30][8];

  const int j = blockIdx.x, tid = threadIdx.x;
  const bool is_news = (j < BSZ);
  const int b = is_news ? j : j - BSZ;

  if (tid < 30)
    s_nid[tid] = is_news ? (BSZ + b * 30 + tid)
                         : user_news[(long long)user_indices[b] * N_NB + tid];
  __syncthreads();

  // stage z rows (bf16 -> f32 LDS); 240 threads, 16 bf16 (2 uint4) each:
  // thread (k = tid>>3, q = tid&7) covers elements q*16 .. q*16+15.
  const __hip_bfloat16* zsrc = is_news ? user_path : news_cnn;
  if (tid < 240) {
    const int k = tid >> 3, q = tid & 7;
    const ushort* src =
        reinterpret_cast<const ushort*>(zsrc + (long long)s_nid[k] * DIM);
    ushort h16[16];
    *reinterpret_cast<uint4*>(&h16[0]) =
        *reinterpret_cast<const uint4*>(&src[q * 16]);
    *reinterpret_cast<uint4*>(&h16[8]) =
        *reinterpret_cast<const uint4*>(&src[q * 16 + 8]);
    float f[16];
#pragma unroll
    for (int i = 0; i < 16; ++i) {
      const uint bits = ((uint)h16[i]) << 16;
      __builtin_memcpy(&f[i], &bits, 4);
    }
#pragma unroll
    for (int v4 = 0; v4 < 4; ++v4)
      *reinterpret_cast<f32x4*>(&zf[k][q * 16 + v4 * 4]) =
          *reinterpret_cast<f32x4*>(&f[v4 * 4]);
  }
  // x: load + per-cap l2n (one gsum16)
  if (tid < 128) {
    const __hip_bfloat16* xrow = is_news
                                     ? news_cnn + (long long)news_indices[b] * DIM
                                     : user_path + (long long)b * DIM;
    float xv = __bfloat162float(xrow[tid]);
    xv = xv / (sqrtf(gsum16(xv * xv)) + 1e-9f);
    xn[tid] = xv;
    uu[tid] = xv;
  }
  __syncthreads();

  // z-normalize locally; cache capsule in regs
  const int kk = tid >> 3, cc = tid & 7;
  float z16[16];
  if (tid < 240) {
    float ss = 0.f;
#pragma unroll
    for (int d = 0; d < 16; ++d) {
      z16[d] = zf[kk][cc * 16 + d];
      ss += z16[d] * z16[d];
    }
    const float inv = 1.f / (sqrtf(ss) + 1e-9f);
#pragma unroll
    for (int d = 0; d < 16; ++d) {
      z16[d] *= inv;
      zf[kk][cc * 16 + d] = z16[d];
    }
  }
  __syncthreads();

  float u_fin = 0.f;
  for (int it = 0; it < ROUTIT; ++it) {
    if (tid < 240) {
      float dot = 0.f;
#pragma unroll
      for (int d = 0; d < 16; ++d) dot += z16[d] * uu[cc * 16 + d];
      pp[kk][cc] = dot;
    }
    __syncthreads();
    if (tid < 30) {
      float m = -1e30f, e[8], s = 0.f;
#pragma unroll
      for (int c2 = 0; c2 < 8; ++c2) m = fmaxf(m, pp[tid][c2]);
#pragma unroll
      for (int c2 = 0; c2 < 8; ++c2) {
        e[c2] = expf(pp[tid][c2] - m);
        s += e[c2];
      }
      const float invs = 1.f / s;
#pragma unroll
      for (int c2 = 0; c2 < 8; ++c2) pp[tid][c2] = e[c2] * invs;
    }
    __syncthreads();
    if (tid < 128) {
      const int c2 = tid >> 4;
      float agg = xn[tid];
#pragma unroll
      for (int k = 0; k < 30; ++k) agg += pp[k][c2] * zf[k][tid];
      u_fin = agg / (sqrtf(gsum16(agg * agg)) + 1e-9f);
      uu[tid] = u_fin;
    }
    __syncthreads();
  }
  if (tid < 128)
    (is_news ? news_out : user_out)[(long long)b * DIM + tid] = u_fin;
}

// ---------------------------------------------------------------------------
// k_score: score = sum((u@W+b) * (n@W+b)); sigmoid.
// ---------------------------------------------------------------------------
__global__ __launch_bounds__(128) void k_score(
    const float* __restrict__ user_e, const float* __restrict__ news_e,
    const float* __restrict__ last_w, const float* __restrict__ last_b,
    float* __restrict__ out) {
  const int b = blockIdx.x, tid = threadIdx.x;
  __shared__ float s_u[DIM], s_n[DIM];
  __shared__ float s_r[2];
  s_u[tid] = user_e[(long long)b * DIM + tid];
  s_n[tid] = news_e[(long long)b * DIM + tid];
  __syncthreads();
  float xm = last_b[tid], ym = last_b[tid];
  for (int k = 0; k < DIM; k += 4) {
#pragma unroll
    for (int i = 0; i < 4; ++i) {
      const float w = last_w[(k + i) * DIM + tid];
      xm += s_u[k + i] * w;
      ym += s_n[k + i] * w;
    }
  }
  float prod = xm * ym;
#pragma unroll
  for (int off = 1; off < 64; off <<= 1) prod += __shfl_xor(prod, off, 64);
  if ((tid & 63) == 0) s_r[tid >> 6] = prod;
  __syncthreads();
  if (tid == 0) {
    const float s = s_r[0] + s_r[1];
    out[b] = 1.f / (1.f + expf(-s));
  }
}

// ---------------------------------------------------------------------------
extern "C" void kernel_launch(void* const* d_in, const int* in_sizes, int n_in,
                              void* d_out, int out_size, void* d_ws,
                              size_t ws_size, hipStream_t stream) {
  (void)in_sizes; (void)n_in; (void)out_size; (void)ws_size;
  const int* user_indices = (const int*)d_in[0];
  const int* news_indices = (const int*)d_in[1];
  const int* news_user = (const int*)d_in[3];
  const int* user_news = (const int*)d_in[4];
  const int* title = (const int*)d_in[5];
  const float* user_emb_matrix = (const float*)d_in[6];
  const float* word_emb_matrix = (const float*)d_in[7];
  const float* conv_w = (const float*)d_in[8];
  const float* conv_b = (const float*)d_in[9];
  const float* dense_w = (const float*)d_in[10];
  const float* dense_b = (const float*)d_in[11];
  const float* user_weights = (const float*)d_in[12];
  const float* user_bias = (const float*)d_in[13];
  const float* item_weights = (const float*)d_in[14];
  const float* item_bias = (const float*)d_in[15];
  const float* last_w = (const float*)d_in[16];
  const float* last_b = (const float*)d_in[17];

  char* ws = (char*)d_ws;
  __hip_bfloat16* flat = (__hip_bfloat16*)ws;            // 102.4 MB
  ws += (size_t)NNEWS * FLAT2 * 2;
  __hip_bfloat16* news_cnn = (__hip_bfloat16*)ws;        // 12.8 MB
  ws += (size_t)NNEWS * DIM * 2;
  __hip_bfloat16* user_path = (__hip_bfloat16*)ws;       // 16.25 MB
  ws += (size_t)NJOBS * DIM * 2;
  float* news_emb = (float*)ws;
  ws += (size_t)BSZ * DIM * 4;
  float* user_emb = (float*)ws;
  ws += (size_t)BSZ * DIM * 4;
  __hip_bfloat16* dwt = (__hip_bfloat16*)ws;             // 262,144 B
  ws += (size_t)DIM * FLAT2 * 2;
  __hip_bfloat16* iwt = (__hip_bfloat16*)ws;
  ws += (size_t)DIM * DIM * 2;
  __hip_bfloat16* uwt = (__hip_bfloat16*)ws;
  float* out = (float*)d_out;

  k_prep<<<(DIM * FLAT2 + 2 * DIM * DIM + 255) / 256, 256, 0, stream>>>(
      dense_w, item_weights, user_weights, dwt, iwt, uwt);
  k_conv<<<NNEWS / 8, 256, 0, stream>>>(title, word_emb_matrix, conv_w,
                                        conv_b, flat);
  k_dense<<<(NNEWS + 63) / 64, 256, 0, stream>>>(
      flat, dwt, dense_b, iwt, item_bias, news_cnn, NNEWS);
  k_user<<<NJOBS / 32, 256, 0, stream>>>(
      user_indices, news_indices, news_user, user_emb_matrix, uwt, user_bias,
      user_path);
  k_route<<<2 * BSZ, 256, 0, stream>>>(news_cnn, user_path, user_indices,
                                       news_indices, user_news, news_emb,
                                       user_emb);
  k_score<<<BSZ, 128, 0, stream>>>(user_emb, news_emb, last_w, last_b, out);
}

// Round 10
// 189.018 us; speedup vs baseline: 7.5651x; 1.0605x over previous
//
#include <hip/hip_runtime.h>
#include <hip/hip_bf16.h>
#include <math.h>

#define BSZ 2048
#define NNEWS 50000
#define U_NB 30
#define N_NB 30
#define TITLE_LEN 10
#define W_EMB 50
#define DIM 128
#define ROUTIT 4
#define FLAT2 1024        // permuted, zero-padded K
#define NJOBS (BSZ * 31)  // 63488 user-path rows

typedef __attribute__((ext_vector_type(8))) short bf16x8;
typedef __attribute__((ext_vector_type(4))) float f32x4;

__device__ __forceinline__ ushort bfbits(float v) {
  __hip_bfloat16 h = __float2bfloat16(v);
  ushort u;
  __builtin_memcpy(&u, &h, 2);
  return u;
}

// Build a bf16x8 A-frag = x[s..s+8) from a 16B-aligned 64-elem bf16 row.
// 2 aligned ds_read_b128 + branch-free cndmask/funnel shift.
__device__ __forceinline__ bf16x8 bfrag(const ushort* row, int s) {
  const char* p = reinterpret_cast<const char*>(row) + ((s * 2) & ~15);
  const uint4 lo = *reinterpret_cast<const uint4*>(p);
  const uint4 hi = *reinterpret_cast<const uint4*>(p + 16);
  const uint d0 = lo.x, d1 = lo.y, d2 = lo.z, d3 = lo.w;
  const uint d4 = hi.x, d5 = hi.y, d6 = hi.z, d7 = hi.w;
  const bool q2 = (s & 4) != 0;
  const uint e0 = q2 ? d2 : d0, e1 = q2 ? d3 : d1, e2 = q2 ? d4 : d2;
  const uint e3 = q2 ? d5 : d3, e4 = q2 ? d6 : d4, e5 = q2 ? d7 : d5;
  const bool q1 = (s & 2) != 0;
  const uint f0 = q1 ? e1 : e0, f1 = q1 ? e2 : e1, f2 = q1 ? e3 : e2;
  const uint f3 = q1 ? e4 : e3, f4 = q1 ? e5 : e4;
  const bool r1 = (s & 1) != 0;
  uint g[4];
  g[0] = r1 ? ((f0 >> 16) | (f1 << 16)) : f0;
  g[1] = r1 ? ((f1 >> 16) | (f2 << 16)) : f1;
  g[2] = r1 ? ((f2 >> 16) | (f3 << 16)) : f2;
  g[3] = r1 ? ((f3 >> 16) | (f4 << 16)) : f3;
  bf16x8 r;
  __builtin_memcpy(&r, g, 16);
  return r;
}

// ---------------------------------------------------------------------------
// k_mark: set used[id]=1 for every news id referenced by the batch.
// ---------------------------------------------------------------------------
__global__ __launch_bounds__(256) void k_mark(
    const int* __restrict__ news_indices, const int* __restrict__ user_indices,
    const int* __restrict__ user_news, unsigned char* __restrict__ used) {
  const int i = blockIdx.x * 256 + threadIdx.x;
  if (i < BSZ) used[news_indices[i]] = 1;
  const int j = i - BSZ;
  if (j >= 0 && j < BSZ * N_NB) {
    const int b = j / N_NB, k = j - b * N_NB;
    used[user_news[(long long)user_indices[b] * N_NB + k]] = 1;
  }
}

// ---------------------------------------------------------------------------
// k_compact: list[0..n) = used news ids (order run-dependent; results are
// per-id so final output is order-independent). counter holds n.
// ---------------------------------------------------------------------------
__global__ __launch_bounds__(256) void k_compact(
    const unsigned char* __restrict__ used, int* __restrict__ list,
    int* __restrict__ counter) {
  const int id = blockIdx.x * 256 + threadIdx.x;
  if (id < NNEWS && used[id]) {
    const int p = atomicAdd(counter, 1);
    list[p] = id;
  }
}

// ---------------------------------------------------------------------------
// k_prep: build dwt' (permuted zero-padded K=1024) + transposed iwt/uwt.
// ---------------------------------------------------------------------------
__global__ __launch_bounds__(256) void k_prep(
    const float* __restrict__ dw, const float* __restrict__ iw,
    const float* __restrict__ uw, __hip_bfloat16* __restrict__ dwt,
    __hip_bfloat16* __restrict__ iwt, __hip_bfloat16* __restrict__ uwt) {
  const int idx = blockIdx.x * 256 + threadIdx.x;
  if (idx < DIM * FLAT2) {
    const int col = idx & 127, k2 = idx >> 7;
    const int i = k2 & 3, X = k2 >> 2;
    const int c = X & 7, gkq = (X >> 3) & 3, jhq = (X >> 5) & 1, h = X >> 6;
    const int j = jhq * 16 + gkq * 4 + i;
    const float v = (j < 31) ? dw[(c * 124 + h * 31 + j) * 128 + col] : 0.f;
    dwt[col * FLAT2 + k2] = __float2bfloat16(v);
  } else if (idx < DIM * FLAT2 + DIM * DIM) {
    const int j = idx - DIM * FLAT2;
    const int o = j & 127, k = j >> 7;
    iwt[o * DIM + k] = __float2bfloat16(iw[j]);
  } else if (idx < DIM * FLAT2 + 2 * DIM * DIM) {
    const int j = idx - DIM * FLAT2 - DIM * DIM;
    const int o = j & 127, k = j >> 7;
    uwt[o * DIM + k] = __float2bfloat16(uw[j]);
  }
}

// ---------------------------------------------------------------------------
// k_conv: 8 compact slots/block. MFMA Toeplitz conv; direct-global epilogue.
// Blocks beyond n exit early.
// ---------------------------------------------------------------------------
__global__ __launch_bounds__(256, 4) void k_conv(
    const int* __restrict__ title, const float* __restrict__ word_emb,
    const float* __restrict__ conv_w, const float* __restrict__ conv_b,
    const int* __restrict__ list, const int* __restrict__ counter,
    __hip_bfloat16* __restrict__ flat) {
  __shared__ int s_words[80];
  __shared__ __align__(16) ushort s_x[80 * 64];  // rows padded to 64

  const int n = counter[0];
  const int base = blockIdx.x * 8;
  if (base >= n) return;

  const int tid = threadIdx.x;
  const int wv = tid >> 6, lane = tid & 63;
  const int c = lane & 15, gk = lane >> 4;

  // B-frags (weights) once; taps >=20 zeroed in B
  bf16x8 b0, b1;
#pragma unroll
  for (int i = 0; i < 8; ++i) {
    const int k = gk * 8 + i;
    float v0 = 0.f, v1 = 0.f;
    if (c < 8 && k < 20) {
      v0 = conv_w[c * 40 + k];
      v1 = conv_w[c * 40 + 20 + k];
    }
    b0[i] = (short)bfbits(v0);
    b1[i] = (short)bfbits(v1);
  }
  const float cbias = (c < 8) ? conv_b[c] : 0.f;

  if (tid < 80) {
    const int idx = min(base + tid / 10, n - 1);
    const int id = list[idx];
    s_words[tid] = title[(long long)id * TITLE_LEN + (tid - (tid / 10) * 10)];
  }
  __syncthreads();

  // gather: 80 rows x 64 bf16 (elems 50..63 zero), uint4 LDS writes
  {
    const float2* we2 = reinterpret_cast<const float2*>(word_emb);
#pragma unroll
    for (int i = 0; i < 3; ++i) {
      const int u = tid + i * 256;
      if (u < 640) {
        const int row = u >> 3, slot = u & 7;
        ushort o[8];
#pragma unroll
        for (int p = 0; p < 4; ++p) {
          const int c2 = slot * 4 + p;
          float2 v = make_float2(0.f, 0.f);
          if (c2 < 25) v = we2[(long long)s_words[row] * 25 + c2];
          o[2 * p] = bfbits(v.x);
          o[2 * p + 1] = bfbits(v.y);
        }
        *reinterpret_cast<uint4*>(&s_x[row * 64 + slot * 8]) =
            *reinterpret_cast<const uint4*>(o);
      }
    }
  }
  __syncthreads();

  // conv via MFMA, rolling 3-frag window; direct-global epilogue
  ushort* fl = reinterpret_cast<ushort*>(flat);
#pragma unroll 1
  for (int tt = 0; tt < 2; ++tt) {
    const int t = wv * 2 + tt;
    const ushort* xb = &s_x[t * 640];  // 10 rows x 64
    ushort* gout = &fl[(size_t)(base + t) * FLAT2];
    const bool live = (base + t) < n;
#pragma unroll
    for (int jh = 0; jh < 2; ++jh) {
      const int s = jh * 16 + (lane & 15) + gk * 8;
      bf16x8 fprev = bfrag(xb, s);  // row 0
#pragma unroll
      for (int h = 0; h < 4; ++h) {
        const bf16x8 fmid = bfrag(xb + (2 * h + 1) * 64, s);
        const bf16x8 fnext = bfrag(xb + (2 * h + 2) * 64, s);
        f32x4 d0 = (f32x4){0.f, 0.f, 0.f, 0.f};
        f32x4 d1 = (f32x4){0.f, 0.f, 0.f, 0.f};
        d0 = __builtin_amdgcn_mfma_f32_16x16x32_bf16(fprev, b0, d0, 0, 0, 0);
        d0 = __builtin_amdgcn_mfma_f32_16x16x32_bf16(fmid, b1, d0, 0, 0, 0);
        d1 = __builtin_amdgcn_mfma_f32_16x16x32_bf16(fmid, b0, d1, 0, 0, 0);
        d1 = __builtin_amdgcn_mfma_f32_16x16x32_bf16(fnext, b1, d1, 0, 0, 0);
        if (c < 8 && live) {
          ushort w[4];
#pragma unroll
          for (int i2 = 0; i2 < 4; ++i2)
            w[i2] = bfbits(fmaxf(fmaxf(d0[i2], d1[i2]) + cbias, 0.f));
          *reinterpret_cast<uint2*>(&gout[(h * 64 + jh * 32 + gk * 8 + c) * 4]) =
              *reinterpret_cast<const uint2*>(w);
        }
        fprev = fnext;
      }
    }
  }
}

// ---------------------------------------------------------------------------
// k_dense: [64 x 1024]@[1024 x 128] (+b, relu) then @[128 x 128] (+b, relu).
// Rows are compact slots; output scattered to news_cnn[list[row]].
// ---------------------------------------------------------------------------
__global__ __launch_bounds__(256, 2) void k_dense(
    const __hip_bfloat16* __restrict__ flat,
    const __hip_bfloat16* __restrict__ dwt, const float* __restrict__ dense_b,
    const __hip_bfloat16* __restrict__ iwt, const float* __restrict__ item_b,
    const int* __restrict__ list, const int* __restrict__ counter,
    __hip_bfloat16* __restrict__ out) {
  __shared__ __align__(16) char lds[18432];
  ushort* A0 = (ushort*)lds;            // [64][72]
  ushort* A1 = (ushort*)(lds + 9216);   // [64][72]
  ushort* c1 = (ushort*)lds;            // [64][136] overlay after dense

  const int n = counter[0];
  const int lrow0 = (int)blockIdx.x * 64;
  if (lrow0 >= n) return;

  const int tid = threadIdx.x;
  const int wv = tid >> 6, lane = tid & 63;
  const int fr = lane & 15, gk = lane >> 4;
  const ushort* fl = (const ushort*)flat;
  const ushort* dwp = (const ushort*)dwt;

  uint4 pA[2];
#define LD_A(KS)                                                              \
  {                                                                           \
    _Pragma("unroll") for (int q = 0; q < 2; ++q) {                           \
      const int uu = tid + q * 256;                                           \
      pA[q] = *reinterpret_cast<const uint4*>(                                \
          &fl[(size_t)(lrow0 + (uu >> 3)) * FLAT2 + (KS) * 64 + (uu & 7) * 8]); \
    }                                                                         \
  }
#define ST_A(BUF)                                                             \
  {                                                                           \
    _Pragma("unroll") for (int q = 0; q < 2; ++q) {                           \
      const int uu = tid + q * 256;                                           \
      *reinterpret_cast<uint4*>(&(BUF)[(uu >> 3) * 72 + (uu & 7) * 8]) = pA[q]; \
    }                                                                         \
  }
#define LD_B(DST, KS)                                                         \
  {                                                                           \
    _Pragma("unroll") for (int nn = 0; nn < 2; ++nn)                          \
        _Pragma("unroll") for (int qq = 0; qq < 2; ++qq) {                    \
      (DST)[nn * 2 + qq] = *reinterpret_cast<const bf16x8*>(                  \
          &dwp[(wv * 32 + nn * 16 + fr) * FLAT2 + (KS) * 64 + qq * 32 +       \
               gk * 8]);                                                      \
    }                                                                         \
  }

  LD_A(0);
  ST_A(A0);
  LD_A(1);
  bf16x8 bA[4];
  LD_B(bA, 0);
  __syncthreads();

  f32x4 acc[4][2];
#pragma unroll
  for (int m = 0; m < 4; ++m)
#pragma unroll
    for (int n2 = 0; n2 < 2; ++n2) acc[m][n2] = (f32x4){0.f, 0.f, 0.f, 0.f};

  for (int ks = 0; ks < 16; ++ks) {
    const ushort* cA = (ks & 1) ? A1 : A0;
    bf16x8 bN[4];
    if (ks < 15) {
      LD_B(bN, ks + 1);
    } else {
#pragma unroll
      for (int z = 0; z < 4; ++z) bN[z] = bA[z];
    }
    bf16x8 af[2][4];
#pragma unroll
    for (int kk = 0; kk < 2; ++kk)
#pragma unroll
      for (int m = 0; m < 4; ++m)
        af[kk][m] = *reinterpret_cast<const bf16x8*>(
            &cA[(m * 16 + fr) * 72 + kk * 32 + gk * 8]);
#pragma unroll
    for (int kk = 0; kk < 2; ++kk)
#pragma unroll
      for (int m = 0; m < 4; ++m)
#pragma unroll
        for (int n2 = 0; n2 < 2; ++n2)
          acc[m][n2] = __builtin_amdgcn_mfma_f32_16x16x32_bf16(
              af[kk][m], bA[n2 * 2 + kk], acc[m][n2], 0, 0, 0);
    if (ks < 15) {
      if (ks & 1) {
        ST_A(A0);
      } else {
        ST_A(A1);
      }
    }
    if (ks < 14) LD_A(ks + 2);
    __syncthreads();
#pragma unroll
    for (int z = 0; z < 4; ++z) bA[z] = bN[z];
  }
#undef LD_A
#undef ST_A
#undef LD_B

  // dense epilogue -> c1[64][136]
#pragma unroll
  for (int n2 = 0; n2 < 2; ++n2) {
    const int col = wv * 32 + n2 * 16 + fr;
    const float bb = dense_b[col];
#pragma unroll
    for (int m = 0; m < 4; ++m)
#pragma unroll
      for (int r = 0; r < 4; ++r)
        c1[(m * 16 + gk * 4 + r) * 136 + col] =
            bfbits(fmaxf(acc[m][n2][r] + bb, 0.f));
  }
  __syncthreads();

  // item GEMM [64x128]@[128x128], B direct from L2
  const ushort* iwp = (const ushort*)iwt;
  f32x4 a2[4][2];
#pragma unroll
  for (int m = 0; m < 4; ++m)
#pragma unroll
    for (int n2 = 0; n2 < 2; ++n2) a2[m][n2] = (f32x4){0.f, 0.f, 0.f, 0.f};
#pragma unroll
  for (int kk = 0; kk < 4; ++kk) {
    bf16x8 af[4], bfr[2];
#pragma unroll
    for (int m = 0; m < 4; ++m)
      af[m] = *reinterpret_cast<const bf16x8*>(
          &c1[(m * 16 + fr) * 136 + kk * 32 + gk * 8]);
#pragma unroll
    for (int n2 = 0; n2 < 2; ++n2)
      bfr[n2] = *reinterpret_cast<const bf16x8*>(
          &iwp[(wv * 32 + n2 * 16 + fr) * DIM + kk * 32 + gk * 8]);
#pragma unroll
    for (int m = 0; m < 4; ++m)
#pragma unroll
      for (int n2 = 0; n2 < 2; ++n2)
        a2[m][n2] = __builtin_amdgcn_mfma_f32_16x16x32_bf16(af[m], bfr[n2],
                                                            a2[m][n2], 0, 0, 0);
  }

#pragma unroll
  for (int n2 = 0; n2 < 2; ++n2) {
    const int col = wv * 32 + n2 * 16 + fr;
    const float bb = item_b[col];
#pragma unroll
    for (int m = 0; m < 4; ++m)
#pragma unroll
      for (int r = 0; r < 4; ++r) {
        const int row = m * 16 + gk * 4 + r;
        const int gr = lrow0 + row;
        if (gr < n) {
          const int id = list[gr];
          out[(size_t)id * DIM + col] =
              __float2bfloat16(fmaxf(a2[m][n2][r] + bb, 0.f));
        }
      }
  }
}

// ---------------------------------------------------------------------------
// k_user: gather user_emb rows -> bf16 LDS, MFMA x uwt (B direct from L2).
// ---------------------------------------------------------------------------
__global__ __launch_bounds__(256) void k_user(
    const int* __restrict__ user_indices, const int* __restrict__ news_indices,
    const int* __restrict__ news_user, const float* __restrict__ user_emb,
    const __hip_bfloat16* __restrict__ uwt, const float* __restrict__ user_b,
    __hip_bfloat16* __restrict__ out) {
  __shared__ __align__(16) __hip_bfloat16 s_e[32][136];
  __shared__ int s_uid[32];
  const int tid = threadIdx.x;
  const int wave = tid >> 6, lane = tid & 63;
  const int base = blockIdx.x * 32;

  if (tid < 32) {
    const int r = base + tid;
    int uid;
    if (r < BSZ) {
      uid = user_indices[r];
    } else {
      const int j = r - BSZ;
      const int b = j / U_NB, k = j - b * U_NB;
      uid = news_user[(long long)news_indices[b] * U_NB + k];
    }
    s_uid[tid] = uid;
  }
  __syncthreads();
#pragma unroll
  for (int i = 0; i < 4; ++i) {
    const int u = tid + i * 256;
    const int row = u >> 5, d4 = u & 31;
    const float4 v = *reinterpret_cast<const float4*>(
        &user_emb[(long long)s_uid[row] * DIM + d4 * 4]);
    __hip_bfloat16* p = &s_e[row][d4 * 4];
    p[0] = __float2bfloat16(v.x);
    p[1] = __float2bfloat16(v.y);
    p[2] = __float2bfloat16(v.z);
    p[3] = __float2bfloat16(v.w);
  }
  __syncthreads();

  const int fr = lane & 15, gk = lane >> 4;
  const ushort* uwp = (const ushort*)uwt;
  f32x4 acc[2][2];
#pragma unroll
  for (int m = 0; m < 2; ++m)
#pragma unroll
    for (int n = 0; n < 2; ++n) acc[m][n] = (f32x4){0.f, 0.f, 0.f, 0.f};

#pragma unroll
  for (int ks = 0; ks < 4; ++ks) {
    bf16x8 af[2], bfr[2];
#pragma unroll
    for (int m = 0; m < 2; ++m)
      af[m] = *reinterpret_cast<const bf16x8*>(
          &s_e[m * 16 + fr][ks * 32 + gk * 8]);
#pragma unroll
    for (int n = 0; n < 2; ++n)
      bfr[n] = *reinterpret_cast<const bf16x8*>(
          &uwp[(wave * 32 + n * 16 + fr) * DIM + ks * 32 + gk * 8]);
#pragma unroll
    for (int m = 0; m < 2; ++m)
#pragma unroll
      for (int n = 0; n < 2; ++n)
        acc[m][n] = __builtin_amdgcn_mfma_f32_16x16x32_bf16(af[m], bfr[n],
                                                            acc[m][n], 0, 0, 0);
  }

#pragma unroll
  for (int n = 0; n < 2; ++n) {
    const int col = wave * 32 + n * 16 + fr;
    const float bb = user_b[col];
#pragma unroll
    for (int m = 0; m < 2; ++m)
#pragma unroll
      for (int r = 0; r < 4; ++r) {
        const int row = m * 16 + gk * 4 + r;
        out[(size_t)(base + row) * DIM + col] =
            __float2bfloat16(fmaxf(acc[m][n][r] + bb, 0.f));
      }
  }
}

// ---------------------------------------------------------------------------
// k_route v2 (shuffle-free inner loop), unchanged from R9.
// ---------------------------------------------------------------------------
__device__ __forceinline__ float gsum16(float v) {
  v += __shfl_xor(v, 1, 16);
  v += __shfl_xor(v, 2, 16);
  v += __shfl_xor(v, 4, 16);
  v += __shfl_xor(v, 8, 16);
  return v;
}

__global__ __launch_bounds__(256) void k_route(
    const __hip_bfloat16* __restrict__ news_cnn,
    const __hip_bfloat16* __restrict__ user_path,
    const int* __restrict__ user_indices, const int* __restrict__ news_indices,
    const int* __restrict__ user_news, float* __restrict__ news_out,
    float* __restrict__ user_out) {
  __shared__ int s_nid[32];
  __shared__ __align__(16) float zf[30][132];
  __shared__ __align__(16) float xn[128];
  __shared__ __align__(16) float uu[128];
  __shared__ __align__(16) float pp[30][8];

  const int j = blockIdx.x, tid = threadIdx.x;
  const bool is_news = (j < BSZ);
  const int b = is_news ? j : j - BSZ;

  if (tid < 30)
    s_nid[tid] = is_news ? (BSZ + b * 30 + tid)
                         : user_news[(long long)user_indices[b] * N_NB + tid];
  __syncthreads();

  const __hip_bfloat16* zsrc = is_news ? user_path : news_cnn;
  if (tid < 240) {
    const int k = tid >> 3, q = tid & 7;
    const ushort* src =
        reinterpret_cast<const ushort*>(zsrc + (long long)s_nid[k] * DIM);
    ushort h16[16];
    *reinterpret_cast<uint4*>(&h16[0]) =
        *reinterpret_cast<const uint4*>(&src[q * 16]);
    *reinterpret_cast<uint4*>(&h16[8]) =
        *reinterpret_cast<const uint4*>(&src[q * 16 + 8]);
    float f[16];
#pragma unroll
    for (int i = 0; i < 16; ++i) {
      const uint bits = ((uint)h16[i]) << 16;
      __builtin_memcpy(&f[i], &bits, 4);
    }
#pragma unroll
    for (int v4 = 0; v4 < 4; ++v4)
      *reinterpret_cast<f32x4*>(&zf[k][q * 16 + v4 * 4]) =
          *reinterpret_cast<f32x4*>(&f[v4 * 4]);
  }
  if (tid < 128) {
    const __hip_bfloat16* xrow = is_news
                                     ? news_cnn + (long long)news_indices[b] * DIM
                                     : user_path + (long long)b * DIM;
    float xv = __bfloat162float(xrow[tid]);
    xv = xv / (sqrtf(gsum16(xv * xv)) + 1e-9f);
    xn[tid] = xv;
    uu[tid] = xv;
  }
  __syncthreads();

  const int kk = tid >> 3, cc = tid & 7;
  float z16[16];
  if (tid < 240) {
    float ss = 0.f;
#pragma unroll
    for (int d = 0; d < 16; ++d) {
      z16[d] = zf[kk][cc * 16 + d];
      ss += z16[d] * z16[d];
    }
    const float inv = 1.f / (sqrtf(ss) + 1e-9f);
#pragma unroll
    for (int d = 0; d < 16; ++d) {
      z16[d] *= inv;
      zf[kk][cc * 16 + d] = z16[d];
    }
  }
  __syncthreads();

  float u_fin = 0.f;
  for (int it = 0; it < ROUTIT; ++it) {
    if (tid < 240) {
      float dot = 0.f;
#pragma unroll
      for (int d = 0; d < 16; ++d) dot += z16[d] * uu[cc * 16 + d];
      pp[kk][cc] = dot;
    }
    __syncthreads();
    if (tid < 30) {
      float m = -1e30f, e[8], s = 0.f;
#pragma unroll
      for (int c2 = 0; c2 < 8; ++c2) m = fmaxf(m, pp[tid][c2]);
#pragma unroll
      for (int c2 = 0; c2 < 8; ++c2) {
        e[c2] = expf(pp[tid][c2] - m);
        s += e[c2];
      }
      const float invs = 1.f / s;
#pragma unroll
      for (int c2 = 0; c2 < 8; ++c2) pp[tid][c2] = e[c2] * invs;
    }
    __syncthreads();
    if (tid < 128) {
      const int c2 = tid >> 4;
      float agg = xn[tid];
#pragma unroll
      for (int k = 0; k < 30; ++k) agg += pp[k][c2] * zf[k][tid];
      u_fin = agg / (sqrtf(gsum16(agg * agg)) + 1e-9f);
      uu[tid] = u_fin;
    }
    __syncthreads();
  }
  if (tid < 128)
    (is_news ? news_out : user_out)[(long long)b * DIM + tid] = u_fin;
}

// ---------------------------------------------------------------------------
// k_score: score = sum((u@W+b) * (n@W+b)); sigmoid.
// ---------------------------------------------------------------------------
__global__ __launch_bounds__(128) void k_score(
    const float* __restrict__ user_e, const float* __restrict__ news_e,
    const float* __restrict__ last_w, const float* __restrict__ last_b,
    float* __restrict__ out) {
  const int b = blockIdx.x, tid = threadIdx.x;
  __shared__ float s_u[DIM], s_n[DIM];
  __shared__ float s_r[2];
  s_u[tid] = user_e[(long long)b * DIM + tid];
  s_n[tid] = news_e[(long long)b * DIM + tid];
  __syncthreads();
  float xm = last_b[tid], ym = last_b[tid];
  for (int k = 0; k < DIM; k += 4) {
#pragma unroll
    for (int i = 0; i < 4; ++i) {
      const float w = last_w[(k + i) * DIM + tid];
      xm += s_u[k + i] * w;
      ym += s_n[k + i] * w;
    }
  }
  float prod = xm * ym;
#pragma unroll
  for (int off = 1; off < 64; off <<= 1) prod += __shfl_xor(prod, off, 64);
  if ((tid & 63) == 0) s_r[tid >> 6] = prod;
  __syncthreads();
  if (tid == 0) {
    const float s = s_r[0] + s_r[1];
    out[b] = 1.f / (1.f + expf(-s));
  }
}

// ---------------------------------------------------------------------------
extern "C" void kernel_launch(void* const* d_in, const int* in_sizes, int n_in,
                              void* d_out, int out_size, void* d_ws,
                              size_t ws_size, hipStream_t stream) {
  (void)in_sizes; (void)n_in; (void)out_size; (void)ws_size;
  const int* user_indices = (const int*)d_in[0];
  const int* news_indices = (const int*)d_in[1];
  const int* news_user = (const int*)d_in[3];
  const int* user_news = (const int*)d_in[4];
  const int* title = (const int*)d_in[5];
  const float* user_emb_matrix = (const float*)d_in[6];
  const float* word_emb_matrix = (const float*)d_in[7];
  const float* conv_w = (const float*)d_in[8];
  const float* conv_b = (const float*)d_in[9];
  const float* dense_w = (const float*)d_in[10];
  const float* dense_b = (const float*)d_in[11];
  const float* user_weights = (const float*)d_in[12];
  const float* user_bias = (const float*)d_in[13];
  const float* item_weights = (const float*)d_in[14];
  const float* item_bias = (const float*)d_in[15];
  const float* last_w = (const float*)d_in[16];
  const float* last_b = (const float*)d_in[17];

  char* ws = (char*)d_ws;
  __hip_bfloat16* flat = (__hip_bfloat16*)ws;            // 102.4 MB
  ws += (size_t)NNEWS * FLAT2 * 2;
  __hip_bfloat16* news_cnn = (__hip_bfloat16*)ws;        // 12.8 MB
  ws += (size_t)NNEWS * DIM * 2;
  __hip_bfloat16* user_path = (__hip_bfloat16*)ws;       // 16.25 MB
  ws += (size_t)NJOBS * DIM * 2;
  float* news_emb = (float*)ws;
  ws += (size_t)BSZ * DIM * 4;
  float* user_emb = (float*)ws;
  ws += (size_t)BSZ * DIM * 4;
  __hip_bfloat16* dwt = (__hip_bfloat16*)ws;             // 262,144 B
  ws += (size_t)DIM * FLAT2 * 2;
  __hip_bfloat16* iwt = (__hip_bfloat16*)ws;
  ws += (size_t)DIM * DIM * 2;
  __hip_bfloat16* uwt = (__hip_bfloat16*)ws;
  ws += (size_t)DIM * DIM * 2;
  unsigned char* used = (unsigned char*)ws;              // 50,000 B
  ws += 50000;
  int* counter = (int*)ws;                               // 4 B (right after used)
  ws += 64;                                              // keep alignment
  int* list = (int*)ws;                                  // 200,000 B
  float* out = (float*)d_out;

  // zero used[] + counter (one async memset; graph-capturable)
  hipMemsetAsync(used, 0, 50000 + 64, stream);

  k_mark<<<(BSZ + BSZ * N_NB + 255) / 256, 256, 0, stream>>>(
      news_indices, user_indices, user_news, used);
  k_compact<<<(NNEWS + 255) / 256, 256, 0, stream>>>(used, list, counter);
  k_prep<<<(DIM * FLAT2 + 2 * DIM * DIM + 255) / 256, 256, 0, stream>>>(
      dense_w, item_weights, user_weights, dwt, iwt, uwt);
  k_conv<<<(NNEWS + 7) / 8, 256, 0, stream>>>(
      title, word_emb_matrix, conv_w, conv_b, list, counter, flat);
  k_dense<<<(NNEWS + 63) / 64, 256, 0, stream>>>(
      flat, dwt, dense_b, iwt, item_bias, list, counter, news_cnn);
  k_user<<<NJOBS / 32, 256, 0, stream>>>(
      user_indices, news_indices, news_user, user_emb_matrix, uwt, user_bias,
      user_path);
  k_route<<<2 * BSZ, 256, 0, stream>>>(news_cnn, user_path, user_indices,
                                       news_indices, user_news, news_emb,
                                       user_emb);
  k_score<<<BSZ, 128, 0, stream>>>(user_emb, news_emb, last_w, last_b, out);
}

// Round 11
// 188.064 us; speedup vs baseline: 7.6034x; 1.0051x over previous
//
#include <hip/hip_runtime.h>
#include <hip/hip_bf16.h>
#include <math.h>

#define BSZ 2048
#define NNEWS 50000
#define U_NB 30
#define N_NB 30
#define TITLE_LEN 10
#define W_EMB 50
#define DIM 128
#define ROUTIT 4
#define FLAT2 1024        // permuted, zero-padded K
#define NJOBS (BSZ * 31)  // 63488 user-path rows

#define CONV_BLOCKS (NNEWS / 8)                       // 6250
#define PREP_ELEMS (DIM * FLAT2 + 2 * DIM * DIM)      // 163,840
#define PREP_BLOCKS (PREP_ELEMS / 256)                // 640
#define DENSE_BLOCKS ((NNEWS + 63) / 64)              // 782
#define USER_BLOCKS (NJOBS / 32)                      // 1984

typedef __attribute__((ext_vector_type(8))) short bf16x8;
typedef __attribute__((ext_vector_type(4))) float f32x4;

__device__ __forceinline__ ushort bfbits(float v) {
  __hip_bfloat16 h = __float2bfloat16(v);
  ushort u;
  __builtin_memcpy(&u, &h, 2);
  return u;
}

// Build a bf16x8 A-frag = x[s..s+8) from a 16B-aligned 64-elem bf16 row.
__device__ __forceinline__ bf16x8 bfrag(const ushort* row, int s) {
  const char* p = reinterpret_cast<const char*>(row) + ((s * 2) & ~15);
  const uint4 lo = *reinterpret_cast<const uint4*>(p);
  const uint4 hi = *reinterpret_cast<const uint4*>(p + 16);
  const uint d0 = lo.x, d1 = lo.y, d2 = lo.z, d3 = lo.w;
  const uint d4 = hi.x, d5 = hi.y, d6 = hi.z, d7 = hi.w;
  const bool q2 = (s & 4) != 0;
  const uint e0 = q2 ? d2 : d0, e1 = q2 ? d3 : d1, e2 = q2 ? d4 : d2;
  const uint e3 = q2 ? d5 : d3, e4 = q2 ? d6 : d4, e5 = q2 ? d7 : d5;
  const bool q1 = (s & 2) != 0;
  const uint f0 = q1 ? e1 : e0, f1 = q1 ? e2 : e1, f2 = q1 ? e3 : e2;
  const uint f3 = q1 ? e4 : e3, f4 = q1 ? e5 : e4;
  const bool r1 = (s & 1) != 0;
  uint g[4];
  g[0] = r1 ? ((f0 >> 16) | (f1 << 16)) : f0;
  g[1] = r1 ? ((f1 >> 16) | (f2 << 16)) : f1;
  g[2] = r1 ? ((f2 >> 16) | (f3 << 16)) : f2;
  g[3] = r1 ? ((f3 >> 16) | (f4 << 16)) : f3;
  bf16x8 r;
  __builtin_memcpy(&r, g, 16);
  return r;
}

// ---------------------------------------------------------------------------
// k_front: blocks [0, CONV_BLOCKS) = MFMA Toeplitz conv (8 titles/block,
// direct-global epilogue); blocks [CONV_BLOCKS, +PREP_BLOCKS) = weight prep
// (dwt' permuted zero-padded K=1024, transposed iwt/uwt). No cross-block
// dependency: conv doesn't read dwt/iwt/uwt; prep doesn't read flat.
// ---------------------------------------------------------------------------
__global__ __launch_bounds__(256, 4) void k_front(
    const int* __restrict__ title, const float* __restrict__ word_emb,
    const float* __restrict__ conv_w, const float* __restrict__ conv_b,
    const float* __restrict__ dw, const float* __restrict__ iw,
    const float* __restrict__ uw, __hip_bfloat16* __restrict__ flat,
    __hip_bfloat16* __restrict__ dwt, __hip_bfloat16* __restrict__ iwt,
    __hip_bfloat16* __restrict__ uwt) {
  const int tid = threadIdx.x;

  if (blockIdx.x >= CONV_BLOCKS) {  // ---- prep part ----
    const int idx = ((int)blockIdx.x - CONV_BLOCKS) * 256 + tid;
    if (idx < DIM * FLAT2) {
      const int col = idx & 127, k2 = idx >> 7;
      const int i = k2 & 3, X = k2 >> 2;
      const int c = X & 7, gkq = (X >> 3) & 3, jhq = (X >> 5) & 1, h = X >> 6;
      const int j = jhq * 16 + gkq * 4 + i;
      const float v = (j < 31) ? dw[(c * 124 + h * 31 + j) * 128 + col] : 0.f;
      dwt[col * FLAT2 + k2] = __float2bfloat16(v);
    } else if (idx < DIM * FLAT2 + DIM * DIM) {
      const int j = idx - DIM * FLAT2;
      const int o = j & 127, k = j >> 7;
      iwt[o * DIM + k] = __float2bfloat16(iw[j]);
    } else if (idx < PREP_ELEMS) {
      const int j = idx - DIM * FLAT2 - DIM * DIM;
      const int o = j & 127, k = j >> 7;
      uwt[o * DIM + k] = __float2bfloat16(uw[j]);
    }
    return;
  }

  // ---- conv part ----
  __shared__ int s_words[80];
  __shared__ __align__(16) ushort s_x[80 * 64];  // rows padded to 64

  const int wv = tid >> 6, lane = tid & 63;
  const int base = blockIdx.x * 8;
  const int c = lane & 15, gk = lane >> 4;

  bf16x8 b0, b1;
#pragma unroll
  for (int i = 0; i < 8; ++i) {
    const int k = gk * 8 + i;
    float v0 = 0.f, v1 = 0.f;
    if (c < 8 && k < 20) {
      v0 = conv_w[c * 40 + k];
      v1 = conv_w[c * 40 + 20 + k];
    }
    b0[i] = (short)bfbits(v0);
    b1[i] = (short)bfbits(v1);
  }
  const float cbias = (c < 8) ? conv_b[c] : 0.f;

  if (tid < 80) s_words[tid] = title[base * TITLE_LEN + tid];
  __syncthreads();

  {
    const float2* we2 = reinterpret_cast<const float2*>(word_emb);
#pragma unroll
    for (int i = 0; i < 3; ++i) {
      const int u = tid + i * 256;
      if (u < 640) {
        const int row = u >> 3, slot = u & 7;
        ushort o[8];
#pragma unroll
        for (int p = 0; p < 4; ++p) {
          const int c2 = slot * 4 + p;
          float2 v = make_float2(0.f, 0.f);
          if (c2 < 25) v = we2[(long long)s_words[row] * 25 + c2];
          o[2 * p] = bfbits(v.x);
          o[2 * p + 1] = bfbits(v.y);
        }
        *reinterpret_cast<uint4*>(&s_x[row * 64 + slot * 8]) =
            *reinterpret_cast<const uint4*>(o);
      }
    }
  }
  __syncthreads();

  ushort* fl = reinterpret_cast<ushort*>(flat);
#pragma unroll 1
  for (int tt = 0; tt < 2; ++tt) {
    const int t = wv * 2 + tt;
    const ushort* xb = &s_x[t * 640];
    ushort* gout = &fl[(size_t)(base + t) * FLAT2];
#pragma unroll
    for (int jh = 0; jh < 2; ++jh) {
      const int s = jh * 16 + (lane & 15) + gk * 8;
      bf16x8 fprev = bfrag(xb, s);
#pragma unroll
      for (int h = 0; h < 4; ++h) {
        const bf16x8 fmid = bfrag(xb + (2 * h + 1) * 64, s);
        const bf16x8 fnext = bfrag(xb + (2 * h + 2) * 64, s);
        f32x4 d0 = (f32x4){0.f, 0.f, 0.f, 0.f};
        f32x4 d1 = (f32x4){0.f, 0.f, 0.f, 0.f};
        d0 = __builtin_amdgcn_mfma_f32_16x16x32_bf16(fprev, b0, d0, 0, 0, 0);
        d0 = __builtin_amdgcn_mfma_f32_16x16x32_bf16(fmid, b1, d0, 0, 0, 0);
        d1 = __builtin_amdgcn_mfma_f32_16x16x32_bf16(fmid, b0, d1, 0, 0, 0);
        d1 = __builtin_amdgcn_mfma_f32_16x16x32_bf16(fnext, b1, d1, 0, 0, 0);
        if (c < 8) {
          ushort w[4];
#pragma unroll
          for (int i2 = 0; i2 < 4; ++i2)
            w[i2] = bfbits(fmaxf(fmaxf(d0[i2], d1[i2]) + cbias, 0.f));
          *reinterpret_cast<uint2*>(&gout[(h * 64 + jh * 32 + gk * 8 + c) * 4]) =
              *reinterpret_cast<const uint2*>(w);
        }
        fprev = fnext;
      }
    }
  }
}

// ---------------------------------------------------------------------------
// k_mid: blocks [0, DENSE_BLOCKS) = dense+item GEMM; blocks
// [DENSE_BLOCKS, +USER_BLOCKS) = user gather+GEMM. Independent outputs
// (news_cnn vs user_path); both consume dispatch-1 results only.
// ---------------------------------------------------------------------------
__global__ __launch_bounds__(256, 2) void k_mid(
    const __hip_bfloat16* __restrict__ flat,
    const __hip_bfloat16* __restrict__ dwt, const float* __restrict__ dense_b,
    const __hip_bfloat16* __restrict__ iwt, const float* __restrict__ item_b,
    __hip_bfloat16* __restrict__ news_cnn,
    const int* __restrict__ user_indices, const int* __restrict__ news_indices,
    const int* __restrict__ news_user, const float* __restrict__ user_emb,
    const __hip_bfloat16* __restrict__ uwt, const float* __restrict__ user_b,
    __hip_bfloat16* __restrict__ user_path) {
  __shared__ __align__(16) char lds[18432];
  const int tid = threadIdx.x;
  const int wv = tid >> 6, lane = tid & 63;
  const int fr = lane & 15, gk = lane >> 4;

  if (blockIdx.x < DENSE_BLOCKS) {  // ---- dense part ----
    ushort* A0 = (ushort*)lds;           // [64][72]
    ushort* A1 = (ushort*)(lds + 9216);  // [64][72]
    ushort* c1 = (ushort*)lds;           // [64][136] overlay after dense

    const int lrow0 = min((int)blockIdx.x * 64, NNEWS - 64);
    const ushort* fl = (const ushort*)flat;
    const ushort* dwp = (const ushort*)dwt;

    uint4 pA[2];
#define LD_A(KS)                                                              \
  {                                                                           \
    _Pragma("unroll") for (int q = 0; q < 2; ++q) {                           \
      const int uu = tid + q * 256;                                           \
      pA[q] = *reinterpret_cast<const uint4*>(                                \
          &fl[(size_t)(lrow0 + (uu >> 3)) * FLAT2 + (KS) * 64 + (uu & 7) * 8]); \
    }                                                                         \
  }
#define ST_A(BUF)                                                             \
  {                                                                           \
    _Pragma("unroll") for (int q = 0; q < 2; ++q) {                           \
      const int uu = tid + q * 256;                                           \
      *reinterpret_cast<uint4*>(&(BUF)[(uu >> 3) * 72 + (uu & 7) * 8]) = pA[q]; \
    }                                                                         \
  }
#define LD_B(DST, KS)                                                         \
  {                                                                           \
    _Pragma("unroll") for (int nn = 0; nn < 2; ++nn)                          \
        _Pragma("unroll") for (int qq = 0; qq < 2; ++qq) {                    \
      (DST)[nn * 2 + qq] = *reinterpret_cast<const bf16x8*>(                  \
          &dwp[(wv * 32 + nn * 16 + fr) * FLAT2 + (KS) * 64 + qq * 32 +       \
               gk * 8]);                                                      \
    }                                                                         \
  }

    LD_A(0);
    ST_A(A0);
    LD_A(1);
    bf16x8 bA[4];
    LD_B(bA, 0);
    __syncthreads();

    f32x4 acc[4][2];
#pragma unroll
    for (int m = 0; m < 4; ++m)
#pragma unroll
      for (int n2 = 0; n2 < 2; ++n2) acc[m][n2] = (f32x4){0.f, 0.f, 0.f, 0.f};

    for (int ks = 0; ks < 16; ++ks) {
      const ushort* cA = (ks & 1) ? A1 : A0;
      bf16x8 bN[4];
      if (ks < 15) {
        LD_B(bN, ks + 1);
      } else {
#pragma unroll
        for (int z = 0; z < 4; ++z) bN[z] = bA[z];
      }
      bf16x8 af[2][4];
#pragma unroll
      for (int kk = 0; kk < 2; ++kk)
#pragma unroll
        for (int m = 0; m < 4; ++m)
          af[kk][m] = *reinterpret_cast<const bf16x8*>(
              &cA[(m * 16 + fr) * 72 + kk * 32 + gk * 8]);
#pragma unroll
      for (int kk = 0; kk < 2; ++kk)
#pragma unroll
        for (int m = 0; m < 4; ++m)
#pragma unroll
          for (int n2 = 0; n2 < 2; ++n2)
            acc[m][n2] = __builtin_amdgcn_mfma_f32_16x16x32_bf16(
                af[kk][m], bA[n2 * 2 + kk], acc[m][n2], 0, 0, 0);
      if (ks < 15) {
        if (ks & 1) {
          ST_A(A0);
        } else {
          ST_A(A1);
        }
      }
      if (ks < 14) LD_A(ks + 2);
      __syncthreads();
#pragma unroll
      for (int z = 0; z < 4; ++z) bA[z] = bN[z];
    }
#undef LD_A
#undef ST_A
#undef LD_B

#pragma unroll
    for (int n2 = 0; n2 < 2; ++n2) {
      const int col = wv * 32 + n2 * 16 + fr;
      const float bb = dense_b[col];
#pragma unroll
      for (int m = 0; m < 4; ++m)
#pragma unroll
        for (int r = 0; r < 4; ++r)
          c1[(m * 16 + gk * 4 + r) * 136 + col] =
              bfbits(fmaxf(acc[m][n2][r] + bb, 0.f));
    }
    __syncthreads();

    const ushort* iwp = (const ushort*)iwt;
    f32x4 a2[4][2];
#pragma unroll
    for (int m = 0; m < 4; ++m)
#pragma unroll
      for (int n2 = 0; n2 < 2; ++n2) a2[m][n2] = (f32x4){0.f, 0.f, 0.f, 0.f};
#pragma unroll
    for (int kk = 0; kk < 4; ++kk) {
      bf16x8 af[4], bfr[2];
#pragma unroll
      for (int m = 0; m < 4; ++m)
        af[m] = *reinterpret_cast<const bf16x8*>(
            &c1[(m * 16 + fr) * 136 + kk * 32 + gk * 8]);
#pragma unroll
      for (int n2 = 0; n2 < 2; ++n2)
        bfr[n2] = *reinterpret_cast<const bf16x8*>(
            &iwp[(wv * 32 + n2 * 16 + fr) * DIM + kk * 32 + gk * 8]);
#pragma unroll
      for (int m = 0; m < 4; ++m)
#pragma unroll
        for (int n2 = 0; n2 < 2; ++n2)
          a2[m][n2] = __builtin_amdgcn_mfma_f32_16x16x32_bf16(
              af[m], bfr[n2], a2[m][n2], 0, 0, 0);
    }

#pragma unroll
    for (int n2 = 0; n2 < 2; ++n2) {
      const int col = wv * 32 + n2 * 16 + fr;
      const float bb = item_b[col];
#pragma unroll
      for (int m = 0; m < 4; ++m)
#pragma unroll
        for (int r = 0; r < 4; ++r) {
          const int row = m * 16 + gk * 4 + r;
          news_cnn[(size_t)(lrow0 + row) * DIM + col] =
              __float2bfloat16(fmaxf(a2[m][n2][r] + bb, 0.f));
        }
    }
    return;
  }

  // ---- user part ----
  __hip_bfloat16* s_e = (__hip_bfloat16*)lds;  // [32][136] = 8704 B
  int* s_uid = (int*)(lds + 8704);             // 128 B
  const int base = ((int)blockIdx.x - DENSE_BLOCKS) * 32;

  if (tid < 32) {
    const int r = base + tid;
    int uid;
    if (r < BSZ) {
      uid = user_indices[r];
    } else {
      const int j = r - BSZ;
      const int b = j / U_NB, k = j - b * U_NB;
      uid = news_user[(long long)news_indices[b] * U_NB + k];
    }
    s_uid[tid] = uid;
  }
  __syncthreads();
#pragma unroll
  for (int i = 0; i < 4; ++i) {
    const int u = tid + i * 256;
    const int row = u >> 5, d4 = u & 31;
    const float4 v = *reinterpret_cast<const float4*>(
        &user_emb[(long long)s_uid[row] * DIM + d4 * 4]);
    __hip_bfloat16* p = &s_e[row * 136 + d4 * 4];
    p[0] = __float2bfloat16(v.x);
    p[1] = __float2bfloat16(v.y);
    p[2] = __float2bfloat16(v.z);
    p[3] = __float2bfloat16(v.w);
  }
  __syncthreads();

  const ushort* uwp = (const ushort*)uwt;
  f32x4 acc[2][2];
#pragma unroll
  for (int m = 0; m < 2; ++m)
#pragma unroll
    for (int n = 0; n < 2; ++n) acc[m][n] = (f32x4){0.f, 0.f, 0.f, 0.f};

#pragma unroll
  for (int ks = 0; ks < 4; ++ks) {
    bf16x8 af[2], bfr[2];
#pragma unroll
    for (int m = 0; m < 2; ++m)
      af[m] = *reinterpret_cast<const bf16x8*>(
          &s_e[(m * 16 + fr) * 136 + ks * 32 + gk * 8]);
#pragma unroll
    for (int n = 0; n < 2; ++n)
      bfr[n] = *reinterpret_cast<const bf16x8*>(
          &uwp[(wv * 32 + n * 16 + fr) * DIM + ks * 32 + gk * 8]);
#pragma unroll
    for (int m = 0; m < 2; ++m)
#pragma unroll
      for (int n = 0; n < 2; ++n)
        acc[m][n] = __builtin_amdgcn_mfma_f32_16x16x32_bf16(af[m], bfr[n],
                                                            acc[m][n], 0, 0, 0);
  }

#pragma unroll
  for (int n = 0; n < 2; ++n) {
    const int col = wv * 32 + n * 16 + fr;
    const float bb = user_b[col];
#pragma unroll
    for (int m = 0; m < 2; ++m)
#pragma unroll
      for (int r = 0; r < 4; ++r) {
        const int row = m * 16 + gk * 4 + r;
        user_path[(size_t)(base + row) * DIM + col] =
            __float2bfloat16(fmaxf(acc[m][n][r] + bb, 0.f));
      }
  }
}

// ---------------------------------------------------------------------------
// k_back: 512 thr/block, block b: threads 0-255 route the news side,
// 256-511 route the user side (lockstep barriers, independent data),
// then inline scoring (sum((u@W+b)*(n@W+b)) -> sigmoid -> out[b]).
// ---------------------------------------------------------------------------
__device__ __forceinline__ float gsum16(float v) {
  v += __shfl_xor(v, 1, 16);
  v += __shfl_xor(v, 2, 16);
  v += __shfl_xor(v, 4, 16);
  v += __shfl_xor(v, 8, 16);
  return v;
}

__global__ __launch_bounds__(512) void k_back(
    const __hip_bfloat16* __restrict__ news_cnn,
    const __hip_bfloat16* __restrict__ user_path,
    const int* __restrict__ user_indices, const int* __restrict__ news_indices,
    const int* __restrict__ user_news, const float* __restrict__ last_w,
    const float* __restrict__ last_b, float* __restrict__ out) {
  __shared__ int s_nid[32];
  __shared__ __align__(16) float zf2[2][30][132];
  __shared__ __align__(16) float xn2[2][128];
  __shared__ __align__(16) float uu2[2][128];
  __shared__ __align__(16) float pp2[2][30][8];
  __shared__ float s_r[2];

  const int b = blockIdx.x, tid = threadIdx.x;
  const int hs = tid >> 8;          // 0 = news side, 1 = user side
  const int t = tid & 255;
  const bool is_news = (hs == 0);
  float(*zf)[132] = zf2[hs];
  float* xn = xn2[hs];
  float* uu = uu2[hs];
  float(*pp)[8] = pp2[hs];

  if (!is_news && t < 30)
    s_nid[t] = user_news[(long long)user_indices[b] * N_NB + t];
  __syncthreads();

  // stage z rows (bf16 -> f32 LDS); 240 threads/side, 16 elems each
  const __hip_bfloat16* zsrc = is_news ? user_path : news_cnn;
  if (t < 240) {
    const int k = t >> 3, q = t & 7;
    const int zid = is_news ? (BSZ + b * 30 + k) : s_nid[k];
    const ushort* src =
        reinterpret_cast<const ushort*>(zsrc + (long long)zid * DIM);
    ushort h16[16];
    *reinterpret_cast<uint4*>(&h16[0]) =
        *reinterpret_cast<const uint4*>(&src[q * 16]);
    *reinterpret_cast<uint4*>(&h16[8]) =
        *reinterpret_cast<const uint4*>(&src[q * 16 + 8]);
    float f[16];
#pragma unroll
    for (int i = 0; i < 16; ++i) {
      const uint bits = ((uint)h16[i]) << 16;
      __builtin_memcpy(&f[i], &bits, 4);
    }
#pragma unroll
    for (int v4 = 0; v4 < 4; ++v4)
      *reinterpret_cast<f32x4*>(&zf[k][q * 16 + v4 * 4]) =
          *reinterpret_cast<f32x4*>(&f[v4 * 4]);
  }
  // x: load + per-cap l2n
  if (t < 128) {
    const __hip_bfloat16* xrow =
        is_news ? news_cnn + (long long)news_indices[b] * DIM
                : user_path + (long long)b * DIM;
    float xv = __bfloat162float(xrow[t]);
    xv = xv / (sqrtf(gsum16(xv * xv)) + 1e-9f);
    xn[t] = xv;
    uu[t] = xv;
  }
  __syncthreads();

  // z-normalize locally; cache capsule in regs
  const int kk = t >> 3, cc = t & 7;
  float z16[16];
  if (t < 240) {
    float ss = 0.f;
#pragma unroll
    for (int d = 0; d < 16; ++d) {
      z16[d] = zf[kk][cc * 16 + d];
      ss += z16[d] * z16[d];
    }
    const float inv = 1.f / (sqrtf(ss) + 1e-9f);
#pragma unroll
    for (int d = 0; d < 16; ++d) {
      z16[d] *= inv;
      zf[kk][cc * 16 + d] = z16[d];
    }
  }
  __syncthreads();

  for (int it = 0; it < ROUTIT; ++it) {
    if (t < 240) {
      float dot = 0.f;
#pragma unroll
      for (int d = 0; d < 16; ++d) dot += z16[d] * uu[cc * 16 + d];
      pp[kk][cc] = dot;
    }
    __syncthreads();
    if (t < 30) {
      float m = -1e30f, e[8], s = 0.f;
#pragma unroll
      for (int c2 = 0; c2 < 8; ++c2) m = fmaxf(m, pp[t][c2]);
#pragma unroll
      for (int c2 = 0; c2 < 8; ++c2) {
        e[c2] = expf(pp[t][c2] - m);
        s += e[c2];
      }
      const float invs = 1.f / s;
#pragma unroll
      for (int c2 = 0; c2 < 8; ++c2) pp[t][c2] = e[c2] * invs;
    }
    __syncthreads();
    if (t < 128) {
      const int c2 = t >> 4;
      float agg = xn[t];
#pragma unroll
      for (int k = 0; k < 30; ++k) agg += pp[k][c2] * zf[k][t];
      uu[t] = agg / (sqrtf(gsum16(agg * agg)) + 1e-9f);
    }
    __syncthreads();
  }

  // inline score: uu2[0] = news emb, uu2[1] = user emb
  if (tid < 128) {
    float xm = last_b[tid], ym = xm;
    for (int k = 0; k < DIM; k += 4) {
#pragma unroll
      for (int i = 0; i < 4; ++i) {
        const float w = last_w[(k + i) * DIM + tid];
        xm += uu2[1][k + i] * w;  // user emb @ W
        ym += uu2[0][k + i] * w;  // news emb @ W
      }
    }
    float prod = xm * ym;
#pragma unroll
    for (int off = 1; off < 64; off <<= 1) prod += __shfl_xor(prod, off, 64);
    if ((tid & 63) == 0) s_r[tid >> 6] = prod;
  }
  __syncthreads();
  if (tid == 0) out[b] = 1.f / (1.f + expf(-(s_r[0] + s_r[1])));
}

// ---------------------------------------------------------------------------
extern "C" void kernel_launch(void* const* d_in, const int* in_sizes, int n_in,
                              void* d_out, int out_size, void* d_ws,
                              size_t ws_size, hipStream_t stream) {
  (void)in_sizes; (void)n_in; (void)out_size; (void)ws_size;
  const int* user_indices = (const int*)d_in[0];
  const int* news_indices = (const int*)d_in[1];
  const int* news_user = (const int*)d_in[3];
  const int* user_news = (const int*)d_in[4];
  const int* title = (const int*)d_in[5];
  const float* user_emb_matrix = (const float*)d_in[6];
  const float* word_emb_matrix = (const float*)d_in[7];
  const float* conv_w = (const float*)d_in[8];
  const float* conv_b = (const float*)d_in[9];
  const float* dense_w = (const float*)d_in[10];
  const float* dense_b = (const float*)d_in[11];
  const float* user_weights = (const float*)d_in[12];
  const float* user_bias = (const float*)d_in[13];
  const float* item_weights = (const float*)d_in[14];
  const float* item_bias = (const float*)d_in[15];
  const float* last_w = (const float*)d_in[16];
  const float* last_b = (const float*)d_in[17];

  char* ws = (char*)d_ws;
  __hip_bfloat16* flat = (__hip_bfloat16*)ws;            // 102.4 MB
  ws += (size_t)NNEWS * FLAT2 * 2;
  __hip_bfloat16* news_cnn = (__hip_bfloat16*)ws;        // 12.8 MB
  ws += (size_t)NNEWS * DIM * 2;
  __hip_bfloat16* user_path = (__hip_bfloat16*)ws;       // 16.25 MB
  ws += (size_t)NJOBS * DIM * 2;
  __hip_bfloat16* dwt = (__hip_bfloat16*)ws;             // 262,144 B
  ws += (size_t)DIM * FLAT2 * 2;
  __hip_bfloat16* iwt = (__hip_bfloat16*)ws;
  ws += (size_t)DIM * DIM * 2;
  __hip_bfloat16* uwt = (__hip_bfloat16*)ws;
  float* out = (float*)d_out;

  k_front<<<CONV_BLOCKS + PREP_BLOCKS, 256, 0, stream>>>(
      title, word_emb_matrix, conv_w, conv_b, dense_w, item_weights,
      user_weights, flat, dwt, iwt, uwt);
  k_mid<<<DENSE_BLOCKS + USER_BLOCKS, 256, 0, stream>>>(
      flat, dwt, dense_b, iwt, item_bias, news_cnn, user_indices, news_indices,
      news_user, user_emb_matrix, uwt, user_bias, user_path);
  k_back<<<BSZ, 512, 0, stream>>>(news_cnn, user_path, user_indices,
                                  news_indices, user_news, last_w, last_b,
                                  out);
}

// Round 12
// 188.044 us; speedup vs baseline: 7.6042x; 1.0001x over previous
//
#include <hip/hip_runtime.h>
#include <hip/hip_bf16.h>
#include <math.h>

#define BSZ 2048
#define NNEWS 50000
#define U_NB 30
#define N_NB 30
#define TITLE_LEN 10
#define W_EMB 50
#define DIM 128
#define ROUTIT 4
#define FLAT2 1024        // permuted, zero-padded K

#define CONV_BLOCKS (NNEWS / 8)                       // 6250
#define PREP_ELEMS (DIM * FLAT2 + 2 * DIM * DIM)      // 163,840
#define PREP_BLOCKS (PREP_ELEMS / 256)                // 640
#define DENSE_BLOCKS ((NNEWS + 63) / 64)              // 782

typedef __attribute__((ext_vector_type(8))) short bf16x8;
typedef __attribute__((ext_vector_type(4))) float f32x4;

__device__ __forceinline__ ushort bfbits(float v) {
  __hip_bfloat16 h = __float2bfloat16(v);
  ushort u;
  __builtin_memcpy(&u, &h, 2);
  return u;
}

// Build a bf16x8 A-frag = x[s..s+8) from a 16B-aligned 64-elem bf16 row.
__device__ __forceinline__ bf16x8 bfrag(const ushort* row, int s) {
  const char* p = reinterpret_cast<const char*>(row) + ((s * 2) & ~15);
  const uint4 lo = *reinterpret_cast<const uint4*>(p);
  const uint4 hi = *reinterpret_cast<const uint4*>(p + 16);
  const uint d0 = lo.x, d1 = lo.y, d2 = lo.z, d3 = lo.w;
  const uint d4 = hi.x, d5 = hi.y, d6 = hi.z, d7 = hi.w;
  const bool q2 = (s & 4) != 0;
  const uint e0 = q2 ? d2 : d0, e1 = q2 ? d3 : d1, e2 = q2 ? d4 : d2;
  const uint e3 = q2 ? d5 : d3, e4 = q2 ? d6 : d4, e5 = q2 ? d7 : d5;
  const bool q1 = (s & 2) != 0;
  const uint f0 = q1 ? e1 : e0, f1 = q1 ? e2 : e1, f2 = q1 ? e3 : e2;
  const uint f3 = q1 ? e4 : e3, f4 = q1 ? e5 : e4;
  const bool r1 = (s & 1) != 0;
  uint g[4];
  g[0] = r1 ? ((f0 >> 16) | (f1 << 16)) : f0;
  g[1] = r1 ? ((f1 >> 16) | (f2 << 16)) : f1;
  g[2] = r1 ? ((f2 >> 16) | (f3 << 16)) : f2;
  g[3] = r1 ? ((f3 >> 16) | (f4 << 16)) : f3;
  bf16x8 r;
  __builtin_memcpy(&r, g, 16);
  return r;
}

// ---------------------------------------------------------------------------
// k_front: blocks [0, CONV_BLOCKS) = MFMA Toeplitz conv; blocks
// [CONV_BLOCKS, +PREP_BLOCKS) = weight prep (dwt'/iwt/uwt).
// ---------------------------------------------------------------------------
__global__ __launch_bounds__(256, 4) void k_front(
    const int* __restrict__ title, const float* __restrict__ word_emb,
    const float* __restrict__ conv_w, const float* __restrict__ conv_b,
    const float* __restrict__ dw, const float* __restrict__ iw,
    const float* __restrict__ uw, __hip_bfloat16* __restrict__ flat,
    __hip_bfloat16* __restrict__ dwt, __hip_bfloat16* __restrict__ iwt,
    __hip_bfloat16* __restrict__ uwt) {
  const int tid = threadIdx.x;

  if (blockIdx.x >= CONV_BLOCKS) {  // ---- prep part ----
    const int idx = ((int)blockIdx.x - CONV_BLOCKS) * 256 + tid;
    if (idx < DIM * FLAT2) {
      const int col = idx & 127, k2 = idx >> 7;
      const int i = k2 & 3, X = k2 >> 2;
      const int c = X & 7, gkq = (X >> 3) & 3, jhq = (X >> 5) & 1, h = X >> 6;
      const int j = jhq * 16 + gkq * 4 + i;
      const float v = (j < 31) ? dw[(c * 124 + h * 31 + j) * 128 + col] : 0.f;
      dwt[col * FLAT2 + k2] = __float2bfloat16(v);
    } else if (idx < DIM * FLAT2 + DIM * DIM) {
      const int j = idx - DIM * FLAT2;
      const int o = j & 127, k = j >> 7;
      iwt[o * DIM + k] = __float2bfloat16(iw[j]);
    } else if (idx < PREP_ELEMS) {
      const int j = idx - DIM * FLAT2 - DIM * DIM;
      const int o = j & 127, k = j >> 7;
      uwt[o * DIM + k] = __float2bfloat16(uw[j]);
    }
    return;
  }

  // ---- conv part ----
  __shared__ int s_words[80];
  __shared__ __align__(16) ushort s_x[80 * 64];

  const int wv = tid >> 6, lane = tid & 63;
  const int base = blockIdx.x * 8;
  const int c = lane & 15, gk = lane >> 4;

  bf16x8 b0, b1;
#pragma unroll
  for (int i = 0; i < 8; ++i) {
    const int k = gk * 8 + i;
    float v0 = 0.f, v1 = 0.f;
    if (c < 8 && k < 20) {
      v0 = conv_w[c * 40 + k];
      v1 = conv_w[c * 40 + 20 + k];
    }
    b0[i] = (short)bfbits(v0);
    b1[i] = (short)bfbits(v1);
  }
  const float cbias = (c < 8) ? conv_b[c] : 0.f;

  if (tid < 80) s_words[tid] = title[base * TITLE_LEN + tid];
  __syncthreads();

  {
    const float2* we2 = reinterpret_cast<const float2*>(word_emb);
#pragma unroll
    for (int i = 0; i < 3; ++i) {
      const int u = tid + i * 256;
      if (u < 640) {
        const int row = u >> 3, slot = u & 7;
        ushort o[8];
#pragma unroll
        for (int p = 0; p < 4; ++p) {
          const int c2 = slot * 4 + p;
          float2 v = make_float2(0.f, 0.f);
          if (c2 < 25) v = we2[(long long)s_words[row] * 25 + c2];
          o[2 * p] = bfbits(v.x);
          o[2 * p + 1] = bfbits(v.y);
        }
        *reinterpret_cast<uint4*>(&s_x[row * 64 + slot * 8]) =
            *reinterpret_cast<const uint4*>(o);
      }
    }
  }
  __syncthreads();

  ushort* fl = reinterpret_cast<ushort*>(flat);
#pragma unroll 1
  for (int tt = 0; tt < 2; ++tt) {
    const int t = wv * 2 + tt;
    const ushort* xb = &s_x[t * 640];
    ushort* gout = &fl[(size_t)(base + t) * FLAT2];
#pragma unroll
    for (int jh = 0; jh < 2; ++jh) {
      const int s = jh * 16 + (lane & 15) + gk * 8;
      bf16x8 fprev = bfrag(xb, s);
#pragma unroll
      for (int h = 0; h < 4; ++h) {
        const bf16x8 fmid = bfrag(xb + (2 * h + 1) * 64, s);
        const bf16x8 fnext = bfrag(xb + (2 * h + 2) * 64, s);
        f32x4 d0 = (f32x4){0.f, 0.f, 0.f, 0.f};
        f32x4 d1 = (f32x4){0.f, 0.f, 0.f, 0.f};
        d0 = __builtin_amdgcn_mfma_f32_16x16x32_bf16(fprev, b0, d0, 0, 0, 0);
        d0 = __builtin_amdgcn_mfma_f32_16x16x32_bf16(fmid, b1, d0, 0, 0, 0);
        d1 = __builtin_amdgcn_mfma_f32_16x16x32_bf16(fmid, b0, d1, 0, 0, 0);
        d1 = __builtin_amdgcn_mfma_f32_16x16x32_bf16(fnext, b1, d1, 0, 0, 0);
        if (c < 8) {
          ushort w[4];
#pragma unroll
          for (int i2 = 0; i2 < 4; ++i2)
            w[i2] = bfbits(fmaxf(fmaxf(d0[i2], d1[i2]) + cbias, 0.f));
          *reinterpret_cast<uint2*>(&gout[(h * 64 + jh * 32 + gk * 8 + c) * 4]) =
              *reinterpret_cast<const uint2*>(w);
        }
        fprev = fnext;
      }
    }
  }
}

// ---------------------------------------------------------------------------
// k_dense: [64 x 1024]@[1024 x 128] (+b, relu) then @[128 x 128] (+b, relu).
// ---------------------------------------------------------------------------
__global__ __launch_bounds__(256, 2) void k_dense(
    const __hip_bfloat16* __restrict__ flat,
    const __hip_bfloat16* __restrict__ dwt, const float* __restrict__ dense_b,
    const __hip_bfloat16* __restrict__ iwt, const float* __restrict__ item_b,
    __hip_bfloat16* __restrict__ news_cnn) {
  __shared__ __align__(16) char lds[18432];
  ushort* A0 = (ushort*)lds;
  ushort* A1 = (ushort*)(lds + 9216);
  ushort* c1 = (ushort*)lds;

  const int tid = threadIdx.x;
  const int wv = tid >> 6, lane = tid & 63;
  const int fr = lane & 15, gk = lane >> 4;
  const int lrow0 = min((int)blockIdx.x * 64, NNEWS - 64);
  const ushort* fl = (const ushort*)flat;
  const ushort* dwp = (const ushort*)dwt;

  uint4 pA[2];
#define LD_A(KS)                                                              \
  {                                                                           \
    _Pragma("unroll") for (int q = 0; q < 2; ++q) {                           \
      const int uu = tid + q * 256;                                           \
      pA[q] = *reinterpret_cast<const uint4*>(                                \
          &fl[(size_t)(lrow0 + (uu >> 3)) * FLAT2 + (KS) * 64 + (uu & 7) * 8]); \
    }                                                                         \
  }
#define ST_A(BUF)                                                             \
  {                                                                           \
    _Pragma("unroll") for (int q = 0; q < 2; ++q) {                           \
      const int uu = tid + q * 256;                                           \
      *reinterpret_cast<uint4*>(&(BUF)[(uu >> 3) * 72 + (uu & 7) * 8]) = pA[q]; \
    }                                                                         \
  }
#define LD_B(DST, KS)                                                         \
  {                                                                           \
    _Pragma("unroll") for (int nn = 0; nn < 2; ++nn)                          \
        _Pragma("unroll") for (int qq = 0; qq < 2; ++qq) {                    \
      (DST)[nn * 2 + qq] = *reinterpret_cast<const bf16x8*>(                  \
          &dwp[(wv * 32 + nn * 16 + fr) * FLAT2 + (KS) * 64 + qq * 32 +       \
               gk * 8]);                                                      \
    }                                                                         \
  }

  LD_A(0);
  ST_A(A0);
  LD_A(1);
  bf16x8 bA[4];
  LD_B(bA, 0);
  __syncthreads();

  f32x4 acc[4][2];
#pragma unroll
  for (int m = 0; m < 4; ++m)
#pragma unroll
    for (int n2 = 0; n2 < 2; ++n2) acc[m][n2] = (f32x4){0.f, 0.f, 0.f, 0.f};

  for (int ks = 0; ks < 16; ++ks) {
    const ushort* cA = (ks & 1) ? A1 : A0;
    bf16x8 bN[4];
    if (ks < 15) {
      LD_B(bN, ks + 1);
    } else {
#pragma unroll
      for (int z = 0; z < 4; ++z) bN[z] = bA[z];
    }
    bf16x8 af[2][4];
#pragma unroll
    for (int kk = 0; kk < 2; ++kk)
#pragma unroll
      for (int m = 0; m < 4; ++m)
        af[kk][m] = *reinterpret_cast<const bf16x8*>(
            &cA[(m * 16 + fr) * 72 + kk * 32 + gk * 8]);
#pragma unroll
    for (int kk = 0; kk < 2; ++kk)
#pragma unroll
      for (int m = 0; m < 4; ++m)
#pragma unroll
        for (int n2 = 0; n2 < 2; ++n2)
          acc[m][n2] = __builtin_amdgcn_mfma_f32_16x16x32_bf16(
              af[kk][m], bA[n2 * 2 + kk], acc[m][n2], 0, 0, 0);
    if (ks < 15) {
      if (ks & 1) {
        ST_A(A0);
      } else {
        ST_A(A1);
      }
    }
    if (ks < 14) LD_A(ks + 2);
    __syncthreads();
#pragma unroll
    for (int z = 0; z < 4; ++z) bA[z] = bN[z];
  }
#undef LD_A
#undef ST_A
#undef LD_B

#pragma unroll
  for (int n2 = 0; n2 < 2; ++n2) {
    const int col = wv * 32 + n2 * 16 + fr;
    const float bb = dense_b[col];
#pragma unroll
    for (int m = 0; m < 4; ++m)
#pragma unroll
      for (int r = 0; r < 4; ++r)
        c1[(m * 16 + gk * 4 + r) * 136 + col] =
            bfbits(fmaxf(acc[m][n2][r] + bb, 0.f));
  }
  __syncthreads();

  const ushort* iwp = (const ushort*)iwt;
  f32x4 a2[4][2];
#pragma unroll
  for (int m = 0; m < 4; ++m)
#pragma unroll
    for (int n2 = 0; n2 < 2; ++n2) a2[m][n2] = (f32x4){0.f, 0.f, 0.f, 0.f};
#pragma unroll
  for (int kk = 0; kk < 4; ++kk) {
    bf16x8 af[4], bfr[2];
#pragma unroll
    for (int m = 0; m < 4; ++m)
      af[m] = *reinterpret_cast<const bf16x8*>(
          &c1[(m * 16 + fr) * 136 + kk * 32 + gk * 8]);
#pragma unroll
    for (int n2 = 0; n2 < 2; ++n2)
      bfr[n2] = *reinterpret_cast<const bf16x8*>(
          &iwp[(wv * 32 + n2 * 16 + fr) * DIM + kk * 32 + gk * 8]);
#pragma unroll
    for (int m = 0; m < 4; ++m)
#pragma unroll
      for (int n2 = 0; n2 < 2; ++n2)
        a2[m][n2] = __builtin_amdgcn_mfma_f32_16x16x32_bf16(
            af[m], bfr[n2], a2[m][n2], 0, 0, 0);
  }

#pragma unroll
  for (int n2 = 0; n2 < 2; ++n2) {
    const int col = wv * 32 + n2 * 16 + fr;
    const float bb = item_b[col];
#pragma unroll
    for (int m = 0; m < 4; ++m)
#pragma unroll
      for (int r = 0; r < 4; ++r) {
        const int row = m * 16 + gk * 4 + r;
        news_cnn[(size_t)(lrow0 + row) * DIM + col] =
            __float2bfloat16(fmaxf(a2[m][n2][r] + bb, 0.f));
      }
  }
}

// ---------------------------------------------------------------------------
// k_back: 512 thr/block, block b.
// Waves 0-3: gather 32 user_emb rows (row0 = user x, rows 1..30 = news-side z
// sources, row31 dummy) -> bf16 LDS -> MFMA @ uwt -> f32 into zf[news]/xn[user].
// Waves 4-7 (concurrent): stage user-side z (news_cnn[user_news]) + news x.
// Then dual capsule routing (news side = threads 0..255, user side 256..511)
// with in-wave shfl softmax (no 30-thread phase), inline scoring.
// ---------------------------------------------------------------------------
__device__ __forceinline__ float gsum16(float v) {
  v += __shfl_xor(v, 1, 16);
  v += __shfl_xor(v, 2, 16);
  v += __shfl_xor(v, 4, 16);
  v += __shfl_xor(v, 8, 16);
  return v;
}

__global__ __launch_bounds__(512) void k_back(
    const __hip_bfloat16* __restrict__ news_cnn,
    const float* __restrict__ user_emb, const __hip_bfloat16* __restrict__ uwt,
    const float* __restrict__ user_b, const int* __restrict__ user_indices,
    const int* __restrict__ news_indices, const int* __restrict__ news_user,
    const int* __restrict__ user_news, const float* __restrict__ last_w,
    const float* __restrict__ last_b, float* __restrict__ out) {
  __shared__ int s_uid[32];
  __shared__ int s_nid[32];
  __shared__ __align__(16) __hip_bfloat16 s_e[32][136];  // 8704 B
  __shared__ __align__(16) float zf2[2][30][132];        // 31,680 B
  __shared__ __align__(16) float xn2[2][128];
  __shared__ __align__(16) float uu2[2][128];
  __shared__ __align__(16) float pp2[2][30][8];
  __shared__ float s_r[2];

  const int b = blockIdx.x, tid = threadIdx.x;

  // P0: index loads
  if (tid < 32) {
    int uid;
    if (tid == 0 || tid == 31)
      uid = user_indices[b];
    else
      uid = news_user[(long long)news_indices[b] * U_NB + (tid - 1)];
    s_uid[tid] = uid;
  }
  if (tid >= 64 && tid < 94)
    s_nid[tid - 64] = user_news[(long long)user_indices[b] * N_NB + (tid - 64)];
  __syncthreads();

  const int hs = tid >> 8;  // 0 = news side, 1 = user side
  const int t = tid & 255;
  float(*zf)[132] = zf2[hs];
  float* xn = xn2[hs];
  float* uu = uu2[hs];
  float(*pp)[8] = pp2[hs];

  // P1: waves 0-3 stage s_e; waves 4-7 stage user-side z + news x (raw f32)
  if (tid < 256) {
#pragma unroll
    for (int i = 0; i < 4; ++i) {
      const int u = tid + i * 256;
      const int row = u >> 5, d4 = u & 31;
      const float4 v = *reinterpret_cast<const float4*>(
          &user_emb[(long long)s_uid[row] * DIM + d4 * 4]);
      __hip_bfloat16* p = &s_e[row][d4 * 4];
      p[0] = __float2bfloat16(v.x);
      p[1] = __float2bfloat16(v.y);
      p[2] = __float2bfloat16(v.z);
      p[3] = __float2bfloat16(v.w);
    }
  } else {
    if (t < 240) {
      const int k = t >> 3, q = t & 7;
      const ushort* src =
          reinterpret_cast<const ushort*>(news_cnn + (long long)s_nid[k] * DIM);
      ushort h16[16];
      *reinterpret_cast<uint4*>(&h16[0]) =
          *reinterpret_cast<const uint4*>(&src[q * 16]);
      *reinterpret_cast<uint4*>(&h16[8]) =
          *reinterpret_cast<const uint4*>(&src[q * 16 + 8]);
      float f[16];
#pragma unroll
      for (int i = 0; i < 16; ++i) {
        const uint bits = ((uint)h16[i]) << 16;
        __builtin_memcpy(&f[i], &bits, 4);
      }
#pragma unroll
      for (int v4 = 0; v4 < 4; ++v4)
        *reinterpret_cast<f32x4*>(&zf2[1][k][q * 16 + v4 * 4]) =
            *reinterpret_cast<f32x4*>(&f[v4 * 4]);
    } else {
      // news-side x raw: 16 threads x 8 elems
      const int j = t - 240;
      const ushort* src = reinterpret_cast<const ushort*>(
          news_cnn + (long long)news_indices[b] * DIM);
      ushort h8[8];
      *reinterpret_cast<uint4*>(h8) =
          *reinterpret_cast<const uint4*>(&src[j * 8]);
#pragma unroll
      for (int i = 0; i < 8; ++i) {
        const uint bits = ((uint)h8[i]) << 16;
        float fv;
        __builtin_memcpy(&fv, &bits, 4);
        xn2[0][j * 8 + i] = fv;
      }
    }
  }
  __syncthreads();

  // P2: waves 0-3 GEMM -> zf2[0] rows / xn2[1]; waves 4-7 normalize zf2[1]
  float z16[16];
  const int kk = t >> 3, cc = t & 7;
  if (tid < 256) {
    const int wv = tid >> 6, lane = tid & 63;
    const int fr = lane & 15, gk = lane >> 4;
    const ushort* uwp = (const ushort*)uwt;
    f32x4 acc[2][2];
#pragma unroll
    for (int m = 0; m < 2; ++m)
#pragma unroll
      for (int n = 0; n < 2; ++n) acc[m][n] = (f32x4){0.f, 0.f, 0.f, 0.f};
#pragma unroll
    for (int ks = 0; ks < 4; ++ks) {
      bf16x8 af[2], bfr[2];
#pragma unroll
      for (int m = 0; m < 2; ++m)
        af[m] = *reinterpret_cast<const bf16x8*>(
            &s_e[m * 16 + fr][ks * 32 + gk * 8]);
#pragma unroll
      for (int n = 0; n < 2; ++n)
        bfr[n] = *reinterpret_cast<const bf16x8*>(
            &uwp[(wv * 32 + n * 16 + fr) * DIM + ks * 32 + gk * 8]);
#pragma unroll
      for (int m = 0; m < 2; ++m)
#pragma unroll
        for (int n = 0; n < 2; ++n)
          acc[m][n] = __builtin_amdgcn_mfma_f32_16x16x32_bf16(
              af[m], bfr[n], acc[m][n], 0, 0, 0);
    }
#pragma unroll
    for (int n = 0; n < 2; ++n) {
      const int col = wv * 32 + n * 16 + fr;
      const float bb = user_b[col];
#pragma unroll
      for (int m = 0; m < 2; ++m)
#pragma unroll
        for (int r = 0; r < 4; ++r) {
          const int row = m * 16 + gk * 4 + r;
          const float val = fmaxf(acc[m][n][r] + bb, 0.f);
          if (row == 0)
            xn2[1][col] = val;
          else if (row < 31)
            zf2[0][row - 1][col] = val;
        }
    }
  } else if (t < 240) {
    float ss = 0.f;
#pragma unroll
    for (int d = 0; d < 16; ++d) {
      z16[d] = zf2[1][kk][cc * 16 + d];
      ss += z16[d] * z16[d];
    }
    const float inv = 1.f / (sqrtf(ss) + 1e-9f);
#pragma unroll
    for (int d = 0; d < 16; ++d) {
      z16[d] *= inv;
      zf2[1][kk][cc * 16 + d] = z16[d];
    }
  }
  __syncthreads();

  // P3: news-side z-normalize; x-normalize both sides
  if (hs == 0 && t < 240) {
    float ss = 0.f;
#pragma unroll
    for (int d = 0; d < 16; ++d) {
      z16[d] = zf2[0][kk][cc * 16 + d];
      ss += z16[d] * z16[d];
    }
    const float inv = 1.f / (sqrtf(ss) + 1e-9f);
#pragma unroll
    for (int d = 0; d < 16; ++d) {
      z16[d] *= inv;
      zf2[0][kk][cc * 16 + d] = z16[d];
    }
  }
  if (t < 128) {
    float xv = xn[t];
    xv = xv / (sqrtf(gsum16(xv * xv)) + 1e-9f);
    xn[t] = xv;
    uu[t] = xv;
  }
  __syncthreads();

  // P4: routing iterations (2 barriers each; softmax via 8-lane shfl)
  for (int it = 0; it < ROUTIT; ++it) {
    if (t < 240) {
      float dot = 0.f;
#pragma unroll
      for (int d = 0; d < 16; ++d) dot += z16[d] * uu[cc * 16 + d];
      float m8 = dot;
      m8 = fmaxf(m8, __shfl_xor(m8, 1, 8));
      m8 = fmaxf(m8, __shfl_xor(m8, 2, 8));
      m8 = fmaxf(m8, __shfl_xor(m8, 4, 8));
      float e = expf(dot - m8);
      float s8 = e;
      s8 += __shfl_xor(s8, 1, 8);
      s8 += __shfl_xor(s8, 2, 8);
      s8 += __shfl_xor(s8, 4, 8);
      pp[kk][cc] = e / s8;
    }
    __syncthreads();
    if (t < 128) {
      const int c2 = t >> 4;
      float agg = xn[t];
#pragma unroll
      for (int k = 0; k < 30; ++k) agg += pp[k][c2] * zf[k][t];
      uu[t] = agg / (sqrtf(gsum16(agg * agg)) + 1e-9f);
    }
    __syncthreads();
  }

  // P5: inline score. uu2[0] = news emb, uu2[1] = user emb
  if (tid < 128) {
    float xm = last_b[tid], ym = xm;
    for (int k = 0; k < DIM; k += 4) {
#pragma unroll
      for (int i = 0; i < 4; ++i) {
        const float w = last_w[(k + i) * DIM + tid];
        xm += uu2[1][k + i] * w;
        ym += uu2[0][k + i] * w;
      }
    }
    float prod = xm * ym;
#pragma unroll
    for (int off = 1; off < 64; off <<= 1) prod += __shfl_xor(prod, off, 64);
    if ((tid & 63) == 0) s_r[tid >> 6] = prod;
  }
  __syncthreads();
  if (tid == 0) out[b] = 1.f / (1.f + expf(-(s_r[0] + s_r[1])));
}

// ---------------------------------------------------------------------------
extern "C" void kernel_launch(void* const* d_in, const int* in_sizes, int n_in,
                              void* d_out, int out_size, void* d_ws,
                              size_t ws_size, hipStream_t stream) {
  (void)in_sizes; (void)n_in; (void)out_size; (void)ws_size;
  const int* user_indices = (const int*)d_in[0];
  const int* news_indices = (const int*)d_in[1];
  const int* news_user = (const int*)d_in[3];
  const int* user_news = (const int*)d_in[4];
  const int* title = (const int*)d_in[5];
  const float* user_emb_matrix = (const float*)d_in[6];
  const float* word_emb_matrix = (const float*)d_in[7];
  const float* conv_w = (const float*)d_in[8];
  const float* conv_b = (const float*)d_in[9];
  const float* dense_w = (const float*)d_in[10];
  const float* dense_b = (const float*)d_in[11];
  const float* user_weights = (const float*)d_in[12];
  const float* user_bias = (const float*)d_in[13];
  const float* item_weights = (const float*)d_in[14];
  const float* item_bias = (const float*)d_in[15];
  const float* last_w = (const float*)d_in[16];
  const float* last_b = (const float*)d_in[17];

  char* ws = (char*)d_ws;
  __hip_bfloat16* flat = (__hip_bfloat16*)ws;            // 102.4 MB
  ws += (size_t)NNEWS * FLAT2 * 2;
  __hip_bfloat16* news_cnn = (__hip_bfloat16*)ws;        // 12.8 MB
  ws += (size_t)NNEWS * DIM * 2;
  __hip_bfloat16* dwt = (__hip_bfloat16*)ws;             // 262,144 B
  ws += (size_t)DIM * FLAT2 * 2;
  __hip_bfloat16* iwt = (__hip_bfloat16*)ws;
  ws += (size_t)DIM * DIM * 2;
  __hip_bfloat16* uwt = (__hip_bfloat16*)ws;
  float* out = (float*)d_out;

  k_front<<<CONV_BLOCKS + PREP_BLOCKS, 256, 0, stream>>>(
      title, word_emb_matrix, conv_w, conv_b, dense_w, item_weights,
      user_weights, flat, dwt, iwt, uwt);
  k_dense<<<DENSE_BLOCKS, 256, 0, stream>>>(flat, dwt, dense_b, iwt, item_bias,
                                            news_cnn);
  k_back<<<BSZ, 512, 0, stream>>>(news_cnn, user_emb_matrix, uwt, user_bias,
                                  user_indices, news_indices, news_user,
                                  user_news, last_w, last_b, out);
}